// Round 1
// baseline (3551.208 us; speedup 1.0000x reference)
//
#include <hip/hip_runtime.h>

#define Nn 50000
#define Ee 600000
#define Gg 8
#define Dd 128
#define NPB 256

// ---------------- degree / norm ----------------
__global__ __launch_bounds__(256) void degree_kernel(
    const int* __restrict__ src, const int* __restrict__ dst,
    float* __restrict__ odeg, float* __restrict__ ideg)
{
    int e = blockIdx.x * 256 + threadIdx.x;
    if (e >= Ee) return;
    atomicAdd(&odeg[src[e]], 1.f);
    atomicAdd(&ideg[dst[e]], 1.f);
}

__global__ __launch_bounds__(256) void norm_kernel(
    float* __restrict__ odeg, float* __restrict__ ideg)
{
    int n = blockIdx.x * 256 + threadIdx.x;
    if (n >= Nn) return;
    odeg[n] = 1.f / sqrtf(fmaxf(odeg[n], 1.f));   // src_norm
    ideg[n] = 1.f / sqrtf(fmaxf(ideg[n], 1.f));   // dst_norm
}

// ---------------- fused GEMM ----------------
// Y = xeff @ W,  xeff[r][k] = ((a ? X[r][k]*a[r] + bias[k] : X[r][k])) * s[r]
// 128-row tile x 128 cols, 256 threads, 8x8 register blocking.
// LDS: W 64KB + X^T tile 128x132 (66KB) = 130KB -> 1 block/CU.
__global__ __launch_bounds__(256) void gemm_kernel(
    const float* __restrict__ X, const float* __restrict__ W,
    const float* __restrict__ a, const float* __restrict__ bias,
    const float* __restrict__ s, float* __restrict__ Y, int nrows)
{
    __shared__ float Ws[128 * 128];
    __shared__ float Xs[128 * 132];   // transposed [k][row], pad 132 for b128 align
    int t = threadIdx.x;

    const float4* W4 = (const float4*)W;
    float4* Ws4 = (float4*)Ws;
#pragma unroll
    for (int i = 0; i < 16; ++i) Ws4[t + 256 * i] = W4[t + 256 * i];

    int row0 = blockIdx.x * 128;
    for (int i = 0; i < 64; ++i) {
        int f = t + 256 * i;           // 0..16383
        int r = f >> 7, c = f & 127;
        int row = row0 + r;
        float v = 0.f;
        if (row < nrows) {
            v = X[(size_t)row * Dd + c];
            float sr = s[row];
            if (a) v = v * a[row] + bias[c];
            v *= sr;
        }
        Xs[c * 132 + r] = v;
    }
    __syncthreads();

    int tc = t & 15, tr = t >> 4;
    int r0 = tr * 8, c0 = tc * 4;

    float acc[8][8];
#pragma unroll
    for (int i = 0; i < 8; ++i)
#pragma unroll
        for (int j = 0; j < 8; ++j) acc[i][j] = 0.f;

#pragma unroll 2
    for (int k = 0; k < 128; ++k) {
        const float4 xa = *(const float4*)(Xs + k * 132 + r0);
        const float4 xb = *(const float4*)(Xs + k * 132 + r0 + 4);
        const float4 wa = *(const float4*)(Ws + k * 128 + c0);
        const float4 wb = *(const float4*)(Ws + k * 128 + c0 + 64);
        float xv[8] = {xa.x, xa.y, xa.z, xa.w, xb.x, xb.y, xb.z, xb.w};
        float wv[8] = {wa.x, wa.y, wa.z, wa.w, wb.x, wb.y, wb.z, wb.w};
#pragma unroll
        for (int i = 0; i < 8; ++i)
#pragma unroll
            for (int j = 0; j < 8; ++j)
                acc[i][j] += xv[i] * wv[j];
    }

#pragma unroll
    for (int i = 0; i < 8; ++i) {
        int row = row0 + r0 + i;
        if (row >= nrows) continue;
        float4 o;
        o.x = acc[i][0]; o.y = acc[i][1]; o.z = acc[i][2]; o.w = acc[i][3];
        *(float4*)(Y + (size_t)row * Dd + c0) = o;
        o.x = acc[i][4]; o.y = acc[i][5]; o.z = acc[i][6]; o.w = acc[i][7];
        *(float4*)(Y + (size_t)row * Dd + c0 + 64) = o;
    }
}

// ---------------- scatter SpMM (atomics) ----------------
// agg[dst[e]][:] += Y[src[e]][:]   -- 32 lanes/edge, float4 each
__global__ __launch_bounds__(256) void scatter_kernel(
    const float* __restrict__ Y, const int* __restrict__ src,
    const int* __restrict__ dst, float* __restrict__ agg)
{
    int idx = blockIdx.x * 256 + threadIdx.x;
    int e = idx >> 5;
    if (e >= Ee) return;
    int c4 = idx & 31;
    int sn = src[e], dn = dst[e];
    const float4 v = *(const float4*)(Y + (size_t)sn * Dd + c4 * 4);
    float* ap = agg + (size_t)dn * Dd + c4 * 4;
    atomicAdd(ap + 0, v.x);
    atomicAdd(ap + 1, v.y);
    atomicAdd(ap + 2, v.z);
    atomicAdd(ap + 3, v.w);
}

// ---------------- mean_nodes pooling ----------------
// h3[n][c] = Hagg[n][c]*dstn[n] + b3[c]; pooled[g] += h3 ; cnt[g] += 1
// graph_id is sorted -> run-length accumulate, few atomics per block.
__global__ __launch_bounds__(128) void pool_kernel(
    const float* __restrict__ Hagg, const float* __restrict__ dstn,
    const float* __restrict__ b3, const int* __restrict__ gid,
    float* __restrict__ pooled, float* __restrict__ cnt)
{
    __shared__ int gs[NPB];
    __shared__ float ds[NPB];
    int c = threadIdx.x;           // channel 0..127
    int n0 = blockIdx.x * NPB;
    for (int i = c; i < NPB; i += 128) {
        int n = n0 + i;
        gs[i] = (n < Nn) ? gid[n] : -1;
        ds[i] = (n < Nn) ? dstn[n] : 0.f;
    }
    __syncthreads();

    float bc = b3[c];
    int cur = gs[0];
    float acc = 0.f, cn = 0.f;
    for (int i = 0; i < NPB; ++i) {
        int n = n0 + i;
        if (n >= Nn) break;
        int g = gs[i];
        if (g != cur) {
            atomicAdd(&pooled[cur * Dd + c], acc);
            if (c == 0) atomicAdd(&cnt[cur], cn);
            acc = 0.f; cn = 0.f; cur = g;
        }
        acc += Hagg[(size_t)n * Dd + c] * ds[i] + bc;
        cn += 1.f;
    }
    atomicAdd(&pooled[cur * Dd + c], acc);
    if (c == 0) atomicAdd(&cnt[cur], cn);
}

// ---------------- classifier FC + LeakyReLU ----------------
// out[g][m] = lrelu( (sum_k in[g][k]*W[k][m]) * (cnt ? 1/max(cnt[g],1) : 1) + bias[m] )
__global__ void fc_kernel(
    const float* __restrict__ in, const float* __restrict__ Wm,
    const float* __restrict__ bias, float* __restrict__ out,
    const float* __restrict__ cnt, int K, int M)
{
    int idx = blockIdx.x * blockDim.x + threadIdx.x;
    if (idx >= Gg * M) return;
    int g = idx / M, m = idx - g * M;
    const float* inr = in + (size_t)g * K;
    float acc = 0.f;
    for (int k = 0; k < K; ++k) acc += inr[k] * Wm[(size_t)k * M + m];
    if (cnt) acc *= 1.f / fmaxf(cnt[g], 1.f);
    acc += bias[m];
    out[idx] = acc > 0.f ? acc : 0.01f * acc;
}

extern "C" void kernel_launch(void* const* d_in, const int* in_sizes, int n_in,
                              void* d_out, int out_size, void* d_ws, size_t ws_size,
                              hipStream_t stream)
{
    const float* inputs = (const float*)d_in[0];
    const int*   src    = (const int*)d_in[1];
    const int*   dst    = (const int*)d_in[2];
    const int*   gid    = (const int*)d_in[3];
    const float* W1  = (const float*)d_in[4];
    const float* b1  = (const float*)d_in[5];
    const float* W2  = (const float*)d_in[6];
    const float* b2  = (const float*)d_in[7];
    const float* W3  = (const float*)d_in[8];
    const float* b3  = (const float*)d_in[9];
    const float* Wc1 = (const float*)d_in[10];
    const float* bc1 = (const float*)d_in[11];
    const float* Wc2 = (const float*)d_in[12];
    const float* bc2 = (const float*)d_in[13];
    const float* Wc3 = (const float*)d_in[14];
    const float* bc3 = (const float*)d_in[15];

    float* ws     = (float*)d_ws;
    float* srcn   = ws;                          // N (deg -> src_norm)
    float* dstn   = ws + Nn;                     // N (deg -> dst_norm)
    float* bufA   = ws + 2 * Nn;                 // N*D
    float* bufB   = bufA + (size_t)Nn * Dd;      // N*D
    float* pooled = bufB + (size_t)Nn * Dd;      // G*D
    float* cnt    = pooled + Gg * Dd;            // G
    float* c1     = cnt + Gg;                    // G*512
    float* c2     = c1 + Gg * 512;               // G*256

    hipMemsetAsync(srcn, 0, 2 * Nn * sizeof(float), stream);
    degree_kernel<<<(Ee + 255) / 256, 256, 0, stream>>>(src, dst, srcn, dstn);
    norm_kernel<<<(Nn + 255) / 256, 256, 0, stream>>>(srcn, dstn);

    int gblocks = (Nn + 127) / 128;

    // layer 1
    gemm_kernel<<<gblocks, 256, 0, stream>>>(inputs, W1, nullptr, nullptr, srcn, bufA, Nn);
    hipMemsetAsync(bufB, 0, (size_t)Nn * Dd * sizeof(float), stream);
    scatter_kernel<<<(Ee * 32) / 256, 256, 0, stream>>>(bufA, src, dst, bufB);

    // layer 2 (dst_norm+b1 epilogue and src_norm prologue fused into staging)
    gemm_kernel<<<gblocks, 256, 0, stream>>>(bufB, W2, dstn, b1, srcn, bufA, Nn);
    hipMemsetAsync(bufB, 0, (size_t)Nn * Dd * sizeof(float), stream);
    scatter_kernel<<<(Ee * 32) / 256, 256, 0, stream>>>(bufA, src, dst, bufB);

    // layer 3
    gemm_kernel<<<gblocks, 256, 0, stream>>>(bufB, W3, dstn, b2, srcn, bufA, Nn);
    hipMemsetAsync(bufB, 0, (size_t)Nn * Dd * sizeof(float), stream);
    scatter_kernel<<<(Ee * 32) / 256, 256, 0, stream>>>(bufA, src, dst, bufB);

    // mean_nodes (dst_norm+b3 applied here)
    hipMemsetAsync(pooled, 0, (Gg * Dd + Gg) * sizeof(float), stream);
    pool_kernel<<<(Nn + NPB - 1) / NPB, 128, 0, stream>>>(bufB, dstn, b3, gid, pooled, cnt);

    // classifier
    fc_kernel<<<(Gg * 512 + 255) / 256, 256, 0, stream>>>(pooled, Wc1, bc1, c1, cnt, 128, 512);
    fc_kernel<<<(Gg * 256 + 255) / 256, 256, 0, stream>>>(c1, Wc2, bc2, c2, nullptr, 512, 256);
    fc_kernel<<<1, 128, 0, stream>>>(c2, Wc3, bc3, (float*)d_out, nullptr, 256, 10);
}

// Round 2
// 724.977 us; speedup vs baseline: 4.8984x; 4.8984x over previous
//
#include <hip/hip_runtime.h>

#define Nn 50000
#define Ee 600000
#define Gg 8
#define Dd 128
#define NP 50048            // padded N (multiple of 64) for ws layout
#define SCHUNK 1024
#define NCHUNK ((Nn + SCHUNK - 1) / SCHUNK)   // 49

// ---------------- degrees (int) ----------------
__global__ __launch_bounds__(256) void degree_kernel(
    const int* __restrict__ src, const int* __restrict__ dst,
    int* __restrict__ odeg, int* __restrict__ ideg)
{
    int e = blockIdx.x * 256 + threadIdx.x;
    if (e >= Ee) return;
    atomicAdd(&odeg[src[e]], 1);
    atomicAdd(&ideg[dst[e]], 1);
}

__global__ __launch_bounds__(256) void norm_kernel(
    const int* __restrict__ odeg, const int* __restrict__ ideg,
    float* __restrict__ srcn, float* __restrict__ dstn)
{
    int n = blockIdx.x * 256 + threadIdx.x;
    if (n >= Nn) return;
    srcn[n] = 1.f / sqrtf(fmaxf((float)odeg[n], 1.f));
    dstn[n] = 1.f / sqrtf(fmaxf((float)ideg[n], 1.f));
}

// ---------------- prefix scan (exclusive) of ideg -> row_ptr ----------------
__global__ __launch_bounds__(256) void scanA(
    const int* __restrict__ ideg, int* __restrict__ row_ptr, int* __restrict__ bsum)
{
    __shared__ int tsum[256];
    int b = blockIdx.x, t = threadIdx.x;
    int base = b * SCHUNK + t * 4;
    int v[4]; int s = 0;
#pragma unroll
    for (int i = 0; i < 4; ++i) {
        int idx = base + i;
        v[i] = (idx < Nn) ? ideg[idx] : 0;
        s += v[i];
    }
    tsum[t] = s;
    __syncthreads();
    for (int off = 1; off < 256; off <<= 1) {
        int x = (t >= off) ? tsum[t - off] : 0;
        __syncthreads();
        tsum[t] += x;
        __syncthreads();
    }
    int run = tsum[t] - s;          // exclusive within chunk
#pragma unroll
    for (int i = 0; i < 4; ++i) {
        int idx = base + i;
        if (idx < Nn) row_ptr[idx] = run;
        run += v[i];
    }
    if (t == 255) bsum[b] = tsum[255];
}

__global__ void scanB(int* __restrict__ bsum)
{
    int t = threadIdx.x;                 // single wave of 64
    int v = (t < NCHUNK) ? bsum[t] : 0;
    int orig = v;
    for (int off = 1; off < 64; off <<= 1) {
        int x = __shfl_up(v, off, 64);
        if (t >= off) v += x;
    }
    if (t < NCHUNK) bsum[t] = v - orig;  // exclusive
}

__global__ __launch_bounds__(256) void scanC(
    int* __restrict__ row_ptr, const int* __restrict__ bsum, int* __restrict__ cursor)
{
    int n = blockIdx.x * 256 + threadIdx.x;
    if (n >= Nn) return;
    int v = row_ptr[n] + bsum[n / SCHUNK];
    row_ptr[n] = v;
    cursor[n] = v;
    if (n == 0) row_ptr[Nn] = Ee;
}

// ---------------- CSR fill (counting-sort bucket fill) ----------------
__global__ __launch_bounds__(256) void fill_kernel(
    const int* __restrict__ src, const int* __restrict__ dst,
    int* __restrict__ cursor, int* __restrict__ csr_src)
{
    int e = blockIdx.x * 256 + threadIdx.x;
    if (e >= Ee) return;
    int pos = atomicAdd(&cursor[dst[e]], 1);
    csr_src[pos] = src[e];
}

// ---------------- gather SpMM: out[n] = sum_{j in row n} Y[csr_src[j]] ------
// one wave per dst row, float2 per lane (512B coalesced per edge read)
__global__ __launch_bounds__(256) void spmm_kernel(
    const float* __restrict__ Y, const int* __restrict__ row_ptr,
    const int* __restrict__ csr_src, float* __restrict__ out)
{
    int w = threadIdx.x >> 6, lane = threadIdx.x & 63;
    int n = blockIdx.x * 4 + w;
    if (n >= Nn) return;
    int beg = row_ptr[n], end = row_ptr[n + 1];
    const float2* Y2 = (const float2*)Y;
    float ax = 0.f, ay = 0.f;
    int j = beg;
    for (; j + 1 < end; j += 2) {
        int s0 = csr_src[j], s1 = csr_src[j + 1];
        float2 v0 = Y2[(size_t)s0 * 64 + lane];
        float2 v1 = Y2[(size_t)s1 * 64 + lane];
        ax += v0.x + v1.x;
        ay += v0.y + v1.y;
    }
    if (j < end) {
        int s0 = csr_src[j];
        float2 v0 = Y2[(size_t)s0 * 64 + lane];
        ax += v0.x; ay += v0.y;
    }
    float2 o; o.x = ax; o.y = ay;
    ((float2*)out)[(size_t)n * 64 + lane] = o;
}

// ---------------- fused GEMM ----------------
// Y = xeff @ W,  xeff[r][k] = ((a ? X[r][k]*a[r] + bias[k] : X[r][k])) * s[r]
__global__ __launch_bounds__(256) void gemm_kernel(
    const float* __restrict__ X, const float* __restrict__ W,
    const float* __restrict__ a, const float* __restrict__ bias,
    const float* __restrict__ s, float* __restrict__ Y, int nrows)
{
    __shared__ float Ws[128 * 128];
    __shared__ float Xs[128 * 132];   // transposed [k][row], pad 132
    int t = threadIdx.x;

    const float4* W4 = (const float4*)W;
    float4* Ws4 = (float4*)Ws;
#pragma unroll
    for (int i = 0; i < 16; ++i) Ws4[t + 256 * i] = W4[t + 256 * i];

    int row0 = blockIdx.x * 128;
    for (int i = 0; i < 64; ++i) {
        int f = t + 256 * i;
        int r = f >> 7, c = f & 127;
        int row = row0 + r;
        float v = 0.f;
        if (row < nrows) {
            v = X[(size_t)row * Dd + c];
            float sr = s[row];
            if (a) v = v * a[row] + bias[c];
            v *= sr;
        }
        Xs[c * 132 + r] = v;
    }
    __syncthreads();

    int tc = t & 15, tr = t >> 4;
    int r0 = tr * 8, c0 = tc * 4;

    float acc[8][8];
#pragma unroll
    for (int i = 0; i < 8; ++i)
#pragma unroll
        for (int j = 0; j < 8; ++j) acc[i][j] = 0.f;

#pragma unroll 2
    for (int k = 0; k < 128; ++k) {
        const float4 xa = *(const float4*)(Xs + k * 132 + r0);
        const float4 xb = *(const float4*)(Xs + k * 132 + r0 + 4);
        const float4 wa = *(const float4*)(Ws + k * 128 + c0);
        const float4 wb = *(const float4*)(Ws + k * 128 + c0 + 64);
        float xv[8] = {xa.x, xa.y, xa.z, xa.w, xb.x, xb.y, xb.z, xb.w};
        float wv[8] = {wa.x, wa.y, wa.z, wa.w, wb.x, wb.y, wb.z, wb.w};
#pragma unroll
        for (int i = 0; i < 8; ++i)
#pragma unroll
            for (int j = 0; j < 8; ++j)
                acc[i][j] += xv[i] * wv[j];
    }

#pragma unroll
    for (int i = 0; i < 8; ++i) {
        int row = row0 + r0 + i;
        if (row >= nrows) continue;
        float4 o;
        o.x = acc[i][0]; o.y = acc[i][1]; o.z = acc[i][2]; o.w = acc[i][3];
        *(float4*)(Y + (size_t)row * Dd + c0) = o;
        o.x = acc[i][4]; o.y = acc[i][5]; o.z = acc[i][6]; o.w = acc[i][7];
        *(float4*)(Y + (size_t)row * Dd + c0 + 64) = o;
    }
}

// ---------------- mean_nodes pooling ----------------
__global__ __launch_bounds__(128) void pool_kernel(
    const float* __restrict__ Hagg, const float* __restrict__ dstn,
    const float* __restrict__ b3, const int* __restrict__ gid,
    float* __restrict__ pooled, float* __restrict__ cnt)
{
    __shared__ int gs[256];
    __shared__ float ds[256];
    int c = threadIdx.x;
    int n0 = blockIdx.x * 256;
    for (int i = c; i < 256; i += 128) {
        int n = n0 + i;
        gs[i] = (n < Nn) ? gid[n] : -1;
        ds[i] = (n < Nn) ? dstn[n] : 0.f;
    }
    __syncthreads();

    float bc = b3[c];
    int cur = gs[0];
    float acc = 0.f, cn = 0.f;
    for (int i = 0; i < 256; ++i) {
        int n = n0 + i;
        if (n >= Nn) break;
        int g = gs[i];
        if (g != cur) {
            atomicAdd(&pooled[cur * Dd + c], acc);
            if (c == 0) atomicAdd(&cnt[cur], cn);
            acc = 0.f; cn = 0.f; cur = g;
        }
        acc += Hagg[(size_t)n * Dd + c] * ds[i] + bc;
        cn += 1.f;
    }
    atomicAdd(&pooled[cur * Dd + c], acc);
    if (c == 0) atomicAdd(&cnt[cur], cn);
}

// ---------------- classifier FC + LeakyReLU ----------------
__global__ void fc_kernel(
    const float* __restrict__ in, const float* __restrict__ Wm,
    const float* __restrict__ bias, float* __restrict__ out,
    const float* __restrict__ cnt, int K, int M)
{
    int idx = blockIdx.x * blockDim.x + threadIdx.x;
    if (idx >= Gg * M) return;
    int g = idx / M, m = idx - g * M;
    const float* inr = in + (size_t)g * K;
    float acc = 0.f;
    for (int k = 0; k < K; ++k) acc += inr[k] * Wm[(size_t)k * M + m];
    if (cnt) acc *= 1.f / fmaxf(cnt[g], 1.f);
    acc += bias[m];
    out[idx] = acc > 0.f ? acc : 0.01f * acc;
}

extern "C" void kernel_launch(void* const* d_in, const int* in_sizes, int n_in,
                              void* d_out, int out_size, void* d_ws, size_t ws_size,
                              hipStream_t stream)
{
    const float* inputs = (const float*)d_in[0];
    const int*   src    = (const int*)d_in[1];
    const int*   dst    = (const int*)d_in[2];
    const int*   gid    = (const int*)d_in[3];
    const float* W1  = (const float*)d_in[4];
    const float* b1  = (const float*)d_in[5];
    const float* W2  = (const float*)d_in[6];
    const float* b2  = (const float*)d_in[7];
    const float* W3  = (const float*)d_in[8];
    const float* b3  = (const float*)d_in[9];
    const float* Wc1 = (const float*)d_in[10];
    const float* bc1 = (const float*)d_in[11];
    const float* Wc2 = (const float*)d_in[12];
    const float* bc2 = (const float*)d_in[13];
    const float* Wc3 = (const float*)d_in[14];
    const float* bc3 = (const float*)d_in[15];

    // ---- workspace layout (ints first, then floats; all 16B aligned) ----
    int*   wi      = (int*)d_ws;
    int*   odeg    = wi;                 // NP
    int*   ideg    = odeg + NP;          // NP
    int*   row_ptr = ideg + NP;          // NP (uses N+1)
    int*   cursor  = row_ptr + NP;       // NP
    int*   bsum    = cursor + NP;        // 64
    int*   csr_src = bsum + 64;          // Ee
    float* wf      = (float*)(csr_src + Ee);
    float* srcn    = wf;                 // NP
    float* dstn    = srcn + NP;          // NP
    float* bufA    = dstn + NP;          // N*D
    float* bufB    = bufA + (size_t)Nn * Dd;
    float* pooled  = bufB + (size_t)Nn * Dd;   // G*D
    float* cnt     = pooled + Gg * Dd;         // G
    float* c1      = cnt + 8;                  // G*512
    float* c2      = c1 + Gg * 512;            // G*256

    // ---- CSR build ----
    hipMemsetAsync(odeg, 0, 2 * NP * sizeof(int), stream);
    degree_kernel<<<(Ee + 255) / 256, 256, 0, stream>>>(src, dst, odeg, ideg);
    norm_kernel<<<(Nn + 255) / 256, 256, 0, stream>>>(odeg, ideg, srcn, dstn);
    scanA<<<NCHUNK, 256, 0, stream>>>(ideg, row_ptr, bsum);
    scanB<<<1, 64, 0, stream>>>(bsum);
    scanC<<<(Nn + 255) / 256, 256, 0, stream>>>(row_ptr, bsum, cursor);
    fill_kernel<<<(Ee + 255) / 256, 256, 0, stream>>>(src, dst, cursor, csr_src);

    int gblocks = (Nn + 127) / 128;
    int sblocks = (Nn + 3) / 4;

    // layer 1
    gemm_kernel<<<gblocks, 256, 0, stream>>>(inputs, W1, nullptr, nullptr, srcn, bufA, Nn);
    spmm_kernel<<<sblocks, 256, 0, stream>>>(bufA, row_ptr, csr_src, bufB);

    // layer 2 (dst_norm+b1 epilogue and src_norm prologue fused into staging)
    gemm_kernel<<<gblocks, 256, 0, stream>>>(bufB, W2, dstn, b1, srcn, bufA, Nn);
    spmm_kernel<<<sblocks, 256, 0, stream>>>(bufA, row_ptr, csr_src, bufB);

    // layer 3
    gemm_kernel<<<gblocks, 256, 0, stream>>>(bufB, W3, dstn, b2, srcn, bufA, Nn);
    spmm_kernel<<<sblocks, 256, 0, stream>>>(bufA, row_ptr, csr_src, bufB);

    // mean_nodes (dst_norm+b3 applied here)
    hipMemsetAsync(pooled, 0, (Gg * Dd + 8) * sizeof(float), stream);
    pool_kernel<<<(Nn + 255) / 256, 128, 0, stream>>>(bufB, dstn, b3, gid, pooled, cnt);

    // classifier
    fc_kernel<<<(Gg * 512 + 255) / 256, 256, 0, stream>>>(pooled, Wc1, bc1, c1, cnt, 128, 512);
    fc_kernel<<<(Gg * 256 + 255) / 256, 256, 0, stream>>>(c1, Wc2, bc2, c2, nullptr, 512, 256);
    fc_kernel<<<1, 128, 0, stream>>>(c2, Wc3, bc3, (float*)d_out, nullptr, 256, 10);
}

// Round 3
// 559.610 us; speedup vs baseline: 6.3459x; 1.2955x over previous
//
#include <hip/hip_runtime.h>

#define Nn 50000
#define Ee 600000
#define Gg 8
#define Dd 128
#define NP 50048            // padded N (multiple of 64) for ws layout
#define SCHUNK 1024
#define NCHUNK ((Nn + SCHUNK - 1) / SCHUNK)   // 49

// ---------------- degrees (int) ----------------
__global__ __launch_bounds__(256) void degree_kernel(
    const int* __restrict__ src, const int* __restrict__ dst,
    int* __restrict__ odeg, int* __restrict__ ideg)
{
    int e = blockIdx.x * 256 + threadIdx.x;
    if (e >= Ee) return;
    atomicAdd(&odeg[src[e]], 1);
    atomicAdd(&ideg[dst[e]], 1);
}

__global__ __launch_bounds__(256) void norm_kernel(
    const int* __restrict__ odeg, const int* __restrict__ ideg,
    float* __restrict__ srcn, float* __restrict__ dstn)
{
    int n = blockIdx.x * 256 + threadIdx.x;
    if (n >= Nn) return;
    srcn[n] = 1.f / sqrtf(fmaxf((float)odeg[n], 1.f));
    dstn[n] = 1.f / sqrtf(fmaxf((float)ideg[n], 1.f));
}

// ---------------- prefix scan (exclusive) of ideg -> row_ptr ----------------
__global__ __launch_bounds__(256) void scanA(
    const int* __restrict__ ideg, int* __restrict__ row_ptr, int* __restrict__ bsum)
{
    __shared__ int tsum[256];
    int b = blockIdx.x, t = threadIdx.x;
    int base = b * SCHUNK + t * 4;
    int v[4]; int s = 0;
#pragma unroll
    for (int i = 0; i < 4; ++i) {
        int idx = base + i;
        v[i] = (idx < Nn) ? ideg[idx] : 0;
        s += v[i];
    }
    tsum[t] = s;
    __syncthreads();
    for (int off = 1; off < 256; off <<= 1) {
        int x = (t >= off) ? tsum[t - off] : 0;
        __syncthreads();
        tsum[t] += x;
        __syncthreads();
    }
    int run = tsum[t] - s;          // exclusive within chunk
#pragma unroll
    for (int i = 0; i < 4; ++i) {
        int idx = base + i;
        if (idx < Nn) row_ptr[idx] = run;
        run += v[i];
    }
    if (t == 255) bsum[b] = tsum[255];
}

__global__ void scanB(int* __restrict__ bsum)
{
    int t = threadIdx.x;                 // single wave of 64
    int v = (t < NCHUNK) ? bsum[t] : 0;
    int orig = v;
    for (int off = 1; off < 64; off <<= 1) {
        int x = __shfl_up(v, off, 64);
        if (t >= off) v += x;
    }
    if (t < NCHUNK) bsum[t] = v - orig;  // exclusive
}

__global__ __launch_bounds__(256) void scanC(
    int* __restrict__ row_ptr, const int* __restrict__ bsum, int* __restrict__ cursor)
{
    int n = blockIdx.x * 256 + threadIdx.x;
    if (n >= Nn) return;
    int v = row_ptr[n] + bsum[n / SCHUNK];
    row_ptr[n] = v;
    cursor[n] = v;
    if (n == 0) row_ptr[Nn] = Ee;
}

// ---------------- CSR fill (counting-sort bucket fill) ----------------
__global__ __launch_bounds__(256) void fill_kernel(
    const int* __restrict__ src, const int* __restrict__ dst,
    int* __restrict__ cursor, int* __restrict__ csr_src)
{
    int e = blockIdx.x * 256 + threadIdx.x;
    if (e >= Ee) return;
    int pos = atomicAdd(&cursor[dst[e]], 1);
    csr_src[pos] = src[e];
}

// ---------------- gather SpMM: out[n] = sum_{j in row n} Y[csr_src[j]] ------
// one wave per dst row, float2 per lane (512B coalesced per edge read)
__global__ __launch_bounds__(256) void spmm_kernel(
    const float* __restrict__ Y, const int* __restrict__ row_ptr,
    const int* __restrict__ csr_src, float* __restrict__ out)
{
    int w = threadIdx.x >> 6, lane = threadIdx.x & 63;
    int n = blockIdx.x * 4 + w;
    if (n >= Nn) return;
    int beg = row_ptr[n], end = row_ptr[n + 1];
    const float2* Y2 = (const float2*)Y;
    float ax = 0.f, ay = 0.f;
    int j = beg;
    for (; j + 1 < end; j += 2) {
        int s0 = csr_src[j], s1 = csr_src[j + 1];
        float2 v0 = Y2[(size_t)s0 * 64 + lane];
        float2 v1 = Y2[(size_t)s1 * 64 + lane];
        ax += v0.x + v1.x;
        ay += v0.y + v1.y;
    }
    if (j < end) {
        int s0 = csr_src[j];
        float2 v0 = Y2[(size_t)s0 * 64 + lane];
        ax += v0.x; ay += v0.y;
    }
    float2 o; o.x = ax; o.y = ay;
    ((float2*)out)[(size_t)n * 64 + lane] = o;
}

// ---------------- fused GEMM ----------------
// Y = xeff @ W,  xeff[r][k] = ((a ? X[r][k]*a[r] + bias[k] : X[r][k])) * s[r]
__global__ __launch_bounds__(256) void gemm_kernel(
    const float* __restrict__ X, const float* __restrict__ W,
    const float* __restrict__ a, const float* __restrict__ bias,
    const float* __restrict__ s, float* __restrict__ Y, int nrows)
{
    __shared__ float Ws[128 * 128];
    __shared__ float Xs[128 * 132];   // transposed [k][row], pad 132
    int t = threadIdx.x;

    const float4* W4 = (const float4*)W;
    float4* Ws4 = (float4*)Ws;
#pragma unroll
    for (int i = 0; i < 16; ++i) Ws4[t + 256 * i] = W4[t + 256 * i];

    int row0 = blockIdx.x * 128;
    for (int i = 0; i < 64; ++i) {
        int f = t + 256 * i;
        int r = f >> 7, c = f & 127;
        int row = row0 + r;
        float v = 0.f;
        if (row < nrows) {
            v = X[(size_t)row * Dd + c];
            float sr = s[row];
            if (a) v = v * a[row] + bias[c];
            v *= sr;
        }
        Xs[c * 132 + r] = v;
    }
    __syncthreads();

    int tc = t & 15, tr = t >> 4;
    int r0 = tr * 8, c0 = tc * 4;

    float acc[8][8];
#pragma unroll
    for (int i = 0; i < 8; ++i)
#pragma unroll
        for (int j = 0; j < 8; ++j) acc[i][j] = 0.f;

#pragma unroll 2
    for (int k = 0; k < 128; ++k) {
        const float4 xa = *(const float4*)(Xs + k * 132 + r0);
        const float4 xb = *(const float4*)(Xs + k * 132 + r0 + 4);
        const float4 wa = *(const float4*)(Ws + k * 128 + c0);
        const float4 wb = *(const float4*)(Ws + k * 128 + c0 + 64);
        float xv[8] = {xa.x, xa.y, xa.z, xa.w, xb.x, xb.y, xb.z, xb.w};
        float wv[8] = {wa.x, wa.y, wa.z, wa.w, wb.x, wb.y, wb.z, wb.w};
#pragma unroll
        for (int i = 0; i < 8; ++i)
#pragma unroll
            for (int j = 0; j < 8; ++j)
                acc[i][j] += xv[i] * wv[j];
    }

#pragma unroll
    for (int i = 0; i < 8; ++i) {
        int row = row0 + r0 + i;
        if (row >= nrows) continue;
        float4 o;
        o.x = acc[i][0]; o.y = acc[i][1]; o.z = acc[i][2]; o.w = acc[i][3];
        *(float4*)(Y + (size_t)row * Dd + c0) = o;
        o.x = acc[i][4]; o.y = acc[i][5]; o.z = acc[i][6]; o.w = acc[i][7];
        *(float4*)(Y + (size_t)row * Dd + c0 + 64) = o;
    }
}

// ---------------- mean_nodes pooling ----------------
__global__ __launch_bounds__(128) void pool_kernel(
    const float* __restrict__ Hagg, const float* __restrict__ dstn,
    const float* __restrict__ b3, const int* __restrict__ gid,
    float* __restrict__ pooled, float* __restrict__ cnt)
{
    __shared__ int gs[256];
    __shared__ float ds[256];
    int c = threadIdx.x;
    int n0 = blockIdx.x * 256;
    for (int i = c; i < 256; i += 128) {
        int n = n0 + i;
        gs[i] = (n < Nn) ? gid[n] : -1;
        ds[i] = (n < Nn) ? dstn[n] : 0.f;
    }
    __syncthreads();

    float bc = b3[c];
    int cur = gs[0];
    float acc = 0.f, cn = 0.f;
    for (int i = 0; i < 256; ++i) {
        int n = n0 + i;
        if (n >= Nn) break;
        int g = gs[i];
        if (g != cur) {
            atomicAdd(&pooled[cur * Dd + c], acc);
            if (c == 0) atomicAdd(&cnt[cur], cn);
            acc = 0.f; cn = 0.f; cur = g;
        }
        acc += Hagg[(size_t)n * Dd + c] * ds[i] + bc;
        cn += 1.f;
    }
    atomicAdd(&pooled[cur * Dd + c], acc);
    if (c == 0) atomicAdd(&cnt[cur], cn);
}

// ---------------- fused classifier: 1 block, 1024 threads ----------------
// x0 = pooled/cnt; fc1 (128->512, K split 2-way); fc2 (512->256, K split 4-way);
// fc3 (256->10, one wave per output col, shuffle reduce). All LeakyReLU(0.01).
__global__ __launch_bounds__(1024) void classifier_kernel(
    const float* __restrict__ pooled, const float* __restrict__ cnt,
    const float* __restrict__ Wc1, const float* __restrict__ bc1,
    const float* __restrict__ Wc2, const float* __restrict__ bc2,
    const float* __restrict__ Wc3, const float* __restrict__ bc3,
    float* __restrict__ out)
{
    __shared__ float x0[Gg * 128];          // 4 KB
    __shared__ float x1[Gg * 512];          // 16 KB
    __shared__ float x2[Gg * 256];          // 8 KB
    __shared__ float par[4 * Gg * 256];     // 32 KB scratch (viewed 2x8x512 or 4x8x256)
    int t = threadIdx.x;

    if (t < Gg * 128) {
        int g = t >> 7;
        x0[t] = pooled[t] / fmaxf(cnt[g], 1.f);
    }
    __syncthreads();

    // ---- fc1: 512 m-cols, K=128 split into 2 halves of 64 ----
    {
        int m = t & 511, h = t >> 9;          // h in {0,1}
        int k0 = h * 64;
        float acc[Gg];
#pragma unroll
        for (int g = 0; g < Gg; ++g) acc[g] = 0.f;
#pragma unroll 16
        for (int k = 0; k < 64; ++k) {
            float w = Wc1[(size_t)(k0 + k) * 512 + m];
#pragma unroll
            for (int g = 0; g < Gg; ++g) acc[g] += x0[g * 128 + k0 + k] * w;
        }
#pragma unroll
        for (int g = 0; g < Gg; ++g) par[(h * Gg + g) * 512 + m] = acc[g];
    }
    __syncthreads();
    if (t < 512) {
        float b = bc1[t];
#pragma unroll
        for (int g = 0; g < Gg; ++g) {
            float v = par[g * 512 + t] + par[(Gg + g) * 512 + t] + b;
            x1[g * 512 + t] = v > 0.f ? v : 0.01f * v;
        }
    }
    __syncthreads();

    // ---- fc2: 256 m-cols, K=512 split into 4 chunks of 128 ----
    {
        int m = t & 255, h = t >> 8;          // h in {0..3}
        int k0 = h * 128;
        float acc[Gg];
#pragma unroll
        for (int g = 0; g < Gg; ++g) acc[g] = 0.f;
#pragma unroll 16
        for (int k = 0; k < 128; ++k) {
            float w = Wc2[(size_t)(k0 + k) * 256 + m];
#pragma unroll
            for (int g = 0; g < Gg; ++g) acc[g] += x1[g * 512 + k0 + k] * w;
        }
#pragma unroll
        for (int g = 0; g < Gg; ++g) par[(h * Gg + g) * 256 + m] = acc[g];
    }
    __syncthreads();
    if (t < 256) {
        float b = bc2[t];
#pragma unroll
        for (int g = 0; g < Gg; ++g) {
            float v = par[(0 * Gg + g) * 256 + t] + par[(1 * Gg + g) * 256 + t]
                    + par[(2 * Gg + g) * 256 + t] + par[(3 * Gg + g) * 256 + t] + b;
            x2[g * 256 + t] = v > 0.f ? v : 0.01f * v;
        }
    }
    __syncthreads();

    // ---- fc3: 10 outputs, one wave per m, K=256 strided by lane ----
    {
        int w = t >> 6, lane = t & 63;
        if (w < 10) {
            float acc[Gg];
#pragma unroll
            for (int g = 0; g < Gg; ++g) acc[g] = 0.f;
#pragma unroll
            for (int kk = 0; kk < 4; ++kk) {
                int k = lane + kk * 64;
                float wv = Wc3[(size_t)k * 10 + w];
#pragma unroll
                for (int g = 0; g < Gg; ++g) acc[g] += x2[g * 256 + k] * wv;
            }
#pragma unroll
            for (int g = 0; g < Gg; ++g) {
                float v = acc[g];
                for (int off = 32; off; off >>= 1) v += __shfl_down(v, off, 64);
                if (lane == 0) {
                    v += bc3[w];
                    out[g * 10 + w] = v > 0.f ? v : 0.01f * v;
                }
            }
        }
    }
}

extern "C" void kernel_launch(void* const* d_in, const int* in_sizes, int n_in,
                              void* d_out, int out_size, void* d_ws, size_t ws_size,
                              hipStream_t stream)
{
    const float* inputs = (const float*)d_in[0];
    const int*   src    = (const int*)d_in[1];
    const int*   dst    = (const int*)d_in[2];
    const int*   gid    = (const int*)d_in[3];
    const float* W1  = (const float*)d_in[4];
    const float* b1  = (const float*)d_in[5];
    const float* W2  = (const float*)d_in[6];
    const float* b2  = (const float*)d_in[7];
    const float* W3  = (const float*)d_in[8];
    const float* b3  = (const float*)d_in[9];
    const float* Wc1 = (const float*)d_in[10];
    const float* bc1 = (const float*)d_in[11];
    const float* Wc2 = (const float*)d_in[12];
    const float* bc2 = (const float*)d_in[13];
    const float* Wc3 = (const float*)d_in[14];
    const float* bc3 = (const float*)d_in[15];

    // ---- workspace layout (ints first, then floats; all 16B aligned) ----
    int*   wi      = (int*)d_ws;
    int*   odeg    = wi;                 // NP
    int*   ideg    = odeg + NP;          // NP
    int*   row_ptr = ideg + NP;          // NP (uses N+1)
    int*   cursor  = row_ptr + NP;       // NP
    int*   bsum    = cursor + NP;        // 64
    int*   csr_src = bsum + 64;          // Ee
    float* wf      = (float*)(csr_src + Ee);
    float* srcn    = wf;                 // NP
    float* dstn    = srcn + NP;          // NP
    float* bufA    = dstn + NP;          // N*D
    float* bufB    = bufA + (size_t)Nn * Dd;
    float* pooled  = bufB + (size_t)Nn * Dd;   // G*D
    float* cnt     = pooled + Gg * Dd;         // G

    // ---- CSR build ----
    hipMemsetAsync(odeg, 0, 2 * NP * sizeof(int), stream);
    degree_kernel<<<(Ee + 255) / 256, 256, 0, stream>>>(src, dst, odeg, ideg);
    norm_kernel<<<(Nn + 255) / 256, 256, 0, stream>>>(odeg, ideg, srcn, dstn);
    scanA<<<NCHUNK, 256, 0, stream>>>(ideg, row_ptr, bsum);
    scanB<<<1, 64, 0, stream>>>(bsum);
    scanC<<<(Nn + 255) / 256, 256, 0, stream>>>(row_ptr, bsum, cursor);
    fill_kernel<<<(Ee + 255) / 256, 256, 0, stream>>>(src, dst, cursor, csr_src);

    int gblocks = (Nn + 127) / 128;
    int sblocks = (Nn + 3) / 4;

    // layer 1
    gemm_kernel<<<gblocks, 256, 0, stream>>>(inputs, W1, nullptr, nullptr, srcn, bufA, Nn);
    spmm_kernel<<<sblocks, 256, 0, stream>>>(bufA, row_ptr, csr_src, bufB);

    // layer 2 (dst_norm+b1 epilogue and src_norm prologue fused into staging)
    gemm_kernel<<<gblocks, 256, 0, stream>>>(bufB, W2, dstn, b1, srcn, bufA, Nn);
    spmm_kernel<<<sblocks, 256, 0, stream>>>(bufA, row_ptr, csr_src, bufB);

    // layer 3
    gemm_kernel<<<gblocks, 256, 0, stream>>>(bufB, W3, dstn, b2, srcn, bufA, Nn);
    spmm_kernel<<<sblocks, 256, 0, stream>>>(bufA, row_ptr, csr_src, bufB);

    // mean_nodes (dst_norm+b3 applied here)
    hipMemsetAsync(pooled, 0, (Gg * Dd + 8) * sizeof(float), stream);
    pool_kernel<<<(Nn + 255) / 256, 128, 0, stream>>>(bufB, dstn, b3, gid, pooled, cnt);

    // fused classifier (one block)
    classifier_kernel<<<1, 1024, 0, stream>>>(pooled, cnt, Wc1, bc1, Wc2, bc2,
                                              Wc3, bc3, (float*)d_out);
}

// Round 4
// 436.665 us; speedup vs baseline: 8.1326x; 1.2816x over previous
//
#include <hip/hip_runtime.h>

#define Nn 50000
#define Ee 600000
#define Gg 8
#define Dd 128
#define NP 50048            // padded N (multiple of 64) for ws layout
#define SCHUNK 1024
#define NCHUNK ((Nn + SCHUNK - 1) / SCHUNK)   // 49

#define BM 128
#define BN 128
#define BK 32

// ---------------- degrees (int) ----------------
__global__ __launch_bounds__(256) void degree_kernel(
    const int* __restrict__ src, const int* __restrict__ dst,
    int* __restrict__ odeg, int* __restrict__ ideg)
{
    int e = blockIdx.x * 256 + threadIdx.x;
    if (e >= Ee) return;
    atomicAdd(&odeg[src[e]], 1);
    atomicAdd(&ideg[dst[e]], 1);
}

__global__ __launch_bounds__(256) void norm_kernel(
    const int* __restrict__ odeg, const int* __restrict__ ideg,
    float* __restrict__ srcn, float* __restrict__ dstn, float* __restrict__ pq)
{
    int n = blockIdx.x * 256 + threadIdx.x;
    if (n >= Nn) return;
    float sn = 1.f / sqrtf(fmaxf((float)odeg[n], 1.f));
    float dn = 1.f / sqrtf(fmaxf((float)ideg[n], 1.f));
    srcn[n] = sn;
    dstn[n] = dn;
    pq[n] = sn * dn;
}

// ---------------- prefix scan (exclusive) of ideg -> row_ptr ----------------
__global__ __launch_bounds__(256) void scanA(
    const int* __restrict__ ideg, int* __restrict__ row_ptr, int* __restrict__ bsum)
{
    __shared__ int tsum[256];
    int b = blockIdx.x, t = threadIdx.x;
    int base = b * SCHUNK + t * 4;
    int v[4]; int s = 0;
#pragma unroll
    for (int i = 0; i < 4; ++i) {
        int idx = base + i;
        v[i] = (idx < Nn) ? ideg[idx] : 0;
        s += v[i];
    }
    tsum[t] = s;
    __syncthreads();
    for (int off = 1; off < 256; off <<= 1) {
        int x = (t >= off) ? tsum[t - off] : 0;
        __syncthreads();
        tsum[t] += x;
        __syncthreads();
    }
    int run = tsum[t] - s;          // exclusive within chunk
#pragma unroll
    for (int i = 0; i < 4; ++i) {
        int idx = base + i;
        if (idx < Nn) row_ptr[idx] = run;
        run += v[i];
    }
    if (t == 255) bsum[b] = tsum[255];
}

__global__ void scanB(int* __restrict__ bsum)
{
    int t = threadIdx.x;                 // single wave of 64
    int v = (t < NCHUNK) ? bsum[t] : 0;
    int orig = v;
    for (int off = 1; off < 64; off <<= 1) {
        int x = __shfl_up(v, off, 64);
        if (t >= off) v += x;
    }
    if (t < NCHUNK) bsum[t] = v - orig;  // exclusive
}

__global__ __launch_bounds__(256) void scanC(
    int* __restrict__ row_ptr, const int* __restrict__ bsum, int* __restrict__ cursor)
{
    int n = blockIdx.x * 256 + threadIdx.x;
    if (n >= Nn) return;
    int v = row_ptr[n] + bsum[n / SCHUNK];
    row_ptr[n] = v;
    cursor[n] = v;
    if (n == 0) row_ptr[Nn] = Ee;
}

// ---------------- CSR fill (counting-sort bucket fill) ----------------
__global__ __launch_bounds__(256) void fill_kernel(
    const int* __restrict__ src, const int* __restrict__ dst,
    int* __restrict__ cursor, int* __restrict__ csr_src)
{
    int e = blockIdx.x * 256 + threadIdx.x;
    if (e >= Ee) return;
    int pos = atomicAdd(&cursor[dst[e]], 1);
    csr_src[pos] = src[e];
}

// ---------------- gather SpMM: out[n] = sum_{j in row n} Y[csr_src[j]] ------
// one wave per dst row, float2 per lane; edge loop unrolled x4 for MLP
__global__ __launch_bounds__(256) void spmm_kernel(
    const float* __restrict__ Y, const int* __restrict__ row_ptr,
    const int* __restrict__ csr_src, float* __restrict__ out)
{
    int w = threadIdx.x >> 6, lane = threadIdx.x & 63;
    int n = blockIdx.x * 4 + w;
    if (n >= Nn) return;
    int beg = row_ptr[n], end = row_ptr[n + 1];
    const float2* Y2 = (const float2*)Y;
    float ax = 0.f, ay = 0.f;
    int j = beg;
    for (; j + 3 < end; j += 4) {
        int s0 = csr_src[j],     s1 = csr_src[j + 1];
        int s2 = csr_src[j + 2], s3 = csr_src[j + 3];
        float2 v0 = Y2[(size_t)s0 * 64 + lane];
        float2 v1 = Y2[(size_t)s1 * 64 + lane];
        float2 v2 = Y2[(size_t)s2 * 64 + lane];
        float2 v3 = Y2[(size_t)s3 * 64 + lane];
        ax += (v0.x + v1.x) + (v2.x + v3.x);
        ay += (v0.y + v1.y) + (v2.y + v3.y);
    }
    for (; j < end; ++j) {
        int s0 = csr_src[j];
        float2 v0 = Y2[(size_t)s0 * 64 + lane];
        ax += v0.x; ay += v0.y;
    }
    float2 o; o.x = ax; o.y = ay;
    ((float2*)out)[(size_t)n * 64 + lane] = o;
}

// ---------------- fused GEMM (BK=32 double-buffered, 2 blocks/CU) ----------
// Y = xeff @ W,  xeff[r][k] = X[r][k]*p[r] + bias[k]*s[r]
//   layer 1: p=srcn, bias=null                  (-> X*srcn)
//   layer 2/3: p=srcn*dstn, bias=b_prev, s=srcn (-> ((X*dstn)+b)*srcn)
__global__ __launch_bounds__(512, 4) void gemm_kernel(
    const float* __restrict__ X, const float* __restrict__ W,
    const float* __restrict__ p, const float* __restrict__ bias,
    const float* __restrict__ s, float* __restrict__ Y, int nrows)
{
    __shared__ float Xs[2][BK][BM + 4];   // transposed [k][row]
    __shared__ float Ws[2][BK][BN];
    int t = threadIdx.x;
    int row0 = blockIdx.x * BM;

    // staging assignment: 1024 float4 items each for X and W, 2 per thread
    int xrow0 = t >> 3;             // item t   : rows 0..63
    int xq = (t & 7) * 4;           // k-quad offset within chunk (same for both items)
    int wk0 = t >> 5;               // W k-row 0..15
    int wn = (t & 31) * 4;

    // per-row factors (constant across chunks)
    float pr[2] = {0.f, 0.f}, sr[2] = {0.f, 0.f};
#pragma unroll
    for (int h = 0; h < 2; ++h) {
        int gr = row0 + xrow0 + h * 64;
        if (gr < nrows) {
            pr[h] = p[gr];
            sr[h] = bias ? s[gr] : 0.f;
        }
    }

    float4 xv[2], wv[2], bv[2];

    auto LOAD = [&](int ch) {
        int k0 = ch * BK;
#pragma unroll
        for (int h = 0; h < 2; ++h) {
            int gr = row0 + xrow0 + h * 64;
            int kk = k0 + xq;
            if (gr < nrows) xv[h] = *(const float4*)(X + (size_t)gr * Dd + kk);
            else            xv[h] = make_float4(0.f, 0.f, 0.f, 0.f);
            if (bias)       bv[h] = *(const float4*)(bias + kk);
            else            bv[h] = make_float4(0.f, 0.f, 0.f, 0.f);
            wv[h] = *(const float4*)(W + (size_t)(k0 + wk0 + h * 16) * Dd + wn);
        }
    };
    auto STORE = [&](int buf) {
#pragma unroll
        for (int h = 0; h < 2; ++h) {
            int r = xrow0 + h * 64;
            float vx = xv[h].x * pr[h] + bv[h].x * sr[h];
            float vy = xv[h].y * pr[h] + bv[h].y * sr[h];
            float vz = xv[h].z * pr[h] + bv[h].z * sr[h];
            float vw = xv[h].w * pr[h] + bv[h].w * sr[h];
            Xs[buf][xq + 0][r] = vx;
            Xs[buf][xq + 1][r] = vy;
            Xs[buf][xq + 2][r] = vz;
            Xs[buf][xq + 3][r] = vw;
            *(float4*)&Ws[buf][wk0 + h * 16][wn] = wv[h];
        }
    };

    int tc = t & 31, tr = t >> 5;
    int c0 = tc * 4, r0 = tr * 8;

    float acc[8][4];
#pragma unroll
    for (int i = 0; i < 8; ++i)
#pragma unroll
        for (int j = 0; j < 4; ++j) acc[i][j] = 0.f;

    LOAD(0); STORE(0);
    __syncthreads();

#pragma unroll
    for (int ch = 0; ch < Dd / BK; ++ch) {
        int cur = ch & 1;
        if (ch < Dd / BK - 1) LOAD(ch + 1);   // issue next-chunk loads early
#pragma unroll 8
        for (int k = 0; k < BK; ++k) {
            float4 xa = *(const float4*)&Xs[cur][k][r0];
            float4 xb = *(const float4*)&Xs[cur][k][r0 + 4];
            float4 wa = *(const float4*)&Ws[cur][k][c0];
            float xr[8] = {xa.x, xa.y, xa.z, xa.w, xb.x, xb.y, xb.z, xb.w};
            float wr[4] = {wa.x, wa.y, wa.z, wa.w};
#pragma unroll
            for (int i = 0; i < 8; ++i)
#pragma unroll
                for (int j = 0; j < 4; ++j)
                    acc[i][j] += xr[i] * wr[j];
        }
        if (ch < Dd / BK - 1) {
            STORE(cur ^ 1);                    // write the other buffer
            __syncthreads();
        }
    }

#pragma unroll
    for (int i = 0; i < 8; ++i) {
        int row = row0 + r0 + i;
        if (row < nrows) {
            float4 o = {acc[i][0], acc[i][1], acc[i][2], acc[i][3]};
            *(float4*)(Y + (size_t)row * Dd + c0) = o;
        }
    }
}

// ---------------- mean_nodes pooling ----------------
__global__ __launch_bounds__(128) void pool_kernel(
    const float* __restrict__ Hagg, const float* __restrict__ dstn,
    const float* __restrict__ b3, const int* __restrict__ gid,
    float* __restrict__ pooled, float* __restrict__ cnt)
{
    __shared__ int gs[256];
    __shared__ float ds[256];
    int c = threadIdx.x;
    int n0 = blockIdx.x * 256;
    for (int i = c; i < 256; i += 128) {
        int n = n0 + i;
        gs[i] = (n < Nn) ? gid[n] : -1;
        ds[i] = (n < Nn) ? dstn[n] : 0.f;
    }
    __syncthreads();

    float bc = b3[c];
    int cur = gs[0];
    float acc = 0.f, cn = 0.f;
    for (int i = 0; i < 256; ++i) {
        int n = n0 + i;
        if (n >= Nn) break;
        int g = gs[i];
        if (g != cur) {
            atomicAdd(&pooled[cur * Dd + c], acc);
            if (c == 0) atomicAdd(&cnt[cur], cn);
            acc = 0.f; cn = 0.f; cur = g;
        }
        acc += Hagg[(size_t)n * Dd + c] * ds[i] + bc;
        cn += 1.f;
    }
    atomicAdd(&pooled[cur * Dd + c], acc);
    if (c == 0) atomicAdd(&cnt[cur], cn);
}

// ---------------- fused classifier: 1 block, 1024 threads ----------------
__global__ __launch_bounds__(1024) void classifier_kernel(
    const float* __restrict__ pooled, const float* __restrict__ cnt,
    const float* __restrict__ Wc1, const float* __restrict__ bc1,
    const float* __restrict__ Wc2, const float* __restrict__ bc2,
    const float* __restrict__ Wc3, const float* __restrict__ bc3,
    float* __restrict__ out)
{
    __shared__ float x0[Gg * 128];
    __shared__ float x1[Gg * 512];
    __shared__ float x2[Gg * 256];
    __shared__ float par[4 * Gg * 256];
    int t = threadIdx.x;

    if (t < Gg * 128) {
        int g = t >> 7;
        x0[t] = pooled[t] / fmaxf(cnt[g], 1.f);
    }
    __syncthreads();

    // ---- fc1: 512 m-cols, K=128 split into 2 halves of 64 ----
    {
        int m = t & 511, h = t >> 9;
        int k0 = h * 64;
        float acc[Gg];
#pragma unroll
        for (int g = 0; g < Gg; ++g) acc[g] = 0.f;
#pragma unroll 16
        for (int k = 0; k < 64; ++k) {
            float w = Wc1[(size_t)(k0 + k) * 512 + m];
#pragma unroll
            for (int g = 0; g < Gg; ++g) acc[g] += x0[g * 128 + k0 + k] * w;
        }
#pragma unroll
        for (int g = 0; g < Gg; ++g) par[(h * Gg + g) * 512 + m] = acc[g];
    }
    __syncthreads();
    if (t < 512) {
        float b = bc1[t];
#pragma unroll
        for (int g = 0; g < Gg; ++g) {
            float v = par[g * 512 + t] + par[(Gg + g) * 512 + t] + b;
            x1[g * 512 + t] = v > 0.f ? v : 0.01f * v;
        }
    }
    __syncthreads();

    // ---- fc2: 256 m-cols, K=512 split into 4 chunks of 128 ----
    {
        int m = t & 255, h = t >> 8;
        int k0 = h * 128;
        float acc[Gg];
#pragma unroll
        for (int g = 0; g < Gg; ++g) acc[g] = 0.f;
#pragma unroll 16
        for (int k = 0; k < 128; ++k) {
            float w = Wc2[(size_t)(k0 + k) * 256 + m];
#pragma unroll
            for (int g = 0; g < Gg; ++g) acc[g] += x1[g * 512 + k0 + k] * w;
        }
#pragma unroll
        for (int g = 0; g < Gg; ++g) par[(h * Gg + g) * 256 + m] = acc[g];
    }
    __syncthreads();
    if (t < 256) {
        float b = bc2[t];
#pragma unroll
        for (int g = 0; g < Gg; ++g) {
            float v = par[(0 * Gg + g) * 256 + t] + par[(1 * Gg + g) * 256 + t]
                    + par[(2 * Gg + g) * 256 + t] + par[(3 * Gg + g) * 256 + t] + b;
            x2[g * 256 + t] = v > 0.f ? v : 0.01f * v;
        }
    }
    __syncthreads();

    // ---- fc3: 10 outputs, one wave per m, K=256 strided by lane ----
    {
        int w = t >> 6, lane = t & 63;
        if (w < 10) {
            float acc[Gg];
#pragma unroll
            for (int g = 0; g < Gg; ++g) acc[g] = 0.f;
#pragma unroll
            for (int kk = 0; kk < 4; ++kk) {
                int k = lane + kk * 64;
                float wv = Wc3[(size_t)k * 10 + w];
#pragma unroll
                for (int g = 0; g < Gg; ++g) acc[g] += x2[g * 256 + k] * wv;
            }
#pragma unroll
            for (int g = 0; g < Gg; ++g) {
                float v = acc[g];
                for (int off = 32; off; off >>= 1) v += __shfl_down(v, off, 64);
                if (lane == 0) {
                    v += bc3[w];
                    out[g * 10 + w] = v > 0.f ? v : 0.01f * v;
                }
            }
        }
    }
}

extern "C" void kernel_launch(void* const* d_in, const int* in_sizes, int n_in,
                              void* d_out, int out_size, void* d_ws, size_t ws_size,
                              hipStream_t stream)
{
    const float* inputs = (const float*)d_in[0];
    const int*   src    = (const int*)d_in[1];
    const int*   dst    = (const int*)d_in[2];
    const int*   gid    = (const int*)d_in[3];
    const float* W1  = (const float*)d_in[4];
    const float* b1  = (const float*)d_in[5];
    const float* W2  = (const float*)d_in[6];
    const float* b2  = (const float*)d_in[7];
    const float* W3  = (const float*)d_in[8];
    const float* b3  = (const float*)d_in[9];
    const float* Wc1 = (const float*)d_in[10];
    const float* bc1 = (const float*)d_in[11];
    const float* Wc2 = (const float*)d_in[12];
    const float* bc2 = (const float*)d_in[13];
    const float* Wc3 = (const float*)d_in[14];
    const float* bc3 = (const float*)d_in[15];

    // ---- workspace layout ----
    int*   wi      = (int*)d_ws;
    int*   odeg    = wi;                 // NP
    int*   ideg    = odeg + NP;          // NP
    int*   row_ptr = ideg + NP;          // NP (uses N+1)
    int*   cursor  = row_ptr + NP;       // NP
    int*   bsum    = cursor + NP;        // 64
    int*   csr_src = bsum + 64;          // Ee
    float* wf      = (float*)(csr_src + Ee);
    float* srcn    = wf;                 // NP
    float* dstn    = srcn + NP;          // NP
    float* pq      = dstn + NP;          // NP (srcn*dstn)
    float* bufA    = pq + NP;            // N*D
    float* bufB    = bufA + (size_t)Nn * Dd;
    float* pooled  = bufB + (size_t)Nn * Dd;   // G*D
    float* cnt     = pooled + Gg * Dd;         // G

    // ---- CSR build ----
    hipMemsetAsync(odeg, 0, 2 * NP * sizeof(int), stream);
    degree_kernel<<<(Ee + 255) / 256, 256, 0, stream>>>(src, dst, odeg, ideg);
    norm_kernel<<<(Nn + 255) / 256, 256, 0, stream>>>(odeg, ideg, srcn, dstn, pq);
    scanA<<<NCHUNK, 256, 0, stream>>>(ideg, row_ptr, bsum);
    scanB<<<1, 64, 0, stream>>>(bsum);
    scanC<<<(Nn + 255) / 256, 256, 0, stream>>>(row_ptr, bsum, cursor);
    fill_kernel<<<(Ee + 255) / 256, 256, 0, stream>>>(src, dst, cursor, csr_src);

    int gblocks = (Nn + BM - 1) / BM;
    int sblocks = (Nn + 3) / 4;

    // layer 1: xeff = X*srcn
    gemm_kernel<<<gblocks, 512, 0, stream>>>(inputs, W1, srcn, nullptr, nullptr, bufA, Nn);
    spmm_kernel<<<sblocks, 256, 0, stream>>>(bufA, row_ptr, csr_src, bufB);

    // layer 2: xeff = X*(srcn*dstn) + b1*srcn
    gemm_kernel<<<gblocks, 512, 0, stream>>>(bufB, W2, pq, b1, srcn, bufA, Nn);
    spmm_kernel<<<sblocks, 256, 0, stream>>>(bufA, row_ptr, csr_src, bufB);

    // layer 3
    gemm_kernel<<<gblocks, 512, 0, stream>>>(bufB, W3, pq, b2, srcn, bufA, Nn);
    spmm_kernel<<<sblocks, 256, 0, stream>>>(bufA, row_ptr, csr_src, bufB);

    // mean_nodes (dst_norm+b3 applied here)
    hipMemsetAsync(pooled, 0, (Gg * Dd + 8) * sizeof(float), stream);
    pool_kernel<<<(Nn + 255) / 256, 128, 0, stream>>>(bufB, dstn, b3, gid, pooled, cnt);

    // fused classifier (one block)
    classifier_kernel<<<1, 1024, 0, stream>>>(pooled, cnt, Wc1, bc1, Wc2, bc2,
                                              Wc3, bc3, (float*)d_out);
}

// Round 5
// 369.177 us; speedup vs baseline: 9.6193x; 1.1828x over previous
//
#include <hip/hip_runtime.h>

#define Nn 50000
#define Ee 600000
#define Gg 8
#define Dd 128
#define NP 50048            // padded N (multiple of 64) for ws layout
#define SCHUNK 1024
#define NCHUNK ((Nn + SCHUNK - 1) / SCHUNK)   // 49

#define BM 128
#define BN 128
#define BK 32

// ---------------- degrees (int) ----------------
__global__ __launch_bounds__(256) void degree_kernel(
    const int* __restrict__ src, const int* __restrict__ dst,
    int* __restrict__ odeg, int* __restrict__ ideg)
{
    int e = blockIdx.x * 256 + threadIdx.x;
    if (e >= Ee) return;
    atomicAdd(&odeg[src[e]], 1);
    atomicAdd(&ideg[dst[e]], 1);
}

__global__ __launch_bounds__(256) void norm_kernel(
    const int* __restrict__ odeg, const int* __restrict__ ideg,
    float* __restrict__ srcn, float* __restrict__ dstn, float* __restrict__ pq)
{
    int n = blockIdx.x * 256 + threadIdx.x;
    if (n >= Nn) return;
    float sn = 1.f / sqrtf(fmaxf((float)odeg[n], 1.f));
    float dn = 1.f / sqrtf(fmaxf((float)ideg[n], 1.f));
    srcn[n] = sn;
    dstn[n] = dn;
    pq[n] = sn * dn;
}

// ---------------- prefix scan (exclusive) of ideg -> row_ptr ----------------
__global__ __launch_bounds__(256) void scanA(
    const int* __restrict__ ideg, int* __restrict__ row_ptr, int* __restrict__ bsum)
{
    __shared__ int tsum[256];
    int b = blockIdx.x, t = threadIdx.x;
    int base = b * SCHUNK + t * 4;
    int v[4]; int s = 0;
#pragma unroll
    for (int i = 0; i < 4; ++i) {
        int idx = base + i;
        v[i] = (idx < Nn) ? ideg[idx] : 0;
        s += v[i];
    }
    tsum[t] = s;
    __syncthreads();
    for (int off = 1; off < 256; off <<= 1) {
        int x = (t >= off) ? tsum[t - off] : 0;
        __syncthreads();
        tsum[t] += x;
        __syncthreads();
    }
    int run = tsum[t] - s;          // exclusive within chunk
#pragma unroll
    for (int i = 0; i < 4; ++i) {
        int idx = base + i;
        if (idx < Nn) row_ptr[idx] = run;
        run += v[i];
    }
    if (t == 255) bsum[b] = tsum[255];
}

__global__ void scanB(int* __restrict__ bsum)
{
    int t = threadIdx.x;                 // single wave of 64
    int v = (t < NCHUNK) ? bsum[t] : 0;
    int orig = v;
    for (int off = 1; off < 64; off <<= 1) {
        int x = __shfl_up(v, off, 64);
        if (t >= off) v += x;
    }
    if (t < NCHUNK) bsum[t] = v - orig;  // exclusive
}

__global__ __launch_bounds__(256) void scanC(
    int* __restrict__ row_ptr, const int* __restrict__ bsum, int* __restrict__ cursor)
{
    int n = blockIdx.x * 256 + threadIdx.x;
    if (n >= Nn) return;
    int v = row_ptr[n] + bsum[n / SCHUNK];
    row_ptr[n] = v;
    cursor[n] = v;
    if (n == 0) row_ptr[Nn] = Ee;
}

// ---------------- CSR fill (counting-sort bucket fill) ----------------
__global__ __launch_bounds__(256) void fill_kernel(
    const int* __restrict__ src, const int* __restrict__ dst,
    int* __restrict__ cursor, int* __restrict__ csr_src)
{
    int e = blockIdx.x * 256 + threadIdx.x;
    if (e >= Ee) return;
    int pos = atomicAdd(&cursor[dst[e]], 1);
    csr_src[pos] = src[e];
}

// ---------------- gather SpMM: out[n] = sum_{j in row n} Y[csr_src[j]] ------
// one wave per dst row, float2 per lane; edge loop unrolled x4 for MLP
__global__ __launch_bounds__(256) void spmm_kernel(
    const float* __restrict__ Y, const int* __restrict__ row_ptr,
    const int* __restrict__ csr_src, float* __restrict__ out)
{
    int w = threadIdx.x >> 6, lane = threadIdx.x & 63;
    int n = blockIdx.x * 4 + w;
    if (n >= Nn) return;
    int beg = row_ptr[n], end = row_ptr[n + 1];
    const float2* Y2 = (const float2*)Y;
    float ax = 0.f, ay = 0.f;
    int j = beg;
    for (; j + 3 < end; j += 4) {
        int s0 = csr_src[j],     s1 = csr_src[j + 1];
        int s2 = csr_src[j + 2], s3 = csr_src[j + 3];
        float2 v0 = Y2[(size_t)s0 * 64 + lane];
        float2 v1 = Y2[(size_t)s1 * 64 + lane];
        float2 v2 = Y2[(size_t)s2 * 64 + lane];
        float2 v3 = Y2[(size_t)s3 * 64 + lane];
        ax += (v0.x + v1.x) + (v2.x + v3.x);
        ay += (v0.y + v1.y) + (v2.y + v3.y);
    }
    for (; j < end; ++j) {
        int s0 = csr_src[j];
        float2 v0 = Y2[(size_t)s0 * 64 + lane];
        ax += v0.x; ay += v0.y;
    }
    float2 o; o.x = ax; o.y = ay;
    ((float2*)out)[(size_t)n * 64 + lane] = o;
}

// ---------------- fused GEMM (BK=32 double-buffered, 2 blocks/CU) ----------
// Y = xeff @ W,  xeff[r][k] = X[r][k]*p[r] + bias[k]*s[r]
__global__ __launch_bounds__(512, 4) void gemm_kernel(
    const float* __restrict__ X, const float* __restrict__ W,
    const float* __restrict__ p, const float* __restrict__ bias,
    const float* __restrict__ s, float* __restrict__ Y, int nrows)
{
    __shared__ float Xs[2][BK][BM + 4];   // transposed [k][row]
    __shared__ float Ws[2][BK][BN];
    int t = threadIdx.x;
    int row0 = blockIdx.x * BM;

    int xrow0 = t >> 3;             // rows 0..63
    int xq = (t & 7) * 4;           // k-quad offset within chunk
    int wk0 = t >> 5;               // W k-row 0..15
    int wn = (t & 31) * 4;

    float pr[2] = {0.f, 0.f}, sr[2] = {0.f, 0.f};
#pragma unroll
    for (int h = 0; h < 2; ++h) {
        int gr = row0 + xrow0 + h * 64;
        if (gr < nrows) {
            pr[h] = p[gr];
            sr[h] = bias ? s[gr] : 0.f;
        }
    }

    float4 xv[2], wv[2], bv[2];

    auto LOAD = [&](int ch) {
        int k0 = ch * BK;
#pragma unroll
        for (int h = 0; h < 2; ++h) {
            int gr = row0 + xrow0 + h * 64;
            int kk = k0 + xq;
            if (gr < nrows) xv[h] = *(const float4*)(X + (size_t)gr * Dd + kk);
            else            xv[h] = make_float4(0.f, 0.f, 0.f, 0.f);
            if (bias)       bv[h] = *(const float4*)(bias + kk);
            else            bv[h] = make_float4(0.f, 0.f, 0.f, 0.f);
            wv[h] = *(const float4*)(W + (size_t)(k0 + wk0 + h * 16) * Dd + wn);
        }
    };
    auto STORE = [&](int buf) {
#pragma unroll
        for (int h = 0; h < 2; ++h) {
            int r = xrow0 + h * 64;
            float vx = xv[h].x * pr[h] + bv[h].x * sr[h];
            float vy = xv[h].y * pr[h] + bv[h].y * sr[h];
            float vz = xv[h].z * pr[h] + bv[h].z * sr[h];
            float vw = xv[h].w * pr[h] + bv[h].w * sr[h];
            Xs[buf][xq + 0][r] = vx;
            Xs[buf][xq + 1][r] = vy;
            Xs[buf][xq + 2][r] = vz;
            Xs[buf][xq + 3][r] = vw;
            *(float4*)&Ws[buf][wk0 + h * 16][wn] = wv[h];
        }
    };

    int tc = t & 31, tr = t >> 5;
    int c0 = tc * 4, r0 = tr * 8;

    float acc[8][4];
#pragma unroll
    for (int i = 0; i < 8; ++i)
#pragma unroll
        for (int j = 0; j < 4; ++j) acc[i][j] = 0.f;

    LOAD(0); STORE(0);
    __syncthreads();

#pragma unroll
    for (int ch = 0; ch < Dd / BK; ++ch) {
        int cur = ch & 1;
        if (ch < Dd / BK - 1) LOAD(ch + 1);   // issue next-chunk loads early
#pragma unroll 8
        for (int k = 0; k < BK; ++k) {
            float4 xa = *(const float4*)&Xs[cur][k][r0];
            float4 xb = *(const float4*)&Xs[cur][k][r0 + 4];
            float4 wa = *(const float4*)&Ws[cur][k][c0];
            float xr[8] = {xa.x, xa.y, xa.z, xa.w, xb.x, xb.y, xb.z, xb.w};
            float wr[4] = {wa.x, wa.y, wa.z, wa.w};
#pragma unroll
            for (int i = 0; i < 8; ++i)
#pragma unroll
                for (int j = 0; j < 4; ++j)
                    acc[i][j] += xr[i] * wr[j];
        }
        if (ch < Dd / BK - 1) {
            STORE(cur ^ 1);                    // write the other buffer
            __syncthreads();
        }
    }

#pragma unroll
    for (int i = 0; i < 8; ++i) {
        int row = row0 + r0 + i;
        if (row < nrows) {
            float4 o = {acc[i][0], acc[i][1], acc[i][2], acc[i][3]};
            *(float4*)(Y + (size_t)row * Dd + c0) = o;
        }
    }
}

// ---------------- mean_nodes pooling (parallel tiled reduction) ----------
// pooled[g][c] += sum_n Hagg[n][c]*dstn[n] ; cnt[g] += #nodes
// 128 nodes/block, 256 threads: thread (r0,c4) strides 16 rows of float4.
__global__ __launch_bounds__(256) void pool_kernel(
    const float* __restrict__ Hagg, const float* __restrict__ dstn,
    const int* __restrict__ gid, float* __restrict__ pooled, int* __restrict__ cnt)
{
    __shared__ int gs[128];
    __shared__ float ds[128];
    __shared__ float sp[Gg][Dd];
    __shared__ int lcnt[Gg];
    int t = threadIdx.x;
    int n0 = blockIdx.x * 128;

    for (int i = t; i < Gg * Dd; i += 256) sp[i >> 7][i & 127] = 0.f;
    if (t < Gg) lcnt[t] = 0;
    if (t < 128) {
        int n = n0 + t;
        gs[t] = (n < Nn) ? gid[n] : -1;
        ds[t] = (n < Nn) ? dstn[n] : 0.f;
    }
    __syncthreads();
    if (t < 128 && gs[t] >= 0) atomicAdd(&lcnt[gs[t]], 1);

    int c4 = (t & 31) * 4, r0 = t >> 5;
    float4 acc = {0.f, 0.f, 0.f, 0.f};
    int cur = -1;
    for (int i = r0; i < 128; i += 8) {
        int g = gs[i];
        if (g < 0) break;
        if (g != cur) {
            if (cur >= 0) {
                atomicAdd(&sp[cur][c4 + 0], acc.x);
                atomicAdd(&sp[cur][c4 + 1], acc.y);
                atomicAdd(&sp[cur][c4 + 2], acc.z);
                atomicAdd(&sp[cur][c4 + 3], acc.w);
            }
            acc = make_float4(0.f, 0.f, 0.f, 0.f);
            cur = g;
        }
        float4 v = *(const float4*)(Hagg + (size_t)(n0 + i) * Dd + c4);
        float d = ds[i];
        acc.x += v.x * d; acc.y += v.y * d;
        acc.z += v.z * d; acc.w += v.w * d;
    }
    if (cur >= 0) {
        atomicAdd(&sp[cur][c4 + 0], acc.x);
        atomicAdd(&sp[cur][c4 + 1], acc.y);
        atomicAdd(&sp[cur][c4 + 2], acc.z);
        atomicAdd(&sp[cur][c4 + 3], acc.w);
    }
    __syncthreads();
    for (int i = t; i < Gg * Dd; i += 256) {
        int g = i >> 7;
        if (lcnt[g] > 0) atomicAdd(&pooled[i], sp[g][i & 127]);
    }
    if (t < Gg && lcnt[t] > 0) atomicAdd(&cnt[t], lcnt[t]);
}

// ---------------- fused classifier: 1 block, 1024 threads ----------------
// x0 = pooled/cnt + b3 ; fc1; fc2; fc3. All LeakyReLU(0.01).
__global__ __launch_bounds__(1024) void classifier_kernel(
    const float* __restrict__ pooled, const int* __restrict__ cnt,
    const float* __restrict__ b3,
    const float* __restrict__ Wc1, const float* __restrict__ bc1,
    const float* __restrict__ Wc2, const float* __restrict__ bc2,
    const float* __restrict__ Wc3, const float* __restrict__ bc3,
    float* __restrict__ out)
{
    __shared__ float x0[Gg * 128];
    __shared__ float x1[Gg * 512];
    __shared__ float x2[Gg * 256];
    __shared__ float par[4 * Gg * 256];
    int t = threadIdx.x;

    if (t < Gg * 128) {
        int g = t >> 7, c = t & 127;
        x0[t] = pooled[t] / fmaxf((float)cnt[g], 1.f) + b3[c];
    }
    __syncthreads();

    // ---- fc1: 512 m-cols, K=128 split into 2 halves of 64 ----
    {
        int m = t & 511, h = t >> 9;
        int k0 = h * 64;
        float acc[Gg];
#pragma unroll
        for (int g = 0; g < Gg; ++g) acc[g] = 0.f;
#pragma unroll 16
        for (int k = 0; k < 64; ++k) {
            float w = Wc1[(size_t)(k0 + k) * 512 + m];
#pragma unroll
            for (int g = 0; g < Gg; ++g) acc[g] += x0[g * 128 + k0 + k] * w;
        }
#pragma unroll
        for (int g = 0; g < Gg; ++g) par[(h * Gg + g) * 512 + m] = acc[g];
    }
    __syncthreads();
    if (t < 512) {
        float b = bc1[t];
#pragma unroll
        for (int g = 0; g < Gg; ++g) {
            float v = par[g * 512 + t] + par[(Gg + g) * 512 + t] + b;
            x1[g * 512 + t] = v > 0.f ? v : 0.01f * v;
        }
    }
    __syncthreads();

    // ---- fc2: 256 m-cols, K=512 split into 4 chunks of 128 ----
    {
        int m = t & 255, h = t >> 8;
        int k0 = h * 128;
        float acc[Gg];
#pragma unroll
        for (int g = 0; g < Gg; ++g) acc[g] = 0.f;
#pragma unroll 16
        for (int k = 0; k < 128; ++k) {
            float w = Wc2[(size_t)(k0 + k) * 256 + m];
#pragma unroll
            for (int g = 0; g < Gg; ++g) acc[g] += x1[g * 512 + k0 + k] * w;
        }
#pragma unroll
        for (int g = 0; g < Gg; ++g) par[(h * Gg + g) * 256 + m] = acc[g];
    }
    __syncthreads();
    if (t < 256) {
        float b = bc2[t];
#pragma unroll
        for (int g = 0; g < Gg; ++g) {
            float v = par[(0 * Gg + g) * 256 + t] + par[(1 * Gg + g) * 256 + t]
                    + par[(2 * Gg + g) * 256 + t] + par[(3 * Gg + g) * 256 + t] + b;
            x2[g * 256 + t] = v > 0.f ? v : 0.01f * v;
        }
    }
    __syncthreads();

    // ---- fc3: 10 outputs, one wave per m, K=256 strided by lane ----
    {
        int w = t >> 6, lane = t & 63;
        if (w < 10) {
            float acc[Gg];
#pragma unroll
            for (int g = 0; g < Gg; ++g) acc[g] = 0.f;
#pragma unroll
            for (int kk = 0; kk < 4; ++kk) {
                int k = lane + kk * 64;
                float wv = Wc3[(size_t)k * 10 + w];
#pragma unroll
                for (int g = 0; g < Gg; ++g) acc[g] += x2[g * 256 + k] * wv;
            }
#pragma unroll
            for (int g = 0; g < Gg; ++g) {
                float v = acc[g];
                for (int off = 32; off; off >>= 1) v += __shfl_down(v, off, 64);
                if (lane == 0) {
                    v += bc3[w];
                    out[g * 10 + w] = v > 0.f ? v : 0.01f * v;
                }
            }
        }
    }
}

extern "C" void kernel_launch(void* const* d_in, const int* in_sizes, int n_in,
                              void* d_out, int out_size, void* d_ws, size_t ws_size,
                              hipStream_t stream)
{
    const float* inputs = (const float*)d_in[0];
    const int*   src    = (const int*)d_in[1];
    const int*   dst    = (const int*)d_in[2];
    const int*   gid    = (const int*)d_in[3];
    const float* W1  = (const float*)d_in[4];
    const float* b1  = (const float*)d_in[5];
    const float* W2  = (const float*)d_in[6];
    const float* b2  = (const float*)d_in[7];
    const float* W3  = (const float*)d_in[8];
    const float* b3  = (const float*)d_in[9];
    const float* Wc1 = (const float*)d_in[10];
    const float* bc1 = (const float*)d_in[11];
    const float* Wc2 = (const float*)d_in[12];
    const float* bc2 = (const float*)d_in[13];
    const float* Wc3 = (const float*)d_in[14];
    const float* bc3 = (const float*)d_in[15];

    // ---- workspace layout ----
    int*   wi      = (int*)d_ws;
    int*   odeg    = wi;                 // NP
    int*   ideg    = odeg + NP;          // NP
    int*   row_ptr = ideg + NP;          // NP (uses N+1)
    int*   cursor  = row_ptr + NP;       // NP
    int*   bsum    = cursor + NP;        // 64
    int*   csr_src = bsum + 64;          // Ee
    float* wf      = (float*)(csr_src + Ee);
    float* srcn    = wf;                 // NP
    float* dstn    = srcn + NP;          // NP
    float* pq      = dstn + NP;          // NP (srcn*dstn)
    float* bufA    = pq + NP;            // N*D
    float* bufB    = bufA + (size_t)Nn * Dd;
    float* pooled  = bufB + (size_t)Nn * Dd;   // G*D
    int*   cnt     = (int*)(pooled + Gg * Dd); // G (int)

    // ---- CSR build ----
    hipMemsetAsync(odeg, 0, 2 * NP * sizeof(int), stream);
    degree_kernel<<<(Ee + 255) / 256, 256, 0, stream>>>(src, dst, odeg, ideg);
    norm_kernel<<<(Nn + 255) / 256, 256, 0, stream>>>(odeg, ideg, srcn, dstn, pq);
    scanA<<<NCHUNK, 256, 0, stream>>>(ideg, row_ptr, bsum);
    scanB<<<1, 64, 0, stream>>>(bsum);
    scanC<<<(Nn + 255) / 256, 256, 0, stream>>>(row_ptr, bsum, cursor);
    fill_kernel<<<(Ee + 255) / 256, 256, 0, stream>>>(src, dst, cursor, csr_src);

    int gblocks = (Nn + BM - 1) / BM;
    int sblocks = (Nn + 3) / 4;

    // layer 1: xeff = X*srcn
    gemm_kernel<<<gblocks, 512, 0, stream>>>(inputs, W1, srcn, nullptr, nullptr, bufA, Nn);
    spmm_kernel<<<sblocks, 256, 0, stream>>>(bufA, row_ptr, csr_src, bufB);

    // layer 2: xeff = X*(srcn*dstn) + b1*srcn
    gemm_kernel<<<gblocks, 512, 0, stream>>>(bufB, W2, pq, b1, srcn, bufA, Nn);
    spmm_kernel<<<sblocks, 256, 0, stream>>>(bufA, row_ptr, csr_src, bufB);

    // layer 3
    gemm_kernel<<<gblocks, 512, 0, stream>>>(bufB, W3, pq, b2, srcn, bufA, Nn);
    spmm_kernel<<<sblocks, 256, 0, stream>>>(bufA, row_ptr, csr_src, bufB);

    // mean_nodes (dstn applied here; b3 deferred to classifier)
    hipMemsetAsync(pooled, 0, Gg * Dd * sizeof(float) + Gg * sizeof(int), stream);
    pool_kernel<<<(Nn + 127) / 128, 256, 0, stream>>>(bufB, dstn, gid, pooled, cnt);

    // fused classifier (one block)
    classifier_kernel<<<1, 1024, 0, stream>>>(pooled, cnt, b3, Wc1, bc1, Wc2, bc2,
                                              Wc3, bc3, (float*)d_out);
}

// Round 6
// 327.631 us; speedup vs baseline: 10.8390x; 1.1268x over previous
//
#include <hip/hip_runtime.h>

#define Nn 50000
#define Ee 600000
#define Gg 8
#define Dd 128
#define NP 50048            // padded N (multiple of 64) for ws layout
#define SCHUNK 1024
#define NCHUNK ((Nn + SCHUNK - 1) / SCHUNK)   // 49

#define BM 128
#define BN 128
#define BK 32

#define HWORDS 25024        // ceil(N/2) padded; 2x16-bit counters per word
#define HB 16               // edge-chunks per endpoint array (Ee/HB = 37500)

// ---------------- LDS histogram of src & dst (no global atomics) ----------
// 32 blocks: even -> src chunk, odd -> dst chunk. Each block: full-node
// packed 16-bit LDS histogram of its 37500 edges, then coalesced flush to
// per-block partials. Carry-safe: block sees < 2^16 edges.
__global__ __launch_bounds__(1024) void hist_kernel(
    const int* __restrict__ src, const int* __restrict__ dst,
    unsigned int* __restrict__ phist)     // [2*HB][HWORDS]
{
    __shared__ unsigned int h[HWORDS];
    int t = threadIdx.x;
    for (int i = t; i < HWORDS; i += 1024) h[i] = 0u;
    __syncthreads();

    int part = blockIdx.x >> 1;
    const int* arr = (blockIdx.x & 1) ? dst : src;
    int e0 = part * (Ee / HB);
    int e1 = e0 + (Ee / HB);
    for (int e = e0 + t; e < e1; e += 1024) {
        int n = arr[e];
        atomicAdd(&h[n >> 1], 1u << ((n & 1) << 4));
    }
    __syncthreads();

    unsigned int* out = phist + (size_t)blockIdx.x * HWORDS;
    for (int i = t; i < HWORDS; i += 1024) out[i] = h[i];
}

// ---------------- reduce partials -> ideg, srcn, dstn, pq ----------------
__global__ __launch_bounds__(256) void reduce_norm_kernel(
    const unsigned int* __restrict__ phist,
    int* __restrict__ ideg, float* __restrict__ srcn,
    float* __restrict__ dstn, float* __restrict__ pq)
{
    int i = blockIdx.x * 256 + threadIdx.x;   // word index (2 nodes)
    if (i >= HWORDS) return;
    unsigned int so0 = 0, so1 = 0, si0 = 0, si1 = 0;
#pragma unroll
    for (int p = 0; p < HB; ++p) {
        unsigned int a = phist[(size_t)(2 * p) * HWORDS + i];       // src part
        unsigned int b = phist[(size_t)(2 * p + 1) * HWORDS + i];   // dst part
        so0 += a & 0xffffu; so1 += a >> 16;
        si0 += b & 0xffffu; si1 += b >> 16;
    }
    int n0 = 2 * i, n1 = 2 * i + 1;
    if (n0 < Nn) {
        ideg[n0] = (int)si0;
        float sn = 1.f / sqrtf(fmaxf((float)so0, 1.f));
        float dn = 1.f / sqrtf(fmaxf((float)si0, 1.f));
        srcn[n0] = sn; dstn[n0] = dn; pq[n0] = sn * dn;
    }
    if (n1 < Nn) {
        ideg[n1] = (int)si1;
        float sn = 1.f / sqrtf(fmaxf((float)so1, 1.f));
        float dn = 1.f / sqrtf(fmaxf((float)si1, 1.f));
        srcn[n1] = sn; dstn[n1] = dn; pq[n1] = sn * dn;
    }
}

// ---------------- prefix scan (exclusive) of ideg -> row_ptr ----------------
__global__ __launch_bounds__(256) void scanA(
    const int* __restrict__ ideg, int* __restrict__ row_ptr, int* __restrict__ bsum)
{
    __shared__ int tsum[256];
    int b = blockIdx.x, t = threadIdx.x;
    int base = b * SCHUNK + t * 4;
    int v[4]; int s = 0;
#pragma unroll
    for (int i = 0; i < 4; ++i) {
        int idx = base + i;
        v[i] = (idx < Nn) ? ideg[idx] : 0;
        s += v[i];
    }
    tsum[t] = s;
    __syncthreads();
    for (int off = 1; off < 256; off <<= 1) {
        int x = (t >= off) ? tsum[t - off] : 0;
        __syncthreads();
        tsum[t] += x;
        __syncthreads();
    }
    int run = tsum[t] - s;          // exclusive within chunk
#pragma unroll
    for (int i = 0; i < 4; ++i) {
        int idx = base + i;
        if (idx < Nn) row_ptr[idx] = run;
        run += v[i];
    }
    if (t == 255) bsum[b] = tsum[255];
}

__global__ void scanB(int* __restrict__ bsum)
{
    int t = threadIdx.x;                 // single wave of 64
    int v = (t < NCHUNK) ? bsum[t] : 0;
    int orig = v;
    for (int off = 1; off < 64; off <<= 1) {
        int x = __shfl_up(v, off, 64);
        if (t >= off) v += x;
    }
    if (t < NCHUNK) bsum[t] = v - orig;  // exclusive
}

__global__ __launch_bounds__(256) void scanC(
    int* __restrict__ row_ptr, const int* __restrict__ bsum, int* __restrict__ cursor)
{
    int n = blockIdx.x * 256 + threadIdx.x;
    if (n >= Nn) return;
    int v = row_ptr[n] + bsum[n / SCHUNK];
    row_ptr[n] = v;
    cursor[n] = v;
    if (n == 0) row_ptr[Nn] = Ee;
}

// ---------------- CSR fill (counting-sort bucket fill) ----------------
__global__ __launch_bounds__(256) void fill_kernel(
    const int* __restrict__ src, const int* __restrict__ dst,
    int* __restrict__ cursor, int* __restrict__ csr_src)
{
    int e = blockIdx.x * 256 + threadIdx.x;
    if (e >= Ee) return;
    int pos = atomicAdd(&cursor[dst[e]], 1);
    csr_src[pos] = src[e];
}

// ---------------- gather SpMM: out[n] = sum_{j in row n} Y[csr_src[j]] ------
__global__ __launch_bounds__(256) void spmm_kernel(
    const float* __restrict__ Y, const int* __restrict__ row_ptr,
    const int* __restrict__ csr_src, float* __restrict__ out)
{
    int w = threadIdx.x >> 6, lane = threadIdx.x & 63;
    int n = blockIdx.x * 4 + w;
    if (n >= Nn) return;
    int beg = row_ptr[n], end = row_ptr[n + 1];
    const float2* Y2 = (const float2*)Y;
    float ax = 0.f, ay = 0.f;
    int j = beg;
    for (; j + 3 < end; j += 4) {
        int s0 = csr_src[j],     s1 = csr_src[j + 1];
        int s2 = csr_src[j + 2], s3 = csr_src[j + 3];
        float2 v0 = Y2[(size_t)s0 * 64 + lane];
        float2 v1 = Y2[(size_t)s1 * 64 + lane];
        float2 v2 = Y2[(size_t)s2 * 64 + lane];
        float2 v3 = Y2[(size_t)s3 * 64 + lane];
        ax += (v0.x + v1.x) + (v2.x + v3.x);
        ay += (v0.y + v1.y) + (v2.y + v3.y);
    }
    for (; j < end; ++j) {
        int s0 = csr_src[j];
        float2 v0 = Y2[(size_t)s0 * 64 + lane];
        ax += v0.x; ay += v0.y;
    }
    float2 o; o.x = ax; o.y = ay;
    ((float2*)out)[(size_t)n * 64 + lane] = o;
}

// ---------------- fused GEMM (BK=32 double-buffered, 2 blocks/CU) ----------
// Y = xeff @ W,  xeff[r][k] = X[r][k]*p[r] + bias[k]*s[r]
__global__ __launch_bounds__(512, 4) void gemm_kernel(
    const float* __restrict__ X, const float* __restrict__ W,
    const float* __restrict__ p, const float* __restrict__ bias,
    const float* __restrict__ s, float* __restrict__ Y, int nrows)
{
    __shared__ float Xs[2][BK][BM + 4];   // transposed [k][row]
    __shared__ float Ws[2][BK][BN];
    int t = threadIdx.x;
    int row0 = blockIdx.x * BM;

    int xrow0 = t >> 3;             // rows 0..63
    int xq = (t & 7) * 4;           // k-quad offset within chunk
    int wk0 = t >> 5;               // W k-row 0..15
    int wn = (t & 31) * 4;

    float pr[2] = {0.f, 0.f}, sr[2] = {0.f, 0.f};
#pragma unroll
    for (int h = 0; h < 2; ++h) {
        int gr = row0 + xrow0 + h * 64;
        if (gr < nrows) {
            pr[h] = p[gr];
            sr[h] = bias ? s[gr] : 0.f;
        }
    }

    float4 xv[2], wv[2], bv[2];

    auto LOAD = [&](int ch) {
        int k0 = ch * BK;
#pragma unroll
        for (int h = 0; h < 2; ++h) {
            int gr = row0 + xrow0 + h * 64;
            int kk = k0 + xq;
            if (gr < nrows) xv[h] = *(const float4*)(X + (size_t)gr * Dd + kk);
            else            xv[h] = make_float4(0.f, 0.f, 0.f, 0.f);
            if (bias)       bv[h] = *(const float4*)(bias + kk);
            else            bv[h] = make_float4(0.f, 0.f, 0.f, 0.f);
            wv[h] = *(const float4*)(W + (size_t)(k0 + wk0 + h * 16) * Dd + wn);
        }
    };
    auto STORE = [&](int buf) {
#pragma unroll
        for (int h = 0; h < 2; ++h) {
            int r = xrow0 + h * 64;
            float vx = xv[h].x * pr[h] + bv[h].x * sr[h];
            float vy = xv[h].y * pr[h] + bv[h].y * sr[h];
            float vz = xv[h].z * pr[h] + bv[h].z * sr[h];
            float vw = xv[h].w * pr[h] + bv[h].w * sr[h];
            Xs[buf][xq + 0][r] = vx;
            Xs[buf][xq + 1][r] = vy;
            Xs[buf][xq + 2][r] = vz;
            Xs[buf][xq + 3][r] = vw;
            *(float4*)&Ws[buf][wk0 + h * 16][wn] = wv[h];
        }
    };

    int tc = t & 31, tr = t >> 5;
    int c0 = tc * 4, r0 = tr * 8;

    float acc[8][4];
#pragma unroll
    for (int i = 0; i < 8; ++i)
#pragma unroll
        for (int j = 0; j < 4; ++j) acc[i][j] = 0.f;

    LOAD(0); STORE(0);
    __syncthreads();

#pragma unroll
    for (int ch = 0; ch < Dd / BK; ++ch) {
        int cur = ch & 1;
        if (ch < Dd / BK - 1) LOAD(ch + 1);   // issue next-chunk loads early
#pragma unroll 8
        for (int k = 0; k < BK; ++k) {
            float4 xa = *(const float4*)&Xs[cur][k][r0];
            float4 xb = *(const float4*)&Xs[cur][k][r0 + 4];
            float4 wa = *(const float4*)&Ws[cur][k][c0];
            float xr[8] = {xa.x, xa.y, xa.z, xa.w, xb.x, xb.y, xb.z, xb.w};
            float wr[4] = {wa.x, wa.y, wa.z, wa.w};
#pragma unroll
            for (int i = 0; i < 8; ++i)
#pragma unroll
                for (int j = 0; j < 4; ++j)
                    acc[i][j] += xr[i] * wr[j];
        }
        if (ch < Dd / BK - 1) {
            STORE(cur ^ 1);                    // write the other buffer
            __syncthreads();
        }
    }

#pragma unroll
    for (int i = 0; i < 8; ++i) {
        int row = row0 + r0 + i;
        if (row < nrows) {
            float4 o = {acc[i][0], acc[i][1], acc[i][2], acc[i][3]};
            *(float4*)(Y + (size_t)row * Dd + c0) = o;
        }
    }
}

// ---------------- mean_nodes pooling (parallel tiled reduction) ----------
__global__ __launch_bounds__(256) void pool_kernel(
    const float* __restrict__ Hagg, const float* __restrict__ dstn,
    const int* __restrict__ gid, float* __restrict__ pooled, int* __restrict__ cnt)
{
    __shared__ int gs[128];
    __shared__ float ds[128];
    __shared__ float sp[Gg][Dd];
    __shared__ int lcnt[Gg];
    int t = threadIdx.x;
    int n0 = blockIdx.x * 128;

    for (int i = t; i < Gg * Dd; i += 256) sp[i >> 7][i & 127] = 0.f;
    if (t < Gg) lcnt[t] = 0;
    if (t < 128) {
        int n = n0 + t;
        gs[t] = (n < Nn) ? gid[n] : -1;
        ds[t] = (n < Nn) ? dstn[n] : 0.f;
    }
    __syncthreads();
    if (t < 128 && gs[t] >= 0) atomicAdd(&lcnt[gs[t]], 1);

    int c4 = (t & 31) * 4, r0 = t >> 5;
    float4 acc = {0.f, 0.f, 0.f, 0.f};
    int cur = -1;
    for (int i = r0; i < 128; i += 8) {
        int g = gs[i];
        if (g < 0) break;
        if (g != cur) {
            if (cur >= 0) {
                atomicAdd(&sp[cur][c4 + 0], acc.x);
                atomicAdd(&sp[cur][c4 + 1], acc.y);
                atomicAdd(&sp[cur][c4 + 2], acc.z);
                atomicAdd(&sp[cur][c4 + 3], acc.w);
            }
            acc = make_float4(0.f, 0.f, 0.f, 0.f);
            cur = g;
        }
        float4 v = *(const float4*)(Hagg + (size_t)(n0 + i) * Dd + c4);
        float d = ds[i];
        acc.x += v.x * d; acc.y += v.y * d;
        acc.z += v.z * d; acc.w += v.w * d;
    }
    if (cur >= 0) {
        atomicAdd(&sp[cur][c4 + 0], acc.x);
        atomicAdd(&sp[cur][c4 + 1], acc.y);
        atomicAdd(&sp[cur][c4 + 2], acc.z);
        atomicAdd(&sp[cur][c4 + 3], acc.w);
    }
    __syncthreads();
    for (int i = t; i < Gg * Dd; i += 256) {
        int g = i >> 7;
        if (lcnt[g] > 0) atomicAdd(&pooled[i], sp[g][i & 127]);
    }
    if (t < Gg && lcnt[t] > 0) atomicAdd(&cnt[t], lcnt[t]);
}

// ---------------- fused classifier: 1 block, 1024 threads ----------------
__global__ __launch_bounds__(1024) void classifier_kernel(
    const float* __restrict__ pooled, const int* __restrict__ cnt,
    const float* __restrict__ b3,
    const float* __restrict__ Wc1, const float* __restrict__ bc1,
    const float* __restrict__ Wc2, const float* __restrict__ bc2,
    const float* __restrict__ Wc3, const float* __restrict__ bc3,
    float* __restrict__ out)
{
    __shared__ float x0[Gg * 128];
    __shared__ float x1[Gg * 512];
    __shared__ float x2[Gg * 256];
    __shared__ float par[4 * Gg * 256];
    int t = threadIdx.x;

    if (t < Gg * 128) {
        int g = t >> 7, c = t & 127;
        x0[t] = pooled[t] / fmaxf((float)cnt[g], 1.f) + b3[c];
    }
    __syncthreads();

    // ---- fc1: 512 m-cols, K=128 split into 2 halves of 64 ----
    {
        int m = t & 511, h = t >> 9;
        int k0 = h * 64;
        float acc[Gg];
#pragma unroll
        for (int g = 0; g < Gg; ++g) acc[g] = 0.f;
#pragma unroll 16
        for (int k = 0; k < 64; ++k) {
            float w = Wc1[(size_t)(k0 + k) * 512 + m];
#pragma unroll
            for (int g = 0; g < Gg; ++g) acc[g] += x0[g * 128 + k0 + k] * w;
        }
#pragma unroll
        for (int g = 0; g < Gg; ++g) par[(h * Gg + g) * 512 + m] = acc[g];
    }
    __syncthreads();
    if (t < 512) {
        float b = bc1[t];
#pragma unroll
        for (int g = 0; g < Gg; ++g) {
            float v = par[g * 512 + t] + par[(Gg + g) * 512 + t] + b;
            x1[g * 512 + t] = v > 0.f ? v : 0.01f * v;
        }
    }
    __syncthreads();

    // ---- fc2: 256 m-cols, K=512 split into 4 chunks of 128 ----
    {
        int m = t & 255, h = t >> 8;
        int k0 = h * 128;
        float acc[Gg];
#pragma unroll
        for (int g = 0; g < Gg; ++g) acc[g] = 0.f;
#pragma unroll 16
        for (int k = 0; k < 128; ++k) {
            float w = Wc2[(size_t)(k0 + k) * 256 + m];
#pragma unroll
            for (int g = 0; g < Gg; ++g) acc[g] += x1[g * 512 + k0 + k] * w;
        }
#pragma unroll
        for (int g = 0; g < Gg; ++g) par[(h * Gg + g) * 256 + m] = acc[g];
    }
    __syncthreads();
    if (t < 256) {
        float b = bc2[t];
#pragma unroll
        for (int g = 0; g < Gg; ++g) {
            float v = par[(0 * Gg + g) * 256 + t] + par[(1 * Gg + g) * 256 + t]
                    + par[(2 * Gg + g) * 256 + t] + par[(3 * Gg + g) * 256 + t] + b;
            x2[g * 256 + t] = v > 0.f ? v : 0.01f * v;
        }
    }
    __syncthreads();

    // ---- fc3: 10 outputs, one wave per m, K=256 strided by lane ----
    {
        int w = t >> 6, lane = t & 63;
        if (w < 10) {
            float acc[Gg];
#pragma unroll
            for (int g = 0; g < Gg; ++g) acc[g] = 0.f;
#pragma unroll
            for (int kk = 0; kk < 4; ++kk) {
                int k = lane + kk * 64;
                float wv = Wc3[(size_t)k * 10 + w];
#pragma unroll
                for (int g = 0; g < Gg; ++g) acc[g] += x2[g * 256 + k] * wv;
            }
#pragma unroll
            for (int g = 0; g < Gg; ++g) {
                float v = acc[g];
                for (int off = 32; off; off >>= 1) v += __shfl_down(v, off, 64);
                if (lane == 0) {
                    v += bc3[w];
                    out[g * 10 + w] = v > 0.f ? v : 0.01f * v;
                }
            }
        }
    }
}

extern "C" void kernel_launch(void* const* d_in, const int* in_sizes, int n_in,
                              void* d_out, int out_size, void* d_ws, size_t ws_size,
                              hipStream_t stream)
{
    const float* inputs = (const float*)d_in[0];
    const int*   src    = (const int*)d_in[1];
    const int*   dst    = (const int*)d_in[2];
    const int*   gid    = (const int*)d_in[3];
    const float* W1  = (const float*)d_in[4];
    const float* b1  = (const float*)d_in[5];
    const float* W2  = (const float*)d_in[6];
    const float* b2  = (const float*)d_in[7];
    const float* W3  = (const float*)d_in[8];
    const float* b3  = (const float*)d_in[9];
    const float* Wc1 = (const float*)d_in[10];
    const float* bc1 = (const float*)d_in[11];
    const float* Wc2 = (const float*)d_in[12];
    const float* bc2 = (const float*)d_in[13];
    const float* Wc3 = (const float*)d_in[14];
    const float* bc3 = (const float*)d_in[15];

    // ---- workspace layout ----
    int*   wi      = (int*)d_ws;
    int*   ideg    = wi;                 // NP
    int*   row_ptr = ideg + NP;          // NP (uses N+1)
    int*   cursor  = row_ptr + NP;       // NP
    int*   bsum    = cursor + NP;        // 64
    int*   csr_src = bsum + 64;          // Ee
    float* wf      = (float*)(csr_src + Ee);
    float* srcn    = wf;                 // NP
    float* dstn    = srcn + NP;          // NP
    float* pq      = dstn + NP;          // NP (srcn*dstn)
    float* bufA    = pq + NP;            // N*D
    float* bufB    = bufA + (size_t)Nn * Dd;
    float* pooled  = bufB + (size_t)Nn * Dd;   // G*D
    int*   cnt     = (int*)(pooled + Gg * Dd); // G (int)

    // phist aliases bufB: consumed by reduce_norm before spmm first writes bufB
    unsigned int* phist = (unsigned int*)bufB;   // [2*HB][HWORDS] = 3.2 MB

    // ---- CSR build ----
    hist_kernel<<<2 * HB, 1024, 0, stream>>>(src, dst, phist);
    reduce_norm_kernel<<<(HWORDS + 255) / 256, 256, 0, stream>>>(
        phist, ideg, srcn, dstn, pq);
    scanA<<<NCHUNK, 256, 0, stream>>>(ideg, row_ptr, bsum);
    scanB<<<1, 64, 0, stream>>>(bsum);
    scanC<<<(Nn + 255) / 256, 256, 0, stream>>>(row_ptr, bsum, cursor);
    fill_kernel<<<(Ee + 255) / 256, 256, 0, stream>>>(src, dst, cursor, csr_src);

    int gblocks = (Nn + BM - 1) / BM;
    int sblocks = (Nn + 3) / 4;

    // layer 1: xeff = X*srcn
    gemm_kernel<<<gblocks, 512, 0, stream>>>(inputs, W1, srcn, nullptr, nullptr, bufA, Nn);
    spmm_kernel<<<sblocks, 256, 0, stream>>>(bufA, row_ptr, csr_src, bufB);

    // layer 2: xeff = X*(srcn*dstn) + b1*srcn
    gemm_kernel<<<gblocks, 512, 0, stream>>>(bufB, W2, pq, b1, srcn, bufA, Nn);
    spmm_kernel<<<sblocks, 256, 0, stream>>>(bufA, row_ptr, csr_src, bufB);

    // layer 3
    gemm_kernel<<<gblocks, 512, 0, stream>>>(bufB, W3, pq, b2, srcn, bufA, Nn);
    spmm_kernel<<<sblocks, 256, 0, stream>>>(bufA, row_ptr, csr_src, bufB);

    // mean_nodes (dstn applied here; b3 deferred to classifier)
    hipMemsetAsync(pooled, 0, Gg * Dd * sizeof(float) + Gg * sizeof(int), stream);
    pool_kernel<<<(Nn + 127) / 128, 256, 0, stream>>>(bufB, dstn, gid, pooled, cnt);

    // fused classifier (one block)
    classifier_kernel<<<1, 1024, 0, stream>>>(pooled, cnt, b3, Wc1, bc1, Wc2, bc2,
                                              Wc3, bc3, (float*)d_out);
}

// Round 7
// 262.118 us; speedup vs baseline: 13.5481x; 1.2499x over previous
//
#include <hip/hip_runtime.h>

#define Nn 50000
#define Ee 600000
#define Gg 8
#define Dd 128
#define NP 50048            // padded N (multiple of 64) for ws layout
#define SCHUNK 1024
#define NCHUNK ((Nn + SCHUNK - 1) / SCHUNK)   // 49

#define HWORDS 25024        // ceil(N/2) padded; 2x16-bit counters per word
#define HB 16               // edge-chunks per endpoint array (Ee/HB = 37500)

// ---------------- LDS histogram of src & dst (no global atomics) ----------
__global__ __launch_bounds__(1024) void hist_kernel(
    const int* __restrict__ src, const int* __restrict__ dst,
    unsigned int* __restrict__ phist)     // [2*HB][HWORDS]
{
    __shared__ unsigned int h[HWORDS];
    int t = threadIdx.x;
    for (int i = t; i < HWORDS; i += 1024) h[i] = 0u;
    __syncthreads();

    int part = blockIdx.x >> 1;
    const int* arr = (blockIdx.x & 1) ? dst : src;
    int e0 = part * (Ee / HB);
    int e1 = e0 + (Ee / HB);
    for (int e = e0 + t; e < e1; e += 1024) {
        int n = arr[e];
        atomicAdd(&h[n >> 1], 1u << ((n & 1) << 4));
    }
    __syncthreads();

    unsigned int* out = phist + (size_t)blockIdx.x * HWORDS;
    for (int i = t; i < HWORDS; i += 1024) out[i] = h[i];
}

// ---------------- reduce partials -> ideg, srcn, dstn, pq ----------------
__global__ __launch_bounds__(256) void reduce_norm_kernel(
    const unsigned int* __restrict__ phist,
    int* __restrict__ ideg, float* __restrict__ srcn,
    float* __restrict__ dstn, float* __restrict__ pq)
{
    int i = blockIdx.x * 256 + threadIdx.x;   // word index (2 nodes)
    if (i >= HWORDS) return;
    unsigned int so0 = 0, so1 = 0, si0 = 0, si1 = 0;
#pragma unroll
    for (int p = 0; p < HB; ++p) {
        unsigned int a = phist[(size_t)(2 * p) * HWORDS + i];       // src part
        unsigned int b = phist[(size_t)(2 * p + 1) * HWORDS + i];   // dst part
        so0 += a & 0xffffu; so1 += a >> 16;
        si0 += b & 0xffffu; si1 += b >> 16;
    }
    int n0 = 2 * i, n1 = 2 * i + 1;
    if (n0 < Nn) {
        ideg[n0] = (int)si0;
        float sn = 1.f / sqrtf(fmaxf((float)so0, 1.f));
        float dn = 1.f / sqrtf(fmaxf((float)si0, 1.f));
        srcn[n0] = sn; dstn[n0] = dn; pq[n0] = sn * dn;
    }
    if (n1 < Nn) {
        ideg[n1] = (int)si1;
        float sn = 1.f / sqrtf(fmaxf((float)so1, 1.f));
        float dn = 1.f / sqrtf(fmaxf((float)si1, 1.f));
        srcn[n1] = sn; dstn[n1] = dn; pq[n1] = sn * dn;
    }
}

// ---------------- prefix scan (exclusive) of ideg -> row_ptr ----------------
__global__ __launch_bounds__(256) void scanA(
    const int* __restrict__ ideg, int* __restrict__ row_ptr, int* __restrict__ bsum)
{
    __shared__ int tsum[256];
    int b = blockIdx.x, t = threadIdx.x;
    int base = b * SCHUNK + t * 4;
    int v[4]; int s = 0;
#pragma unroll
    for (int i = 0; i < 4; ++i) {
        int idx = base + i;
        v[i] = (idx < Nn) ? ideg[idx] : 0;
        s += v[i];
    }
    tsum[t] = s;
    __syncthreads();
    for (int off = 1; off < 256; off <<= 1) {
        int x = (t >= off) ? tsum[t - off] : 0;
        __syncthreads();
        tsum[t] += x;
        __syncthreads();
    }
    int run = tsum[t] - s;          // exclusive within chunk
#pragma unroll
    for (int i = 0; i < 4; ++i) {
        int idx = base + i;
        if (idx < Nn) row_ptr[idx] = run;
        run += v[i];
    }
    if (t == 255) bsum[b] = tsum[255];
}

__global__ void scanB(int* __restrict__ bsum)
{
    int t = threadIdx.x;                 // single wave of 64
    int v = (t < NCHUNK) ? bsum[t] : 0;
    int orig = v;
    for (int off = 1; off < 64; off <<= 1) {
        int x = __shfl_up(v, off, 64);
        if (t >= off) v += x;
    }
    if (t < NCHUNK) bsum[t] = v - orig;  // exclusive
}

__global__ __launch_bounds__(256) void scanC(
    int* __restrict__ row_ptr, const int* __restrict__ bsum, int* __restrict__ cursor)
{
    int n = blockIdx.x * 256 + threadIdx.x;
    if (n >= Nn) return;
    int v = row_ptr[n] + bsum[n / SCHUNK];
    row_ptr[n] = v;
    cursor[n] = v;
    if (n == 0) row_ptr[Nn] = Ee;
}

// ---------------- CSR fill (counting-sort bucket fill) ----------------
__global__ __launch_bounds__(256) void fill_kernel(
    const int* __restrict__ src, const int* __restrict__ dst,
    int* __restrict__ cursor, int* __restrict__ csr_src)
{
    int e = blockIdx.x * 256 + threadIdx.x;
    if (e >= Ee) return;
    int pos = atomicAdd(&cursor[dst[e]], 1);
    csr_src[pos] = src[e];
}

// ---------------- fused gather SpMM with per-edge scalar ----------------
// out[n][:] = sum_{e in row n} scal[src_e] * Y[src_e][:]
// wout[n]   = sum_{e} scal[src_e] * (win ? win[src_e] : 1)     (if wout)
// 32 lanes per row (float4 = 512B row), 2 rows per wave, unroll 4.
__global__ __launch_bounds__(256) void spmm_kernel(
    const float* __restrict__ Y, const int* __restrict__ row_ptr,
    const int* __restrict__ csr_src, const float* __restrict__ scal,
    const float* __restrict__ win, float* __restrict__ out,
    float* __restrict__ wout)
{
    int half = threadIdx.x >> 5, lane = threadIdx.x & 31;
    int n = blockIdx.x * 8 + half;
    if (n >= Nn) return;
    int beg = row_ptr[n], end = row_ptr[n + 1];
    const float4* Y4 = (const float4*)Y;
    float4 acc = {0.f, 0.f, 0.f, 0.f};
    float ws = 0.f;
    int j = beg;
    for (; j + 3 < end; j += 4) {
        int s0 = csr_src[j],     s1 = csr_src[j + 1];
        int s2 = csr_src[j + 2], s3 = csr_src[j + 3];
        float c0 = scal[s0], c1 = scal[s1], c2 = scal[s2], c3 = scal[s3];
        float4 y0 = Y4[(size_t)s0 * 32 + lane];
        float4 y1 = Y4[(size_t)s1 * 32 + lane];
        float4 y2 = Y4[(size_t)s2 * 32 + lane];
        float4 y3 = Y4[(size_t)s3 * 32 + lane];
        if (wout)
            ws += win ? (c0 * win[s0] + c1 * win[s1] + c2 * win[s2] + c3 * win[s3])
                      : (c0 + c1 + c2 + c3);
        acc.x += c0 * y0.x + c1 * y1.x + c2 * y2.x + c3 * y3.x;
        acc.y += c0 * y0.y + c1 * y1.y + c2 * y2.y + c3 * y3.y;
        acc.z += c0 * y0.z + c1 * y1.z + c2 * y2.z + c3 * y3.z;
        acc.w += c0 * y0.w + c1 * y1.w + c2 * y2.w + c3 * y3.w;
    }
    for (; j < end; ++j) {
        int s0 = csr_src[j];
        float c0 = scal[s0];
        float4 y0 = Y4[(size_t)s0 * 32 + lane];
        if (wout) ws += win ? c0 * win[s0] : c0;
        acc.x += c0 * y0.x; acc.y += c0 * y0.y;
        acc.z += c0 * y0.z; acc.w += c0 * y0.w;
    }
    ((float4*)out)[(size_t)n * 32 + lane] = acc;
    if (wout && lane == 0) wout[n] = ws;
}

// ---------------- pooling: P=sum(dn*v3), pw1=sum(dn*w1), pw2=sum(dn*w2) ----
__global__ __launch_bounds__(256) void pool_kernel(
    const float* __restrict__ V3, const float* __restrict__ dstn,
    const float* __restrict__ w1, const float* __restrict__ w2,
    const int* __restrict__ gid, float* __restrict__ pooled,
    float* __restrict__ pw1, float* __restrict__ pw2, int* __restrict__ cnt)
{
    __shared__ int gs[128];
    __shared__ float ds[128];
    __shared__ float sp[Gg][Dd];
    __shared__ float lw1[Gg], lw2[Gg];
    __shared__ int lcnt[Gg];
    int t = threadIdx.x;
    int n0 = blockIdx.x * 128;

    for (int i = t; i < Gg * Dd; i += 256) sp[i >> 7][i & 127] = 0.f;
    if (t < Gg) { lcnt[t] = 0; lw1[t] = 0.f; lw2[t] = 0.f; }
    if (t < 128) {
        int n = n0 + t;
        gs[t] = (n < Nn) ? gid[n] : -1;
        ds[t] = (n < Nn) ? dstn[n] : 0.f;
    }
    __syncthreads();
    if (t < 128 && gs[t] >= 0) {
        int n = n0 + t, g = gs[t];
        atomicAdd(&lcnt[g], 1);
        atomicAdd(&lw1[g], ds[t] * w1[n]);
        atomicAdd(&lw2[g], ds[t] * w2[n]);
    }

    int c4 = (t & 31) * 4, r0 = t >> 5;
    float4 acc = {0.f, 0.f, 0.f, 0.f};
    int cur = -1;
    for (int i = r0; i < 128; i += 8) {
        int g = gs[i];
        if (g < 0) break;
        if (g != cur) {
            if (cur >= 0) {
                atomicAdd(&sp[cur][c4 + 0], acc.x);
                atomicAdd(&sp[cur][c4 + 1], acc.y);
                atomicAdd(&sp[cur][c4 + 2], acc.z);
                atomicAdd(&sp[cur][c4 + 3], acc.w);
            }
            acc = make_float4(0.f, 0.f, 0.f, 0.f);
            cur = g;
        }
        float4 v = *(const float4*)(V3 + (size_t)(n0 + i) * Dd + c4);
        float d = ds[i];
        acc.x += v.x * d; acc.y += v.y * d;
        acc.z += v.z * d; acc.w += v.w * d;
    }
    if (cur >= 0) {
        atomicAdd(&sp[cur][c4 + 0], acc.x);
        atomicAdd(&sp[cur][c4 + 1], acc.y);
        atomicAdd(&sp[cur][c4 + 2], acc.z);
        atomicAdd(&sp[cur][c4 + 3], acc.w);
    }
    __syncthreads();
    for (int i = t; i < Gg * Dd; i += 256) {
        int g = i >> 7;
        if (lcnt[g] > 0) atomicAdd(&pooled[i], sp[g][i & 127]);
    }
    if (t < Gg && lcnt[t] > 0) {
        atomicAdd(&cnt[t], lcnt[t]);
        atomicAdd(&pw1[t], lw1[t]);
        atomicAdd(&pw2[t], lw2[t]);
    }
}

// ---------------- fused classifier: 1 block, 1024 threads ----------------
// x0 = (P/cnt)@W1@W2@W3 + (pw2/cnt)*(b1@W2@W3) + (pw1/cnt)*(b2@W3) + b3
// then fc1 -> fc2 -> fc3 with LeakyReLU(0.01).
__global__ __launch_bounds__(1024) void classifier_kernel(
    const float* __restrict__ pooled, const float* __restrict__ pw1r,
    const float* __restrict__ pw2r, const int* __restrict__ cnt,
    const float* __restrict__ W1, const float* __restrict__ W2,
    const float* __restrict__ W3,
    const float* __restrict__ b1, const float* __restrict__ b2,
    const float* __restrict__ b3,
    const float* __restrict__ Wc1, const float* __restrict__ bc1,
    const float* __restrict__ Wc2, const float* __restrict__ bc2,
    const float* __restrict__ Wc3, const float* __restrict__ bc3,
    float* __restrict__ out)
{
    __shared__ float x0[Gg * 128];
    __shared__ float T1[Gg * 128];
    __shared__ float T2[Gg * 128];
    __shared__ float e1[128], e1b[128], e2[128];
    __shared__ float pw1s[Gg], pw2s[Gg];
    __shared__ float x1[Gg * 512];
    __shared__ float x2[Gg * 256];
    __shared__ float par[4 * Gg * 256];
    int t = threadIdx.x;
    int g = t >> 7, c = t & 127;

    // s0: mean-normalize
    {
        float cg = fmaxf((float)cnt[g], 1.f);
        x0[t] = pooled[t] / cg;
        if (t < Gg) {
            float cgg = fmaxf((float)cnt[t], 1.f);
            pw1s[t] = pw1r[t] / cgg;
            pw2s[t] = pw2r[t] / cgg;
        }
    }
    __syncthreads();
    // s1: T1 = x0@W1 ; e1 = b1@W2
    {
        float a = 0.f;
#pragma unroll 8
        for (int k = 0; k < 128; ++k) a += x0[g * 128 + k] * W1[k * 128 + c];
        T1[t] = a;
        if (t < 128) {
            float e = 0.f;
#pragma unroll 8
            for (int k = 0; k < 128; ++k) e += b1[k] * W2[k * 128 + t];
            e1[t] = e;
        }
    }
    __syncthreads();
    // s2: T2 = T1@W2 ; e1b = e1@W3 ; e2 = b2@W3
    {
        float a = 0.f;
#pragma unroll 8
        for (int k = 0; k < 128; ++k) a += T1[g * 128 + k] * W2[k * 128 + c];
        T2[t] = a;
        if (t < 128) {
            float e = 0.f;
#pragma unroll 8
            for (int k = 0; k < 128; ++k) e += e1[k] * W3[k * 128 + t];
            e1b[t] = e;
        } else if (t < 256) {
            int cc = t - 128;
            float e = 0.f;
#pragma unroll 8
            for (int k = 0; k < 128; ++k) e += b2[k] * W3[k * 128 + cc];
            e2[cc] = e;
        }
    }
    __syncthreads();
    // s3: x0 = T2@W3 + pw2*e1b + pw1*e2 + b3
    {
        float a = 0.f;
#pragma unroll 8
        for (int k = 0; k < 128; ++k) a += T2[g * 128 + k] * W3[k * 128 + c];
        x0[t] = a + pw2s[g] * e1b[c] + pw1s[g] * e2[c] + b3[c];
    }
    __syncthreads();

    // ---- fc1: 512 m-cols, K=128 split into 2 halves of 64 ----
    {
        int m = t & 511, h = t >> 9;
        int k0 = h * 64;
        float acc[Gg];
#pragma unroll
        for (int gg = 0; gg < Gg; ++gg) acc[gg] = 0.f;
#pragma unroll 16
        for (int k = 0; k < 64; ++k) {
            float w = Wc1[(size_t)(k0 + k) * 512 + m];
#pragma unroll
            for (int gg = 0; gg < Gg; ++gg) acc[gg] += x0[gg * 128 + k0 + k] * w;
        }
#pragma unroll
        for (int gg = 0; gg < Gg; ++gg) par[(h * Gg + gg) * 512 + m] = acc[gg];
    }
    __syncthreads();
    if (t < 512) {
        float b = bc1[t];
#pragma unroll
        for (int gg = 0; gg < Gg; ++gg) {
            float v = par[gg * 512 + t] + par[(Gg + gg) * 512 + t] + b;
            x1[gg * 512 + t] = v > 0.f ? v : 0.01f * v;
        }
    }
    __syncthreads();

    // ---- fc2: 256 m-cols, K=512 split into 4 chunks of 128 ----
    {
        int m = t & 255, h = t >> 8;
        int k0 = h * 128;
        float acc[Gg];
#pragma unroll
        for (int gg = 0; gg < Gg; ++gg) acc[gg] = 0.f;
#pragma unroll 16
        for (int k = 0; k < 128; ++k) {
            float w = Wc2[(size_t)(k0 + k) * 256 + m];
#pragma unroll
            for (int gg = 0; gg < Gg; ++gg) acc[gg] += x1[gg * 512 + k0 + k] * w;
        }
#pragma unroll
        for (int gg = 0; gg < Gg; ++gg) par[(h * Gg + gg) * 256 + m] = acc[gg];
    }
    __syncthreads();
    if (t < 256) {
        float b = bc2[t];
#pragma unroll
        for (int gg = 0; gg < Gg; ++gg) {
            float v = par[(0 * Gg + gg) * 256 + t] + par[(1 * Gg + gg) * 256 + t]
                    + par[(2 * Gg + gg) * 256 + t] + par[(3 * Gg + gg) * 256 + t] + b;
            x2[gg * 256 + t] = v > 0.f ? v : 0.01f * v;
        }
    }
    __syncthreads();

    // ---- fc3: 10 outputs, one wave per m, K=256 strided by lane ----
    {
        int w = t >> 6, lane = t & 63;
        if (w < 10) {
            float acc[Gg];
#pragma unroll
            for (int gg = 0; gg < Gg; ++gg) acc[gg] = 0.f;
#pragma unroll
            for (int kk = 0; kk < 4; ++kk) {
                int k = lane + kk * 64;
                float wv = Wc3[(size_t)k * 10 + w];
#pragma unroll
                for (int gg = 0; gg < Gg; ++gg) acc[gg] += x2[gg * 256 + k] * wv;
            }
#pragma unroll
            for (int gg = 0; gg < Gg; ++gg) {
                float v = acc[gg];
                for (int off = 32; off; off >>= 1) v += __shfl_down(v, off, 64);
                if (lane == 0) {
                    v += bc3[w];
                    out[gg * 10 + w] = v > 0.f ? v : 0.01f * v;
                }
            }
        }
    }
}

extern "C" void kernel_launch(void* const* d_in, const int* in_sizes, int n_in,
                              void* d_out, int out_size, void* d_ws, size_t ws_size,
                              hipStream_t stream)
{
    const float* inputs = (const float*)d_in[0];
    const int*   src    = (const int*)d_in[1];
    const int*   dst    = (const int*)d_in[2];
    const int*   gid    = (const int*)d_in[3];
    const float* W1  = (const float*)d_in[4];
    const float* b1  = (const float*)d_in[5];
    const float* W2  = (const float*)d_in[6];
    const float* b2  = (const float*)d_in[7];
    const float* W3  = (const float*)d_in[8];
    const float* b3  = (const float*)d_in[9];
    const float* Wc1 = (const float*)d_in[10];
    const float* bc1 = (const float*)d_in[11];
    const float* Wc2 = (const float*)d_in[12];
    const float* bc2 = (const float*)d_in[13];
    const float* Wc3 = (const float*)d_in[14];
    const float* bc3 = (const float*)d_in[15];

    // ---- workspace layout ----
    int*   wi      = (int*)d_ws;
    int*   ideg    = wi;                 // NP
    int*   row_ptr = ideg + NP;          // NP (uses N+1)
    int*   cursor  = row_ptr + NP;       // NP
    int*   bsum    = cursor + NP;        // 64
    int*   csr_src = bsum + 64;          // Ee
    float* wf      = (float*)(csr_src + Ee);
    float* srcn    = wf;                 // NP
    float* dstn    = srcn + NP;          // NP
    float* pq      = dstn + NP;          // NP (srcn*dstn)
    float* w1v     = pq + NP;            // NP (A srcn)
    float* w2v     = w1v + NP;           // NP (A (pq*w1))
    float* bufA    = w2v + NP;           // N*D
    float* bufB    = bufA + (size_t)Nn * Dd;   // N*D
    float* pooled  = bufB + (size_t)Nn * Dd;   // G*D
    float* pw1     = pooled + Gg * Dd;         // G
    float* pw2     = pw1 + Gg;                 // G
    int*   cnt     = (int*)(pw2 + Gg);         // G (int)

    // phist aliases bufB: consumed by reduce_norm before spmm2 writes bufB
    unsigned int* phist = (unsigned int*)bufB;   // [2*HB][HWORDS] = 3.2 MB

    // ---- CSR build ----
    hist_kernel<<<2 * HB, 1024, 0, stream>>>(src, dst, phist);
    reduce_norm_kernel<<<(HWORDS + 255) / 256, 256, 0, stream>>>(
        phist, ideg, srcn, dstn, pq);
    scanA<<<NCHUNK, 256, 0, stream>>>(ideg, row_ptr, bsum);
    scanB<<<1, 64, 0, stream>>>(bsum);
    scanC<<<(Nn + 255) / 256, 256, 0, stream>>>(row_ptr, bsum, cursor);
    fill_kernel<<<(Ee + 255) / 256, 256, 0, stream>>>(src, dst, cursor, csr_src);

    int sblocks = (Nn + 7) / 8;

    // v1 = A(srcn*x), w1 = A srcn
    spmm_kernel<<<sblocks, 256, 0, stream>>>(inputs, row_ptr, csr_src, srcn,
                                             nullptr, bufA, w1v);
    // v2 = A(pq*v1), w2 = A(pq*w1)
    spmm_kernel<<<sblocks, 256, 0, stream>>>(bufA, row_ptr, csr_src, pq,
                                             w1v, bufB, w2v);
    // v3 = A(pq*v2)
    spmm_kernel<<<sblocks, 256, 0, stream>>>(bufB, row_ptr, csr_src, pq,
                                             nullptr, bufA, nullptr);

    // pooling of v3, dn*w1, dn*w2
    hipMemsetAsync(pooled, 0, (Gg * Dd + 2 * Gg) * sizeof(float) + Gg * sizeof(int),
                   stream);
    pool_kernel<<<(Nn + 127) / 128, 256, 0, stream>>>(bufA, dstn, w1v, w2v, gid,
                                                      pooled, pw1, pw2, cnt);

    // fused classifier (one block): deferred W1/W2/W3 chain + MLP head
    classifier_kernel<<<1, 1024, 0, stream>>>(pooled, pw1, pw2, cnt,
                                              W1, W2, W3, b1, b2, b3,
                                              Wc1, bc1, Wc2, bc2, Wc3, bc3,
                                              (float*)d_out);
}

// Round 8
// 241.110 us; speedup vs baseline: 14.7286x; 1.0871x over previous
//
#include <hip/hip_runtime.h>

#define Nn 50000
#define Ee 600000
#define Gg 8
#define Dd 128
#define NP 50048            // padded N (multiple of 64) for ws layout
#define SCHUNK 1024
#define NCHUNK ((Nn + SCHUNK - 1) / SCHUNK)   // 49

#define HWORDS 25024        // ceil(N/2) padded; 2x16-bit counters per word
#define HB 16               // edge-chunks per endpoint array (Ee/HB = 37500)
#define HIST_BLOCKS (2 * HB)          // 32
#define W12_BLOCKS 16
#define RN_BLOCKS ((HWORDS + 255) / 256)   // 98
#define W123_BLOCKS 64

// ---------------- hist + piggyback W12/e1/e2 on idle CUs ----------------
// blocks [0,32): LDS histogram of src/dst chunk -> per-block partials.
// blocks [32,48): W12 = W1@W2, 8 cols each.
// block 48: e1 = b1@W2 (t<128), e2 = b2@W3 (128<=t<256).
__global__ __launch_bounds__(1024) void hist_kernel(
    const int* __restrict__ src, const int* __restrict__ dst,
    unsigned int* __restrict__ phist,
    const float* __restrict__ W1, const float* __restrict__ W2,
    const float* __restrict__ W3, const float* __restrict__ b1,
    const float* __restrict__ b2,
    float* __restrict__ W12, float* __restrict__ e1, float* __restrict__ e2)
{
    __shared__ unsigned int h[HWORDS];
    int t = threadIdx.x;
    int b = blockIdx.x;

    if (b < HIST_BLOCKS) {
        for (int i = t; i < HWORDS; i += 1024) h[i] = 0u;
        __syncthreads();
        int part = b >> 1;
        const int* arr = (b & 1) ? dst : src;
        int e0 = part * (Ee / HB);
        int eN = e0 + (Ee / HB);
        for (int e = e0 + t; e < eN; e += 1024) {
            int n = arr[e];
            atomicAdd(&h[n >> 1], 1u << ((n & 1) << 4));
        }
        __syncthreads();
        unsigned int* out = phist + (size_t)b * HWORDS;
        for (int i = t; i < HWORDS; i += 1024) out[i] = h[i];
    } else if (b < HIST_BLOCKS + W12_BLOCKS) {
        int j = (b - HIST_BLOCKS) * 8 + (t & 7);
        int k = t >> 3;
        float a = 0.f;
#pragma unroll 8
        for (int m = 0; m < 128; ++m) a += W1[k * 128 + m] * W2[m * 128 + j];
        W12[k * 128 + j] = a;
    } else {
        if (t < 128) {
            float a = 0.f;
#pragma unroll 8
            for (int k = 0; k < 128; ++k) a += b1[k] * W2[k * 128 + t];
            e1[t] = a;
        } else if (t < 256) {
            int c = t - 128;
            float a = 0.f;
#pragma unroll 8
            for (int k = 0; k < 128; ++k) a += b2[k] * W3[k * 128 + c];
            e2[c] = a;
        }
    }
}

// ---------------- reduce partials + piggyback W123/e1b ----------------
// blocks [0,98): reduce -> ideg, srcn, dstn, pq.
// blocks [98,162): W123 = W12@W3, 2 cols each. block 162: e1b = e1@W3.
__global__ __launch_bounds__(256) void reduce_norm_kernel(
    const unsigned int* __restrict__ phist,
    int* __restrict__ ideg, float* __restrict__ srcn,
    float* __restrict__ dstn, float* __restrict__ pq,
    const float* __restrict__ W12, const float* __restrict__ W3,
    const float* __restrict__ e1,
    float* __restrict__ W123, float* __restrict__ e1b)
{
    int b = blockIdx.x, t = threadIdx.x;
    if (b < RN_BLOCKS) {
        int i = b * 256 + t;
        if (i >= HWORDS) return;
        unsigned int so0 = 0, so1 = 0, si0 = 0, si1 = 0;
#pragma unroll
        for (int p = 0; p < HB; ++p) {
            unsigned int a = phist[(size_t)(2 * p) * HWORDS + i];
            unsigned int bb = phist[(size_t)(2 * p + 1) * HWORDS + i];
            so0 += a & 0xffffu; so1 += a >> 16;
            si0 += bb & 0xffffu; si1 += bb >> 16;
        }
        int n0 = 2 * i, n1 = 2 * i + 1;
        if (n0 < Nn) {
            ideg[n0] = (int)si0;
            float sn = 1.f / sqrtf(fmaxf((float)so0, 1.f));
            float dn = 1.f / sqrtf(fmaxf((float)si0, 1.f));
            srcn[n0] = sn; dstn[n0] = dn; pq[n0] = sn * dn;
        }
        if (n1 < Nn) {
            ideg[n1] = (int)si1;
            float sn = 1.f / sqrtf(fmaxf((float)so1, 1.f));
            float dn = 1.f / sqrtf(fmaxf((float)si1, 1.f));
            srcn[n1] = sn; dstn[n1] = dn; pq[n1] = sn * dn;
        }
    } else if (b < RN_BLOCKS + W123_BLOCKS) {
        int j = (b - RN_BLOCKS) * 2 + (t & 1);
        int k = t >> 1;
        float a = 0.f;
#pragma unroll 8
        for (int m = 0; m < 128; ++m) a += W12[k * 128 + m] * W3[m * 128 + j];
        W123[k * 128 + j] = a;
    } else {
        if (t < 128) {
            float a = 0.f;
#pragma unroll 8
            for (int k = 0; k < 128; ++k) a += e1[k] * W3[k * 128 + t];
            e1b[t] = a;
        }
    }
}

// ---------------- prefix scan (exclusive) of ideg -> row_ptr ----------------
__global__ __launch_bounds__(256) void scanA(
    const int* __restrict__ ideg, int* __restrict__ row_ptr, int* __restrict__ bsum)
{
    __shared__ int tsum[256];
    int b = blockIdx.x, t = threadIdx.x;
    int base = b * SCHUNK + t * 4;
    int v[4]; int s = 0;
#pragma unroll
    for (int i = 0; i < 4; ++i) {
        int idx = base + i;
        v[i] = (idx < Nn) ? ideg[idx] : 0;
        s += v[i];
    }
    tsum[t] = s;
    __syncthreads();
    for (int off = 1; off < 256; off <<= 1) {
        int x = (t >= off) ? tsum[t - off] : 0;
        __syncthreads();
        tsum[t] += x;
        __syncthreads();
    }
    int run = tsum[t] - s;
#pragma unroll
    for (int i = 0; i < 4; ++i) {
        int idx = base + i;
        if (idx < Nn) row_ptr[idx] = run;
        run += v[i];
    }
    if (t == 255) bsum[b] = tsum[255];
}

__global__ void scanB(int* __restrict__ bsum)
{
    int t = threadIdx.x;
    int v = (t < NCHUNK) ? bsum[t] : 0;
    int orig = v;
    for (int off = 1; off < 64; off <<= 1) {
        int x = __shfl_up(v, off, 64);
        if (t >= off) v += x;
    }
    if (t < NCHUNK) bsum[t] = v - orig;
}

__global__ __launch_bounds__(256) void scanC(
    int* __restrict__ row_ptr, const int* __restrict__ bsum, int* __restrict__ cursor)
{
    int n = blockIdx.x * 256 + threadIdx.x;
    if (n >= Nn) return;
    int v = row_ptr[n] + bsum[n / SCHUNK];
    row_ptr[n] = v;
    cursor[n] = v;
    if (n == 0) row_ptr[Nn] = Ee;
}

// ---------------- CSR fill (counting-sort bucket fill) ----------------
__global__ __launch_bounds__(256) void fill_kernel(
    const int* __restrict__ src, const int* __restrict__ dst,
    int* __restrict__ cursor, int* __restrict__ csr_src)
{
    int e = blockIdx.x * 256 + threadIdx.x;
    if (e >= Ee) return;
    int pos = atomicAdd(&cursor[dst[e]], 1);
    csr_src[pos] = src[e];
}

// ---------------- fused gather SpMM with per-edge scalar ----------------
__global__ __launch_bounds__(256) void spmm_kernel(
    const float* __restrict__ Y, const int* __restrict__ row_ptr,
    const int* __restrict__ csr_src, const float* __restrict__ scal,
    const float* __restrict__ win, float* __restrict__ out,
    float* __restrict__ wout)
{
    int half = threadIdx.x >> 5, lane = threadIdx.x & 31;
    int n = blockIdx.x * 8 + half;
    if (n >= Nn) return;
    int beg = row_ptr[n], end = row_ptr[n + 1];
    const float4* Y4 = (const float4*)Y;
    float4 acc = {0.f, 0.f, 0.f, 0.f};
    float ws = 0.f;
    int j = beg;
    for (; j + 3 < end; j += 4) {
        int s0 = csr_src[j],     s1 = csr_src[j + 1];
        int s2 = csr_src[j + 2], s3 = csr_src[j + 3];
        float c0 = scal[s0], c1 = scal[s1], c2 = scal[s2], c3 = scal[s3];
        float4 y0 = Y4[(size_t)s0 * 32 + lane];
        float4 y1 = Y4[(size_t)s1 * 32 + lane];
        float4 y2 = Y4[(size_t)s2 * 32 + lane];
        float4 y3 = Y4[(size_t)s3 * 32 + lane];
        if (wout)
            ws += win ? (c0 * win[s0] + c1 * win[s1] + c2 * win[s2] + c3 * win[s3])
                      : (c0 + c1 + c2 + c3);
        acc.x += c0 * y0.x + c1 * y1.x + c2 * y2.x + c3 * y3.x;
        acc.y += c0 * y0.y + c1 * y1.y + c2 * y2.y + c3 * y3.y;
        acc.z += c0 * y0.z + c1 * y1.z + c2 * y2.z + c3 * y3.z;
        acc.w += c0 * y0.w + c1 * y1.w + c2 * y2.w + c3 * y3.w;
    }
    for (; j < end; ++j) {
        int s0 = csr_src[j];
        float c0 = scal[s0];
        float4 y0 = Y4[(size_t)s0 * 32 + lane];
        if (wout) ws += win ? c0 * win[s0] : c0;
        acc.x += c0 * y0.x; acc.y += c0 * y0.y;
        acc.z += c0 * y0.z; acc.w += c0 * y0.w;
    }
    ((float4*)out)[(size_t)n * 32 + lane] = acc;
    if (wout && lane == 0) wout[n] = ws;
}

// ---------------- pooling: P=sum(dn*v3), pw1=sum(dn*w1), pw2=sum(dn*w2) ----
__global__ __launch_bounds__(256) void pool_kernel(
    const float* __restrict__ V3, const float* __restrict__ dstn,
    const float* __restrict__ w1, const float* __restrict__ w2,
    const int* __restrict__ gid, float* __restrict__ pooled,
    float* __restrict__ pw1, float* __restrict__ pw2, int* __restrict__ cnt)
{
    __shared__ int gs[128];
    __shared__ float ds[128];
    __shared__ float sp[Gg][Dd];
    __shared__ float lw1[Gg], lw2[Gg];
    __shared__ int lcnt[Gg];
    int t = threadIdx.x;
    int n0 = blockIdx.x * 128;

    for (int i = t; i < Gg * Dd; i += 256) sp[i >> 7][i & 127] = 0.f;
    if (t < Gg) { lcnt[t] = 0; lw1[t] = 0.f; lw2[t] = 0.f; }
    if (t < 128) {
        int n = n0 + t;
        gs[t] = (n < Nn) ? gid[n] : -1;
        ds[t] = (n < Nn) ? dstn[n] : 0.f;
    }
    __syncthreads();
    if (t < 128 && gs[t] >= 0) {
        int n = n0 + t, g = gs[t];
        atomicAdd(&lcnt[g], 1);
        atomicAdd(&lw1[g], ds[t] * w1[n]);
        atomicAdd(&lw2[g], ds[t] * w2[n]);
    }

    int c4 = (t & 31) * 4, r0 = t >> 5;
    float4 acc = {0.f, 0.f, 0.f, 0.f};
    int cur = -1;
    for (int i = r0; i < 128; i += 8) {
        int g = gs[i];
        if (g < 0) break;
        if (g != cur) {
            if (cur >= 0) {
                atomicAdd(&sp[cur][c4 + 0], acc.x);
                atomicAdd(&sp[cur][c4 + 1], acc.y);
                atomicAdd(&sp[cur][c4 + 2], acc.z);
                atomicAdd(&sp[cur][c4 + 3], acc.w);
            }
            acc = make_float4(0.f, 0.f, 0.f, 0.f);
            cur = g;
        }
        float4 v = *(const float4*)(V3 + (size_t)(n0 + i) * Dd + c4);
        float d = ds[i];
        acc.x += v.x * d; acc.y += v.y * d;
        acc.z += v.z * d; acc.w += v.w * d;
    }
    if (cur >= 0) {
        atomicAdd(&sp[cur][c4 + 0], acc.x);
        atomicAdd(&sp[cur][c4 + 1], acc.y);
        atomicAdd(&sp[cur][c4 + 2], acc.z);
        atomicAdd(&sp[cur][c4 + 3], acc.w);
    }
    __syncthreads();
    for (int i = t; i < Gg * Dd; i += 256) {
        int g = i >> 7;
        if (lcnt[g] > 0) atomicAdd(&pooled[i], sp[g][i & 127]);
    }
    if (t < Gg && lcnt[t] > 0) {
        atomicAdd(&cnt[t], lcnt[t]);
        atomicAdd(&pw1[t], lw1[t]);
        atomicAdd(&pw2[t], lw2[t]);
    }
}

// ---------------- head: x0 = (P@W123)/cnt + pw2*e1b + pw1*e2 + b3 ---------
__global__ __launch_bounds__(1024) void x0_kernel(
    const float* __restrict__ pooled, const float* __restrict__ pw1r,
    const float* __restrict__ pw2r, const int* __restrict__ cnt,
    const float* __restrict__ W123, const float* __restrict__ e1b,
    const float* __restrict__ e2, const float* __restrict__ b3,
    float* __restrict__ x0g)
{
    int t = threadIdx.x;
    int g = t >> 7, c = t & 127;
    float a = 0.f;
#pragma unroll 8
    for (int k = 0; k < 128; ++k) a += pooled[g * 128 + k] * W123[k * 128 + c];
    float inv = 1.f / fmaxf((float)cnt[g], 1.f);
    x0g[t] = a * inv + (pw2r[g] * inv) * e1b[c] + (pw1r[g] * inv) * e2[c] + b3[c];
}

// ---------------- head: fc1 (128->512), 32 blocks, K split 2-way ----------
__global__ __launch_bounds__(256) void fc1_kernel(
    const float* __restrict__ x0g, const float* __restrict__ Wc1,
    const float* __restrict__ bc1, float* __restrict__ x1g)
{
    __shared__ float xs[Gg * 128];
    __shared__ float par[256];
    int t = threadIdx.x;
    for (int i = t; i < Gg * 128; i += 256) xs[i] = x0g[i];
    __syncthreads();
    int h = t >> 7, rem = t & 127;
    int g = rem >> 4, m = blockIdx.x * 16 + (rem & 15);
    int k0 = h * 64;
    float a = 0.f;
#pragma unroll 16
    for (int k = 0; k < 64; ++k) a += xs[g * 128 + k0 + k] * Wc1[(size_t)(k0 + k) * 512 + m];
    par[t] = a;
    __syncthreads();
    if (t < 128) {
        float v = par[t] + par[t + 128] + bc1[m];
        x1g[g * 512 + m] = v > 0.f ? v : 0.01f * v;
    }
}

// ---------------- head: fc2 (512->256), 32 blocks, K split 4-way ----------
__global__ __launch_bounds__(256) void fc2_kernel(
    const float* __restrict__ x1g, const float* __restrict__ Wc2,
    const float* __restrict__ bc2, float* __restrict__ x2g)
{
    __shared__ float xs[Gg * 512];
    __shared__ float par[256];
    int t = threadIdx.x;
    for (int i = t; i < Gg * 512; i += 256) xs[i] = x1g[i];
    __syncthreads();
    int q = t >> 6, rem = t & 63;
    int g = rem >> 3, m = blockIdx.x * 8 + (rem & 7);
    int k0 = q * 128;
    float a = 0.f;
#pragma unroll 16
    for (int k = 0; k < 128; ++k) a += xs[g * 512 + k0 + k] * Wc2[(size_t)(k0 + k) * 256 + m];
    par[t] = a;
    __syncthreads();
    if (t < 64) {
        float v = par[t] + par[t + 64] + par[t + 128] + par[t + 192] + bc2[m];
        x2g[g * 256 + m] = v > 0.f ? v : 0.01f * v;
    }
}

// ---------------- head: fc3 (256->10), 1 block, wave per output -----------
__global__ __launch_bounds__(640) void fc3_kernel(
    const float* __restrict__ x2g, const float* __restrict__ Wc3,
    const float* __restrict__ bc3, float* __restrict__ out)
{
    __shared__ float xs[Gg * 256];
    int t = threadIdx.x;
    for (int i = t; i < Gg * 256; i += 640) xs[i] = x2g[i];
    __syncthreads();
    int w = t >> 6, lane = t & 63;
    if (w < 10) {
        float acc[Gg];
#pragma unroll
        for (int g = 0; g < Gg; ++g) acc[g] = 0.f;
#pragma unroll
        for (int kk = 0; kk < 4; ++kk) {
            int k = lane + kk * 64;
            float wv = Wc3[(size_t)k * 10 + w];
#pragma unroll
            for (int g = 0; g < Gg; ++g) acc[g] += xs[g * 256 + k] * wv;
        }
#pragma unroll
        for (int g = 0; g < Gg; ++g) {
            float v = acc[g];
            for (int off = 32; off; off >>= 1) v += __shfl_down(v, off, 64);
            if (lane == 0) {
                v += bc3[w];
                out[g * 10 + w] = v > 0.f ? v : 0.01f * v;
            }
        }
    }
}

extern "C" void kernel_launch(void* const* d_in, const int* in_sizes, int n_in,
                              void* d_out, int out_size, void* d_ws, size_t ws_size,
                              hipStream_t stream)
{
    const float* inputs = (const float*)d_in[0];
    const int*   src    = (const int*)d_in[1];
    const int*   dst    = (const int*)d_in[2];
    const int*   gid    = (const int*)d_in[3];
    const float* W1  = (const float*)d_in[4];
    const float* b1  = (const float*)d_in[5];
    const float* W2  = (const float*)d_in[6];
    const float* b2  = (const float*)d_in[7];
    const float* W3  = (const float*)d_in[8];
    const float* b3  = (const float*)d_in[9];
    const float* Wc1 = (const float*)d_in[10];
    const float* bc1 = (const float*)d_in[11];
    const float* Wc2 = (const float*)d_in[12];
    const float* bc2 = (const float*)d_in[13];
    const float* Wc3 = (const float*)d_in[14];
    const float* bc3 = (const float*)d_in[15];

    // ---- workspace layout ----
    int*   wi      = (int*)d_ws;
    int*   ideg    = wi;                 // NP
    int*   row_ptr = ideg + NP;          // NP (uses N+1)
    int*   cursor  = row_ptr + NP;       // NP
    int*   bsum    = cursor + NP;        // 64
    int*   csr_src = bsum + 64;          // Ee
    float* wf      = (float*)(csr_src + Ee);
    float* srcn    = wf;                 // NP
    float* dstn    = srcn + NP;          // NP
    float* pq      = dstn + NP;          // NP (srcn*dstn)
    float* w1v     = pq + NP;            // NP (A srcn)
    float* w2v     = w1v + NP;           // NP (A (pq*w1))
    float* bufA    = w2v + NP;           // N*D
    float* bufB    = bufA + (size_t)Nn * Dd;   // N*D
    float* pooled  = bufB + (size_t)Nn * Dd;   // G*D
    float* pw1     = pooled + Gg * Dd;         // G
    float* pw2     = pw1 + Gg;                 // G
    int*   cnt     = (int*)(pw2 + Gg);         // G (int)
    float* W12v    = (float*)(cnt + Gg);       // 128*128
    float* W123v   = W12v + 128 * 128;         // 128*128
    float* e1v     = W123v + 128 * 128;        // 128
    float* e1bv    = e1v + 128;                // 128
    float* e2v     = e1bv + 128;               // 128
    float* x0g     = e2v + 128;                // G*128
    float* x1g     = x0g + Gg * 128;           // G*512
    float* x2g     = x1g + Gg * 512;           // G*256

    // phist aliases bufB: consumed by reduce_norm before spmm2 writes bufB
    unsigned int* phist = (unsigned int*)bufB;   // [2*HB][HWORDS] = 3.2 MB

    // ---- CSR build + piggybacked weight-chain precompute ----
    hist_kernel<<<HIST_BLOCKS + W12_BLOCKS + 1, 1024, 0, stream>>>(
        src, dst, phist, W1, W2, W3, b1, b2, W12v, e1v, e2v);
    reduce_norm_kernel<<<RN_BLOCKS + W123_BLOCKS + 1, 256, 0, stream>>>(
        phist, ideg, srcn, dstn, pq, W12v, W3, e1v, W123v, e1bv);
    scanA<<<NCHUNK, 256, 0, stream>>>(ideg, row_ptr, bsum);
    scanB<<<1, 64, 0, stream>>>(bsum);
    scanC<<<(Nn + 255) / 256, 256, 0, stream>>>(row_ptr, bsum, cursor);
    fill_kernel<<<(Ee + 255) / 256, 256, 0, stream>>>(src, dst, cursor, csr_src);

    int sblocks = (Nn + 7) / 8;

    // v1 = A(srcn*x), w1 = A srcn
    spmm_kernel<<<sblocks, 256, 0, stream>>>(inputs, row_ptr, csr_src, srcn,
                                             nullptr, bufA, w1v);
    // v2 = A(pq*v1), w2 = A(pq*w1)
    spmm_kernel<<<sblocks, 256, 0, stream>>>(bufA, row_ptr, csr_src, pq,
                                             w1v, bufB, w2v);
    // v3 = A(pq*v2)
    spmm_kernel<<<sblocks, 256, 0, stream>>>(bufB, row_ptr, csr_src, pq,
                                             nullptr, bufA, nullptr);

    // pooling of v3, dn*w1, dn*w2
    hipMemsetAsync(pooled, 0, (Gg * Dd + 2 * Gg) * sizeof(float) + Gg * sizeof(int),
                   stream);
    pool_kernel<<<(Nn + 127) / 128, 256, 0, stream>>>(bufA, dstn, w1v, w2v, gid,
                                                      pooled, pw1, pw2, cnt);

    // head: x0 combine + 3 FC layers (multi-block, parallel weight fetch)
    x0_kernel<<<1, 1024, 0, stream>>>(pooled, pw1, pw2, cnt, W123v, e1bv, e2v,
                                      b3, x0g);
    fc1_kernel<<<32, 256, 0, stream>>>(x0g, Wc1, bc1, x1g);
    fc2_kernel<<<32, 256, 0, stream>>>(x1g, Wc2, bc2, x2g);
    fc3_kernel<<<1, 640, 0, stream>>>(x2g, Wc3, bc3, (float*)d_out);
}

// Round 9
// 203.066 us; speedup vs baseline: 17.4880x; 1.1873x over previous
//
#include <hip/hip_runtime.h>

#define Nn 50000
#define Ee 600000
#define Gg 8
#define Dd 128
#define NP 50048            // padded N for ws layout
#define SCHUNK 1024
#define NCHUNK ((Nn + SCHUNK - 1) / SCHUNK)   // 49

#define HWORDS 25024        // ceil(N/2); 2x16-bit counters per word
#define HB 16               // edge-chunks per endpoint array
#define HIST_BLOCKS (2 * HB)          // 32
#define W12_BLOCKS 16
#define RN_BLOCKS ((HWORDS + 255) / 256)   // 98
#define W123_BLOCKS 64
#define PBLK ((Nn + 127) / 128)       // 391 dotpool blocks
#define RBLK 32
#define RCHUNK ((PBLK + RBLK - 1) / RBLK)  // 13

// ---------------- hist + piggyback W12/e1/e2 on idle CUs ----------------
__global__ __launch_bounds__(1024) void hist_kernel(
    const int* __restrict__ src, const int* __restrict__ dst,
    unsigned int* __restrict__ phist,
    const float* __restrict__ W1, const float* __restrict__ W2,
    const float* __restrict__ W3, const float* __restrict__ b1,
    const float* __restrict__ b2,
    float* __restrict__ W12, float* __restrict__ e1, float* __restrict__ e2)
{
    __shared__ unsigned int h[HWORDS];
    int t = threadIdx.x;
    int b = blockIdx.x;

    if (b < HIST_BLOCKS) {
        for (int i = t; i < HWORDS; i += 1024) h[i] = 0u;
        __syncthreads();
        int part = b >> 1;
        const int* arr = (b & 1) ? dst : src;
        int e0 = part * (Ee / HB);
        int eN = e0 + (Ee / HB);
        for (int e = e0 + t; e < eN; e += 1024) {
            int n = arr[e];
            atomicAdd(&h[n >> 1], 1u << ((n & 1) << 4));
        }
        __syncthreads();
        unsigned int* out = phist + (size_t)b * HWORDS;
        for (int i = t; i < HWORDS; i += 1024) out[i] = h[i];
    } else if (b < HIST_BLOCKS + W12_BLOCKS) {
        int j = (b - HIST_BLOCKS) * 8 + (t & 7);
        int k = t >> 3;
        float a = 0.f;
#pragma unroll 8
        for (int m = 0; m < 128; ++m) a += W1[k * 128 + m] * W2[m * 128 + j];
        W12[k * 128 + j] = a;
    } else {
        if (t < 128) {
            float a = 0.f;
#pragma unroll 8
            for (int k = 0; k < 128; ++k) a += b1[k] * W2[k * 128 + t];
            e1[t] = a;
        } else if (t < 256) {
            int c = t - 128;
            float a = 0.f;
#pragma unroll 8
            for (int k = 0; k < 128; ++k) a += b2[k] * W3[k * 128 + c];
            e2[c] = a;
        }
    }
}

// ---------------- reduce partials -> odeg, srcn, pq, z, cnt (+W123/e1b) ----
// z[n][g] = (gid[n]==g) ? dn[n] : 0   (the 8 pooling seed vectors)
__global__ __launch_bounds__(256) void reduce_norm_kernel(
    const unsigned int* __restrict__ phist, const int* __restrict__ gid,
    int* __restrict__ odeg, float* __restrict__ srcn, float* __restrict__ pq,
    float* __restrict__ z, int* __restrict__ cnt,
    const float* __restrict__ W12, const float* __restrict__ W3,
    const float* __restrict__ e1,
    float* __restrict__ W123, float* __restrict__ e1b)
{
    int b = blockIdx.x, t = threadIdx.x;
    if (b < RN_BLOCKS) {
        __shared__ int lc[Gg];
        if (t < Gg) lc[t] = 0;
        __syncthreads();
        int i = b * 256 + t;
        if (i < HWORDS) {
            unsigned int so0 = 0, so1 = 0, si0 = 0, si1 = 0;
#pragma unroll
            for (int p = 0; p < HB; ++p) {
                unsigned int a = phist[(size_t)(2 * p) * HWORDS + i];
                unsigned int bb = phist[(size_t)(2 * p + 1) * HWORDS + i];
                so0 += a & 0xffffu; so1 += a >> 16;
                si0 += bb & 0xffffu; si1 += bb >> 16;
            }
#pragma unroll
            for (int hh = 0; hh < 2; ++hh) {
                int n = 2 * i + hh;
                unsigned int so = hh ? so1 : so0, si = hh ? si1 : si0;
                if (n < Nn) {
                    odeg[n] = (int)so;
                    float sn = 1.f / sqrtf(fmaxf((float)so, 1.f));
                    float dn = 1.f / sqrtf(fmaxf((float)si, 1.f));
                    srcn[n] = sn; pq[n] = sn * dn;
                    int g = gid[n];
                    atomicAdd(&lc[g], 1);
                    float zr[8];
#pragma unroll
                    for (int gg = 0; gg < 8; ++gg) zr[gg] = (gg == g) ? dn : 0.f;
                    *(float4*)(z + (size_t)n * 8)     = *(float4*)zr;
                    *(float4*)(z + (size_t)n * 8 + 4) = *(float4*)(zr + 4);
                }
            }
        }
        __syncthreads();
        if (t < Gg && lc[t] > 0) atomicAdd(&cnt[t], lc[t]);
    } else if (b < RN_BLOCKS + W123_BLOCKS) {
        int j = (b - RN_BLOCKS) * 2 + (t & 1);
        int k = t >> 1;
        float a = 0.f;
#pragma unroll 8
        for (int m = 0; m < 128; ++m) a += W12[k * 128 + m] * W3[m * 128 + j];
        W123[k * 128 + j] = a;
    } else {
        if (t < 128) {
            float a = 0.f;
#pragma unroll 8
            for (int k = 0; k < 128; ++k) a += e1[k] * W3[k * 128 + t];
            e1b[t] = a;
        }
    }
}

// ---------------- prefix scan (exclusive) of odeg -> row_ptr ---------------
__global__ __launch_bounds__(256) void scanA(
    const int* __restrict__ deg, int* __restrict__ row_ptr, int* __restrict__ bsum)
{
    __shared__ int tsum[256];
    int b = blockIdx.x, t = threadIdx.x;
    int base = b * SCHUNK + t * 4;
    int v[4]; int s = 0;
#pragma unroll
    for (int i = 0; i < 4; ++i) {
        int idx = base + i;
        v[i] = (idx < Nn) ? deg[idx] : 0;
        s += v[i];
    }
    tsum[t] = s;
    __syncthreads();
    for (int off = 1; off < 256; off <<= 1) {
        int x = (t >= off) ? tsum[t - off] : 0;
        __syncthreads();
        tsum[t] += x;
        __syncthreads();
    }
    int run = tsum[t] - s;
#pragma unroll
    for (int i = 0; i < 4; ++i) {
        int idx = base + i;
        if (idx < Nn) row_ptr[idx] = run;
        run += v[i];
    }
    if (t == 255) bsum[b] = tsum[255];
}

__global__ void scanB(int* __restrict__ bsum)
{
    int t = threadIdx.x;
    int v = (t < NCHUNK) ? bsum[t] : 0;
    int orig = v;
    for (int off = 1; off < 64; off <<= 1) {
        int x = __shfl_up(v, off, 64);
        if (t >= off) v += x;
    }
    if (t < NCHUNK) bsum[t] = v - orig;
}

__global__ __launch_bounds__(256) void scanC(
    int* __restrict__ row_ptr, const int* __restrict__ bsum, int* __restrict__ cursor)
{
    int n = blockIdx.x * 256 + threadIdx.x;
    if (n >= Nn) return;
    int v = row_ptr[n] + bsum[n / SCHUNK];
    row_ptr[n] = v;
    cursor[n] = v;
    if (n == 0) row_ptr[Nn] = Ee;
}

// ---------------- CSR-by-src fill: csr_dst[pos] = dst ----------------------
__global__ __launch_bounds__(256) void fill_kernel(
    const int* __restrict__ src, const int* __restrict__ dst,
    int* __restrict__ cursor, int* __restrict__ csr_dst)
{
    int e = blockIdx.x * 256 + threadIdx.x;
    if (e >= Ee) return;
    int pos = atomicAdd(&cursor[src[e]], 1);
    csr_dst[pos] = dst[e];
}

// ---------------- backward SpMM (N x 8): uout[m][g] = sum scal*uin[dst][g] --
// 8 lanes per node (one per g); optional pw accumulation: pw_g += sn[m]*uout[m][g]
__global__ __launch_bounds__(256) void bspmm_kernel(
    const float* __restrict__ uin, const int* __restrict__ row_ptr,
    const int* __restrict__ csr, const float* __restrict__ scal,
    float* __restrict__ uout, const float* __restrict__ sn,
    float* __restrict__ pwout)
{
    int t = threadIdx.x;
    int m = blockIdx.x * 32 + (t >> 3);
    int g = t & 7;
    float acc = 0.f, snm = 0.f;
    if (m < Nn) {
        int beg = row_ptr[m], end = row_ptr[m + 1];
        float a0 = 0.f, a1 = 0.f;
        int j = beg;
        if (scal) {
            for (; j + 1 < end; j += 2) {
                int i0 = csr[j], i1 = csr[j + 1];
                a0 += scal[i0] * uin[(size_t)i0 * 8 + g];
                a1 += scal[i1] * uin[(size_t)i1 * 8 + g];
            }
            if (j < end) { int i0 = csr[j]; a0 += scal[i0] * uin[(size_t)i0 * 8 + g]; }
        } else {
            for (; j + 1 < end; j += 2) {
                int i0 = csr[j], i1 = csr[j + 1];
                a0 += uin[(size_t)i0 * 8 + g];
                a1 += uin[(size_t)i1 * 8 + g];
            }
            if (j < end) a0 += uin[(size_t)csr[j] * 8 + g];
        }
        acc = a0 + a1;
        uout[(size_t)m * 8 + g] = acc;
        if (pwout) snm = sn[m];
    }
    if (pwout) {
        __shared__ float red[Gg];
        if (t < Gg) red[t] = 0.f;
        __syncthreads();
        atomicAdd(&red[g], snm * acc);
        __syncthreads();
        if (t < Gg) atomicAdd(&pwout[t], red[t]);
    }
}

// ---------------- dense dot-pool: partial[b][g][c] = sum_n f[n][g]*x[n][c] --
// f[n][g] = sn[n]*u3[n][g]; x read once, coalesced.
__global__ __launch_bounds__(256) void dotpool_kernel(
    const float* __restrict__ x, const float* __restrict__ u3,
    const float* __restrict__ sn, float* __restrict__ partial)
{
    __shared__ float f[128][Gg];
    __shared__ float sp[Gg][Dd];
    int t = threadIdx.x;
    int n0 = blockIdx.x * 128;
    if (t < 128) {
        int n = n0 + t;
        float s = 0.f;
        float4 a = {0.f, 0.f, 0.f, 0.f}, b = {0.f, 0.f, 0.f, 0.f};
        if (n < Nn) {
            s = sn[n];
            a = *(const float4*)(u3 + (size_t)n * 8);
            b = *(const float4*)(u3 + (size_t)n * 8 + 4);
        }
        f[t][0] = s * a.x; f[t][1] = s * a.y; f[t][2] = s * a.z; f[t][3] = s * a.w;
        f[t][4] = s * b.x; f[t][5] = s * b.y; f[t][6] = s * b.z; f[t][7] = s * b.w;
    }
    for (int i = t; i < Gg * Dd; i += 256) ((float*)sp)[i] = 0.f;
    __syncthreads();

    int r0 = t >> 5, c = t & 31;
    float4 acc[Gg];
#pragma unroll
    for (int g = 0; g < Gg; ++g) acc[g] = make_float4(0.f, 0.f, 0.f, 0.f);
    for (int i = r0; i < 128; i += 8) {
        int n = n0 + i;
        if (n >= Nn) break;
        float4 xv = ((const float4*)x)[(size_t)n * 32 + c];
#pragma unroll
        for (int g = 0; g < Gg; ++g) {
            float fv = f[i][g];
            acc[g].x += fv * xv.x; acc[g].y += fv * xv.y;
            acc[g].z += fv * xv.z; acc[g].w += fv * xv.w;
        }
    }
#pragma unroll
    for (int g = 0; g < Gg; ++g) {
        atomicAdd(&sp[g][c * 4 + 0], acc[g].x);
        atomicAdd(&sp[g][c * 4 + 1], acc[g].y);
        atomicAdd(&sp[g][c * 4 + 2], acc[g].z);
        atomicAdd(&sp[g][c * 4 + 3], acc[g].w);
    }
    __syncthreads();
    float* out = partial + (size_t)blockIdx.x * Gg * Dd;
    for (int i = t; i < Gg * Dd; i += 256) out[i] = ((float*)sp)[i];
}

// ---------------- reduce partials -> pooled -------------------------------
__global__ __launch_bounds__(256) void dotreduce_kernel(
    const float* __restrict__ partial, float* __restrict__ pooled)
{
    int t = threadIdx.x;
    int b0 = blockIdx.x * RCHUNK;
    int b1 = b0 + RCHUNK; if (b1 > PBLK) b1 = PBLK;
    for (int i = t; i < Gg * Dd; i += 256) {
        float a = 0.f;
        for (int b = b0; b < b1; ++b) a += partial[(size_t)b * Gg * Dd + i];
        atomicAdd(&pooled[i], a);
    }
}

// ---------------- head: x0 = (P@W123)/cnt + pw2*e1b + pw1*e2 + b3 ---------
__global__ __launch_bounds__(1024) void x0_kernel(
    const float* __restrict__ pooled, const float* __restrict__ pw1r,
    const float* __restrict__ pw2r, const int* __restrict__ cnt,
    const float* __restrict__ W123, const float* __restrict__ e1b,
    const float* __restrict__ e2, const float* __restrict__ b3,
    float* __restrict__ x0g)
{
    int t = threadIdx.x;
    int g = t >> 7, c = t & 127;
    float a = 0.f;
#pragma unroll 8
    for (int k = 0; k < 128; ++k) a += pooled[g * 128 + k] * W123[k * 128 + c];
    float inv = 1.f / fmaxf((float)cnt[g], 1.f);
    x0g[t] = a * inv + (pw2r[g] * inv) * e1b[c] + (pw1r[g] * inv) * e2[c] + b3[c];
}

// ---------------- head: fc1 (128->512), 32 blocks -------------------------
__global__ __launch_bounds__(256) void fc1_kernel(
    const float* __restrict__ x0g, const float* __restrict__ Wc1,
    const float* __restrict__ bc1, float* __restrict__ x1g)
{
    __shared__ float xs[Gg * 128];
    __shared__ float par[256];
    int t = threadIdx.x;
    for (int i = t; i < Gg * 128; i += 256) xs[i] = x0g[i];
    __syncthreads();
    int h = t >> 7, rem = t & 127;
    int g = rem >> 4, m = blockIdx.x * 16 + (rem & 15);
    int k0 = h * 64;
    float a = 0.f;
#pragma unroll 16
    for (int k = 0; k < 64; ++k) a += xs[g * 128 + k0 + k] * Wc1[(size_t)(k0 + k) * 512 + m];
    par[t] = a;
    __syncthreads();
    if (t < 128) {
        float v = par[t] + par[t + 128] + bc1[m];
        x1g[g * 512 + m] = v > 0.f ? v : 0.01f * v;
    }
}

// ---------------- head: fc2 (512->256), 32 blocks -------------------------
__global__ __launch_bounds__(256) void fc2_kernel(
    const float* __restrict__ x1g, const float* __restrict__ Wc2,
    const float* __restrict__ bc2, float* __restrict__ x2g)
{
    __shared__ float xs[Gg * 512];
    __shared__ float par[256];
    int t = threadIdx.x;
    for (int i = t; i < Gg * 512; i += 256) xs[i] = x1g[i];
    __syncthreads();
    int q = t >> 6, rem = t & 63;
    int g = rem >> 3, m = blockIdx.x * 8 + (rem & 7);
    int k0 = q * 128;
    float a = 0.f;
#pragma unroll 16
    for (int k = 0; k < 128; ++k) a += xs[g * 512 + k0 + k] * Wc2[(size_t)(k0 + k) * 256 + m];
    par[t] = a;
    __syncthreads();
    if (t < 64) {
        float v = par[t] + par[t + 64] + par[t + 128] + par[t + 192] + bc2[m];
        x2g[g * 256 + m] = v > 0.f ? v : 0.01f * v;
    }
}

// ---------------- head: fc3 (256->10), 1 block ----------------------------
__global__ __launch_bounds__(640) void fc3_kernel(
    const float* __restrict__ x2g, const float* __restrict__ Wc3,
    const float* __restrict__ bc3, float* __restrict__ out)
{
    __shared__ float xs[Gg * 256];
    int t = threadIdx.x;
    for (int i = t; i < Gg * 256; i += 640) xs[i] = x2g[i];
    __syncthreads();
    int w = t >> 6, lane = t & 63;
    if (w < 10) {
        float acc[Gg];
#pragma unroll
        for (int g = 0; g < Gg; ++g) acc[g] = 0.f;
#pragma unroll
        for (int kk = 0; kk < 4; ++kk) {
            int k = lane + kk * 64;
            float wv = Wc3[(size_t)k * 10 + w];
#pragma unroll
            for (int g = 0; g < Gg; ++g) acc[g] += xs[g * 256 + k] * wv;
        }
#pragma unroll
        for (int g = 0; g < Gg; ++g) {
            float v = acc[g];
            for (int off = 32; off; off >>= 1) v += __shfl_down(v, off, 64);
            if (lane == 0) {
                v += bc3[w];
                out[g * 10 + w] = v > 0.f ? v : 0.01f * v;
            }
        }
    }
}

extern "C" void kernel_launch(void* const* d_in, const int* in_sizes, int n_in,
                              void* d_out, int out_size, void* d_ws, size_t ws_size,
                              hipStream_t stream)
{
    const float* inputs = (const float*)d_in[0];
    const int*   src    = (const int*)d_in[1];
    const int*   dst    = (const int*)d_in[2];
    const int*   gid    = (const int*)d_in[3];
    const float* W1  = (const float*)d_in[4];
    const float* b1  = (const float*)d_in[5];
    const float* W2  = (const float*)d_in[6];
    const float* b2  = (const float*)d_in[7];
    const float* W3  = (const float*)d_in[8];
    const float* b3  = (const float*)d_in[9];
    const float* Wc1 = (const float*)d_in[10];
    const float* bc1 = (const float*)d_in[11];
    const float* Wc2 = (const float*)d_in[12];
    const float* bc2 = (const float*)d_in[13];
    const float* Wc3 = (const float*)d_in[14];
    const float* bc3 = (const float*)d_in[15];

    // ---- workspace layout ----
    int*   wi      = (int*)d_ws;
    int*   odeg    = wi;                       // NP
    int*   row_ptr = odeg + NP;                // NP (uses N+1)
    int*   cursor  = row_ptr + NP;             // NP
    int*   bsum    = cursor + NP;              // 64
    int*   csr_dst = bsum + 64;                // Ee
    float* wf      = (float*)(csr_dst + Ee);
    float* srcn    = wf;                       // NP
    float* pq      = srcn + NP;                // NP
    float* z       = pq + NP;                  // NP*8
    float* u1      = z + (size_t)NP * 8;       // NP*8
    float* u2      = u1 + (size_t)NP * 8;      // NP*8
    float* u3      = u2 + (size_t)NP * 8;      // NP*8
    float* partial = u3 + (size_t)NP * 8;      // PBLK*1024
    float* pooled  = partial + (size_t)PBLK * Gg * Dd;  // 1024
    float* pw1     = pooled + Gg * Dd;         // 8
    float* pw2     = pw1 + Gg;                 // 8
    int*   cnt     = (int*)(pw2 + Gg);         // 8
    float* W12v    = (float*)(cnt + Gg);       // 128*128
    float* W123v   = W12v + 128 * 128;         // 128*128
    float* e1v     = W123v + 128 * 128;        // 128
    float* e1bv    = e1v + 128;                // 128
    float* e2v     = e1bv + 128;               // 128
    float* x0g     = e2v + 128;                // G*128
    float* x1g     = x0g + Gg * 128;           // G*512
    float* x2g     = x1g + Gg * 512;           // G*256
    unsigned int* phist = (unsigned int*)(x2g + Gg * 256);  // 32*HWORDS

    // zero the accumulators (pooled, pw1, pw2, cnt) in one contiguous memset
    hipMemsetAsync(pooled, 0, (Gg * Dd + 2 * Gg) * sizeof(float) + Gg * sizeof(int),
                   stream);

    // ---- degrees + norms + z seeds + CSR-by-src (piggybacked W-chain) ----
    hist_kernel<<<HIST_BLOCKS + W12_BLOCKS + 1, 1024, 0, stream>>>(
        src, dst, phist, W1, W2, W3, b1, b2, W12v, e1v, e2v);
    reduce_norm_kernel<<<RN_BLOCKS + W123_BLOCKS + 1, 256, 0, stream>>>(
        phist, gid, odeg, srcn, pq, z, cnt, W12v, W3, e1v, W123v, e1bv);
    scanA<<<NCHUNK, 256, 0, stream>>>(odeg, row_ptr, bsum);
    scanB<<<1, 64, 0, stream>>>(bsum);
    scanC<<<(Nn + 255) / 256, 256, 0, stream>>>(row_ptr, bsum, cursor);
    fill_kernel<<<(Ee + 255) / 256, 256, 0, stream>>>(src, dst, cursor, csr_dst);

    // ---- backward chain: u1 = A^T z ; u2 = A^T(pq*u1) ; u3 = A^T(pq*u2) ----
    int bblocks = (Nn + 31) / 32;
    bspmm_kernel<<<bblocks, 256, 0, stream>>>(z, row_ptr, csr_dst, nullptr,
                                              u1, srcn, pw1);
    bspmm_kernel<<<bblocks, 256, 0, stream>>>(u1, row_ptr, csr_dst, pq,
                                              u2, srcn, pw2);
    bspmm_kernel<<<bblocks, 256, 0, stream>>>(u2, row_ptr, csr_dst, pq,
                                              u3, nullptr, nullptr);

    // ---- pooled[g][c] = sum_n sn[n]*u3[n][g] * x[n][c] (dense read of x) ----
    dotpool_kernel<<<PBLK, 256, 0, stream>>>(inputs, u3, srcn, partial);
    dotreduce_kernel<<<RBLK, 256, 0, stream>>>(partial, pooled);

    // ---- head ----
    x0_kernel<<<1, 1024, 0, stream>>>(pooled, pw1, pw2, cnt, W123v, e1bv, e2v,
                                      b3, x0g);
    fc1_kernel<<<32, 256, 0, stream>>>(x0g, Wc1, bc1, x1g);
    fc2_kernel<<<32, 256, 0, stream>>>(x1g, Wc2, bc2, x2g);
    fc3_kernel<<<1, 640, 0, stream>>>(x2g, Wc3, bc3, (float*)d_out);
}

// Round 10
// 198.258 us; speedup vs baseline: 17.9120x; 1.0242x over previous
//
#include <hip/hip_runtime.h>

#define Nn 50000
#define Ee 600000
#define Gg 8
#define Dd 128
#define NP 50048            // padded N for ws layout
#define SCHUNK 1024
#define NCHUNK ((Nn + SCHUNK - 1) / SCHUNK)   // 49

#define HWORDS 25024        // ceil(N/2); 2x16-bit counters per word
#define HB 16               // edge-chunks per endpoint array
#define HIST_BLOCKS (2 * HB)          // 32
#define W12_BLOCKS 16
#define RN_BLOCKS ((HWORDS + 255) / 256)   // 98
#define W123_BLOCKS 64
#define PBLK ((Nn + 127) / 128)       // 391 dotpool blocks

// ---------------- hist + piggyback W12/e1/e2 + accumulator zeroing --------
__global__ __launch_bounds__(1024) void hist_kernel(
    const int* __restrict__ src, const int* __restrict__ dst,
    unsigned int* __restrict__ phist,
    const float* __restrict__ W1, const float* __restrict__ W2,
    const float* __restrict__ W3, const float* __restrict__ b1,
    const float* __restrict__ b2,
    float* __restrict__ W12, float* __restrict__ e1, float* __restrict__ e2,
    float* __restrict__ accz)     // pw1(8), pw2(8), cnt(8) -> 24 words to zero
{
    __shared__ unsigned int h[HWORDS];
    int t = threadIdx.x;
    int b = blockIdx.x;

    if (b < HIST_BLOCKS) {
        for (int i = t; i < HWORDS; i += 1024) h[i] = 0u;
        __syncthreads();
        int part = b >> 1;
        const int* arr = (b & 1) ? dst : src;
        int e0 = part * (Ee / HB);
        int eN = e0 + (Ee / HB);
        for (int e = e0 + t; e < eN; e += 1024) {
            int n = arr[e];
            atomicAdd(&h[n >> 1], 1u << ((n & 1) << 4));
        }
        __syncthreads();
        unsigned int* out = phist + (size_t)b * HWORDS;
        for (int i = t; i < HWORDS; i += 1024) out[i] = h[i];
    } else if (b < HIST_BLOCKS + W12_BLOCKS) {
        int j = (b - HIST_BLOCKS) * 8 + (t & 7);
        int k = t >> 3;
        float a = 0.f;
#pragma unroll 8
        for (int m = 0; m < 128; ++m) a += W1[k * 128 + m] * W2[m * 128 + j];
        W12[k * 128 + j] = a;
    } else {
        if (t < 128) {
            float a = 0.f;
#pragma unroll 8
            for (int k = 0; k < 128; ++k) a += b1[k] * W2[k * 128 + t];
            e1[t] = a;
        } else if (t < 256) {
            int c = t - 128;
            float a = 0.f;
#pragma unroll 8
            for (int k = 0; k < 128; ++k) a += b2[k] * W3[k * 128 + c];
            e2[c] = a;
        } else if (t < 256 + 24) {
            accz[t - 256] = 0.f;          // zero pw1, pw2, cnt
        }
    }
}

// ---------------- reduce partials -> odeg, srcn, pq, z, cnt (+W123/e1b) ----
// z[n][g] = (gid[n]==g) ? dn[n] : 0   (the 8 pooling seed vectors)
__global__ __launch_bounds__(256) void reduce_norm_kernel(
    const unsigned int* __restrict__ phist, const int* __restrict__ gid,
    int* __restrict__ odeg, float* __restrict__ srcn, float* __restrict__ pq,
    float* __restrict__ z, int* __restrict__ cnt,
    const float* __restrict__ W12, const float* __restrict__ W3,
    const float* __restrict__ e1,
    float* __restrict__ W123, float* __restrict__ e1b)
{
    int b = blockIdx.x, t = threadIdx.x;
    if (b < RN_BLOCKS) {
        __shared__ int lc[Gg];
        if (t < Gg) lc[t] = 0;
        __syncthreads();
        int i = b * 256 + t;
        if (i < HWORDS) {
            unsigned int so0 = 0, so1 = 0, si0 = 0, si1 = 0;
#pragma unroll
            for (int p = 0; p < HB; ++p) {
                unsigned int a = phist[(size_t)(2 * p) * HWORDS + i];
                unsigned int bb = phist[(size_t)(2 * p + 1) * HWORDS + i];
                so0 += a & 0xffffu; so1 += a >> 16;
                si0 += bb & 0xffffu; si1 += bb >> 16;
            }
#pragma unroll
            for (int hh = 0; hh < 2; ++hh) {
                int n = 2 * i + hh;
                unsigned int so = hh ? so1 : so0, si = hh ? si1 : si0;
                if (n < Nn) {
                    odeg[n] = (int)so;
                    float sn = 1.f / sqrtf(fmaxf((float)so, 1.f));
                    float dn = 1.f / sqrtf(fmaxf((float)si, 1.f));
                    srcn[n] = sn; pq[n] = sn * dn;
                    int g = gid[n];
                    atomicAdd(&lc[g], 1);
                    float zr[8];
#pragma unroll
                    for (int gg = 0; gg < 8; ++gg) zr[gg] = (gg == g) ? dn : 0.f;
                    *(float4*)(z + (size_t)n * 8)     = *(float4*)zr;
                    *(float4*)(z + (size_t)n * 8 + 4) = *(float4*)(zr + 4);
                }
            }
        }
        __syncthreads();
        if (t < Gg && lc[t] > 0) atomicAdd(&cnt[t], lc[t]);
    } else if (b < RN_BLOCKS + W123_BLOCKS) {
        int j = (b - RN_BLOCKS) * 2 + (t & 1);
        int k = t >> 1;
        float a = 0.f;
#pragma unroll 8
        for (int m = 0; m < 128; ++m) a += W12[k * 128 + m] * W3[m * 128 + j];
        W123[k * 128 + j] = a;
    } else {
        if (t < 128) {
            float a = 0.f;
#pragma unroll 8
            for (int k = 0; k < 128; ++k) a += e1[k] * W3[k * 128 + t];
            e1b[t] = a;
        }
    }
}

// ---------------- prefix scan (exclusive) of odeg -> row_ptr ---------------
__global__ __launch_bounds__(256) void scanA(
    const int* __restrict__ deg, int* __restrict__ row_ptr, int* __restrict__ bsum)
{
    __shared__ int tsum[256];
    int b = blockIdx.x, t = threadIdx.x;
    int base = b * SCHUNK + t * 4;
    int v[4]; int s = 0;
#pragma unroll
    for (int i = 0; i < 4; ++i) {
        int idx = base + i;
        v[i] = (idx < Nn) ? deg[idx] : 0;
        s += v[i];
    }
    tsum[t] = s;
    __syncthreads();
    for (int off = 1; off < 256; off <<= 1) {
        int x = (t >= off) ? tsum[t - off] : 0;
        __syncthreads();
        tsum[t] += x;
        __syncthreads();
    }
    int run = tsum[t] - s;
#pragma unroll
    for (int i = 0; i < 4; ++i) {
        int idx = base + i;
        if (idx < Nn) row_ptr[idx] = run;
        run += v[i];
    }
    if (t == 255) bsum[b] = tsum[255];
}

__global__ void scanB(int* __restrict__ bsum)
{
    int t = threadIdx.x;
    int v = (t < NCHUNK) ? bsum[t] : 0;
    int orig = v;
    for (int off = 1; off < 64; off <<= 1) {
        int x = __shfl_up(v, off, 64);
        if (t >= off) v += x;
    }
    if (t < NCHUNK) bsum[t] = v - orig;
}

__global__ __launch_bounds__(256) void scanC(
    int* __restrict__ row_ptr, const int* __restrict__ bsum, int* __restrict__ cursor)
{
    int n = blockIdx.x * 256 + threadIdx.x;
    if (n >= Nn) return;
    int v = row_ptr[n] + bsum[n / SCHUNK];
    row_ptr[n] = v;
    cursor[n] = v;
    if (n == 0) row_ptr[Nn] = Ee;
}

// ---------------- CSR-by-src fill: csr_dst[pos] = dst ----------------------
__global__ __launch_bounds__(256) void fill_kernel(
    const int* __restrict__ src, const int* __restrict__ dst,
    int* __restrict__ cursor, int* __restrict__ csr_dst)
{
    int e = blockIdx.x * 256 + threadIdx.x;
    if (e >= Ee) return;
    int pos = atomicAdd(&cursor[src[e]], 1);
    csr_dst[pos] = dst[e];
}

// ---------------- backward SpMM (N x 8): uout[m][g] = sum scal*uin[dst][g] --
__global__ __launch_bounds__(256) void bspmm_kernel(
    const float* __restrict__ uin, const int* __restrict__ row_ptr,
    const int* __restrict__ csr, const float* __restrict__ scal,
    float* __restrict__ uout, const float* __restrict__ sn,
    float* __restrict__ pwout)
{
    int t = threadIdx.x;
    int m = blockIdx.x * 32 + (t >> 3);
    int g = t & 7;
    float acc = 0.f, snm = 0.f;
    if (m < Nn) {
        int beg = row_ptr[m], end = row_ptr[m + 1];
        float a0 = 0.f, a1 = 0.f;
        int j = beg;
        if (scal) {
            for (; j + 1 < end; j += 2) {
                int i0 = csr[j], i1 = csr[j + 1];
                a0 += scal[i0] * uin[(size_t)i0 * 8 + g];
                a1 += scal[i1] * uin[(size_t)i1 * 8 + g];
            }
            if (j < end) { int i0 = csr[j]; a0 += scal[i0] * uin[(size_t)i0 * 8 + g]; }
        } else {
            for (; j + 1 < end; j += 2) {
                int i0 = csr[j], i1 = csr[j + 1];
                a0 += uin[(size_t)i0 * 8 + g];
                a1 += uin[(size_t)i1 * 8 + g];
            }
            if (j < end) a0 += uin[(size_t)csr[j] * 8 + g];
        }
        acc = a0 + a1;
        uout[(size_t)m * 8 + g] = acc;
        if (pwout) snm = sn[m];
    }
    if (pwout) {
        __shared__ float red[Gg];
        if (t < Gg) red[t] = 0.f;
        __syncthreads();
        atomicAdd(&red[g], snm * acc);
        __syncthreads();
        if (t < Gg) atomicAdd(&pwout[t], red[t]);
    }
}

// ---------------- dense dot-pool: partial[b][g][c] = sum_n f[n][g]*x[n][c] --
__global__ __launch_bounds__(256) void dotpool_kernel(
    const float* __restrict__ x, const float* __restrict__ u3,
    const float* __restrict__ sn, float* __restrict__ partial)
{
    __shared__ float f[128][Gg];
    __shared__ float sp[Gg][Dd];
    int t = threadIdx.x;
    int n0 = blockIdx.x * 128;
    if (t < 128) {
        int n = n0 + t;
        float s = 0.f;
        float4 a = {0.f, 0.f, 0.f, 0.f}, b = {0.f, 0.f, 0.f, 0.f};
        if (n < Nn) {
            s = sn[n];
            a = *(const float4*)(u3 + (size_t)n * 8);
            b = *(const float4*)(u3 + (size_t)n * 8 + 4);
        }
        f[t][0] = s * a.x; f[t][1] = s * a.y; f[t][2] = s * a.z; f[t][3] = s * a.w;
        f[t][4] = s * b.x; f[t][5] = s * b.y; f[t][6] = s * b.z; f[t][7] = s * b.w;
    }
    for (int i = t; i < Gg * Dd; i += 256) ((float*)sp)[i] = 0.f;
    __syncthreads();

    int r0 = t >> 5, c = t & 31;
    float4 acc[Gg];
#pragma unroll
    for (int g = 0; g < Gg; ++g) acc[g] = make_float4(0.f, 0.f, 0.f, 0.f);
    for (int i = r0; i < 128; i += 8) {
        int n = n0 + i;
        if (n >= Nn) break;
        float4 xv = ((const float4*)x)[(size_t)n * 32 + c];
#pragma unroll
        for (int g = 0; g < Gg; ++g) {
            float fv = f[i][g];
            acc[g].x += fv * xv.x; acc[g].y += fv * xv.y;
            acc[g].z += fv * xv.z; acc[g].w += fv * xv.w;
        }
    }
#pragma unroll
    for (int g = 0; g < Gg; ++g) {
        atomicAdd(&sp[g][c * 4 + 0], acc[g].x);
        atomicAdd(&sp[g][c * 4 + 1], acc[g].y);
        atomicAdd(&sp[g][c * 4 + 2], acc[g].z);
        atomicAdd(&sp[g][c * 4 + 3], acc[g].w);
    }
    __syncthreads();
    float* out = partial + (size_t)blockIdx.x * Gg * Dd;
    for (int i = t; i < Gg * Dd; i += 256) out[i] = ((float*)sp)[i];
}

// ---------------- reduce partials -> pooled (direct write, no memset) ------
__global__ __launch_bounds__(256) void dotreduce_kernel(
    const float* __restrict__ partial, float* __restrict__ pooled)
{
    int i = blockIdx.x * 256 + threadIdx.x;    // 4 blocks x 256 = 1024 outputs
    float a0 = 0.f, a1 = 0.f, a2 = 0.f, a3 = 0.f;
    int b = 0;
    for (; b + 3 < PBLK; b += 4) {
        a0 += partial[(size_t)(b + 0) * Gg * Dd + i];
        a1 += partial[(size_t)(b + 1) * Gg * Dd + i];
        a2 += partial[(size_t)(b + 2) * Gg * Dd + i];
        a3 += partial[(size_t)(b + 3) * Gg * Dd + i];
    }
    for (; b < PBLK; ++b) a0 += partial[(size_t)b * Gg * Dd + i];
    pooled[i] = (a0 + a1) + (a2 + a3);
}

// ---------------- head: x0 = (P@W123)/cnt + pw2*e1b + pw1*e2 + b3 ---------
__global__ __launch_bounds__(1024) void x0_kernel(
    const float* __restrict__ pooled, const float* __restrict__ pw1r,
    const float* __restrict__ pw2r, const int* __restrict__ cnt,
    const float* __restrict__ W123, const float* __restrict__ e1b,
    const float* __restrict__ e2, const float* __restrict__ b3,
    float* __restrict__ x0g)
{
    int t = threadIdx.x;
    int g = t >> 7, c = t & 127;
    float a = 0.f;
#pragma unroll 8
    for (int k = 0; k < 128; ++k) a += pooled[g * 128 + k] * W123[k * 128 + c];
    float inv = 1.f / fmaxf((float)cnt[g], 1.f);
    x0g[t] = a * inv + (pw2r[g] * inv) * e1b[c] + (pw1r[g] * inv) * e2[c] + b3[c];
}

// ---------------- head: fc1 (128->512), 32 blocks -------------------------
__global__ __launch_bounds__(256) void fc1_kernel(
    const float* __restrict__ x0g, const float* __restrict__ Wc1,
    const float* __restrict__ bc1, float* __restrict__ x1g)
{
    __shared__ float xs[Gg * 128];
    __shared__ float par[256];
    int t = threadIdx.x;
    for (int i = t; i < Gg * 128; i += 256) xs[i] = x0g[i];
    __syncthreads();
    int h = t >> 7, rem = t & 127;
    int g = rem >> 4, m = blockIdx.x * 16 + (rem & 15);
    int k0 = h * 64;
    float a = 0.f;
#pragma unroll 16
    for (int k = 0; k < 64; ++k) a += xs[g * 128 + k0 + k] * Wc1[(size_t)(k0 + k) * 512 + m];
    par[t] = a;
    __syncthreads();
    if (t < 128) {
        float v = par[t] + par[t + 128] + bc1[m];
        x1g[g * 512 + m] = v > 0.f ? v : 0.01f * v;
    }
}

// ---------------- head: fc2 (512->256), 32 blocks -------------------------
__global__ __launch_bounds__(256) void fc2_kernel(
    const float* __restrict__ x1g, const float* __restrict__ Wc2,
    const float* __restrict__ bc2, float* __restrict__ x2g)
{
    __shared__ float xs[Gg * 512];
    __shared__ float par[256];
    int t = threadIdx.x;
    for (int i = t; i < Gg * 512; i += 256) xs[i] = x1g[i];
    __syncthreads();
    int q = t >> 6, rem = t & 63;
    int g = rem >> 3, m = blockIdx.x * 8 + (rem & 7);
    int k0 = q * 128;
    float a = 0.f;
#pragma unroll 16
    for (int k = 0; k < 128; ++k) a += xs[g * 512 + k0 + k] * Wc2[(size_t)(k0 + k) * 256 + m];
    par[t] = a;
    __syncthreads();
    if (t < 64) {
        float v = par[t] + par[t + 64] + par[t + 128] + par[t + 192] + bc2[m];
        x2g[g * 256 + m] = v > 0.f ? v : 0.01f * v;
    }
}

// ---------------- head: fc3 (256->10), 1 block ----------------------------
__global__ __launch_bounds__(640) void fc3_kernel(
    const float* __restrict__ x2g, const float* __restrict__ Wc3,
    const float* __restrict__ bc3, float* __restrict__ out)
{
    __shared__ float xs[Gg * 256];
    int t = threadIdx.x;
    for (int i = t; i < Gg * 256; i += 640) xs[i] = x2g[i];
    __syncthreads();
    int w = t >> 6, lane = t & 63;
    if (w < 10) {
        float acc[Gg];
#pragma unroll
        for (int g = 0; g < Gg; ++g) acc[g] = 0.f;
#pragma unroll
        for (int kk = 0; kk < 4; ++kk) {
            int k = lane + kk * 64;
            float wv = Wc3[(size_t)k * 10 + w];
#pragma unroll
            for (int g = 0; g < Gg; ++g) acc[g] += xs[g * 256 + k] * wv;
        }
#pragma unroll
        for (int g = 0; g < Gg; ++g) {
            float v = acc[g];
            for (int off = 32; off; off >>= 1) v += __shfl_down(v, off, 64);
            if (lane == 0) {
                v += bc3[w];
                out[g * 10 + w] = v > 0.f ? v : 0.01f * v;
            }
        }
    }
}

extern "C" void kernel_launch(void* const* d_in, const int* in_sizes, int n_in,
                              void* d_out, int out_size, void* d_ws, size_t ws_size,
                              hipStream_t stream)
{
    const float* inputs = (const float*)d_in[0];
    const int*   src    = (const int*)d_in[1];
    const int*   dst    = (const int*)d_in[2];
    const int*   gid    = (const int*)d_in[3];
    const float* W1  = (const float*)d_in[4];
    const float* b1  = (const float*)d_in[5];
    const float* W2  = (const float*)d_in[6];
    const float* b2  = (const float*)d_in[7];
    const float* W3  = (const float*)d_in[8];
    const float* b3  = (const float*)d_in[9];
    const float* Wc1 = (const float*)d_in[10];
    const float* bc1 = (const float*)d_in[11];
    const float* Wc2 = (const float*)d_in[12];
    const float* bc2 = (const float*)d_in[13];
    const float* Wc3 = (const float*)d_in[14];
    const float* bc3 = (const float*)d_in[15];

    // ---- workspace layout ----
    int*   wi      = (int*)d_ws;
    int*   odeg    = wi;                       // NP
    int*   row_ptr = odeg + NP;                // NP (uses N+1)
    int*   cursor  = row_ptr + NP;             // NP
    int*   bsum    = cursor + NP;              // 64
    int*   csr_dst = bsum + 64;                // Ee
    float* wf      = (float*)(csr_dst + Ee);
    float* srcn    = wf;                       // NP
    float* pq      = srcn + NP;                // NP
    float* z       = pq + NP;                  // NP*8
    float* u1      = z + (size_t)NP * 8;       // NP*8
    float* u2      = u1 + (size_t)NP * 8;      // NP*8
    float* u3      = u2 + (size_t)NP * 8;      // NP*8
    float* partial = u3 + (size_t)NP * 8;      // PBLK*1024
    float* pooled  = partial + (size_t)PBLK * Gg * Dd;  // 1024
    float* pw1     = pooled + Gg * Dd;         // 8
    float* pw2     = pw1 + Gg;                 // 8
    int*   cnt     = (int*)(pw2 + Gg);         // 8
    float* W12v    = (float*)(cnt + Gg);       // 128*128
    float* W123v   = W12v + 128 * 128;         // 128*128
    float* e1v     = W123v + 128 * 128;        // 128
    float* e1bv    = e1v + 128;                // 128
    float* e2v     = e1bv + 128;               // 128
    float* x0g     = e2v + 128;                // G*128
    float* x1g     = x0g + Gg * 128;           // G*512
    float* x2g     = x1g + Gg * 512;           // G*256
    unsigned int* phist = (unsigned int*)(x2g + Gg * 256);  // 32*HWORDS

    // ---- degrees + norms + z seeds + CSR-by-src (piggybacked W-chain;
    //      accumulators pw1/pw2/cnt zeroed by spare threads) ----
    hist_kernel<<<HIST_BLOCKS + W12_BLOCKS + 1, 1024, 0, stream>>>(
        src, dst, phist, W1, W2, W3, b1, b2, W12v, e1v, e2v, pw1);
    reduce_norm_kernel<<<RN_BLOCKS + W123_BLOCKS + 1, 256, 0, stream>>>(
        phist, gid, odeg, srcn, pq, z, cnt, W12v, W3, e1v, W123v, e1bv);
    scanA<<<NCHUNK, 256, 0, stream>>>(odeg, row_ptr, bsum);
    scanB<<<1, 64, 0, stream>>>(bsum);
    scanC<<<(Nn + 255) / 256, 256, 0, stream>>>(row_ptr, bsum, cursor);
    fill_kernel<<<(Ee + 255) / 256, 256, 0, stream>>>(src, dst, cursor, csr_dst);

    // ---- backward chain: u1 = A^T z ; u2 = A^T(pq*u1) ; u3 = A^T(pq*u2) ----
    int bblocks = (Nn + 31) / 32;
    bspmm_kernel<<<bblocks, 256, 0, stream>>>(z, row_ptr, csr_dst, nullptr,
                                              u1, srcn, pw1);
    bspmm_kernel<<<bblocks, 256, 0, stream>>>(u1, row_ptr, csr_dst, pq,
                                              u2, srcn, pw2);
    bspmm_kernel<<<bblocks, 256, 0, stream>>>(u2, row_ptr, csr_dst, pq,
                                              u3, nullptr, nullptr);

    // ---- pooled[g][c] = sum_n sn[n]*u3[n][g] * x[n][c] (dense read of x) ----
    dotpool_kernel<<<PBLK, 256, 0, stream>>>(inputs, u3, srcn, partial);
    dotreduce_kernel<<<4, 256, 0, stream>>>(partial, pooled);

    // ---- head ----
    x0_kernel<<<1, 1024, 0, stream>>>(pooled, pw1, pw2, cnt, W123v, e1bv, e2v,
                                      b3, x0g);
    fc1_kernel<<<32, 256, 0, stream>>>(x0g, Wc1, bc1, x1g);
    fc2_kernel<<<32, 256, 0, stream>>>(x1g, Wc2, bc2, x2g);
    fc3_kernel<<<1, 640, 0, stream>>>(x2g, Wc3, bc3, (float*)d_out);
}

// Round 11
// 195.744 us; speedup vs baseline: 18.1421x; 1.0128x over previous
//
#include <hip/hip_runtime.h>

#define Nn 50000
#define Ee 600000
#define Gg 8
#define Dd 128
#define NP 50048
#define NCHUNK 49           // scan blocks (1024 nodes each)

#define HWORDS 25024        // ceil(N/2); 2x16-bit counters per word
#define HB 16
#define HIST_BLOCKS (2 * HB)          // 32
#define W12_BLOCKS 16
#define W123_BLOCKS 64
#define PBLK ((Nn + 127) / 128)       // 391

// ---------------- hist + piggyback W12/e1/e2 + zero accumulators/flags ----
__global__ __launch_bounds__(1024) void hist_kernel(
    const int* __restrict__ src, const int* __restrict__ dst,
    unsigned int* __restrict__ phist,
    const float* __restrict__ W1, const float* __restrict__ W2,
    const float* __restrict__ W3, const float* __restrict__ b1,
    const float* __restrict__ b2,
    float* __restrict__ W12, float* __restrict__ e1, float* __restrict__ e2,
    int* __restrict__ accz)   // pw1(8),pw2(8),cnt(8),fs(64) -> 88 words
{
    __shared__ unsigned int h[HWORDS];
    int t = threadIdx.x;
    int b = blockIdx.x;

    if (b < HIST_BLOCKS) {
        for (int i = t; i < HWORDS; i += 1024) h[i] = 0u;
        __syncthreads();
        int part = b >> 1;
        const int* arr = (b & 1) ? dst : src;
        int e0 = part * (Ee / HB);
        int eN = e0 + (Ee / HB);
        for (int e = e0 + t; e < eN; e += 1024) {
            int n = arr[e];
            atomicAdd(&h[n >> 1], 1u << ((n & 1) << 4));
        }
        __syncthreads();
        unsigned int* out = phist + (size_t)b * HWORDS;
        for (int i = t; i < HWORDS; i += 1024) out[i] = h[i];
    } else if (b < HIST_BLOCKS + W12_BLOCKS) {
        int j = (b - HIST_BLOCKS) * 8 + (t & 7);
        int k = t >> 3;
        float a = 0.f;
#pragma unroll 8
        for (int m = 0; m < 128; ++m) a += W1[k * 128 + m] * W2[m * 128 + j];
        W12[k * 128 + j] = a;
    } else {
        if (t < 128) {
            float a = 0.f;
#pragma unroll 8
            for (int k = 0; k < 128; ++k) a += b1[k] * W2[k * 128 + t];
            e1[t] = a;
        } else if (t < 256) {
            int c = t - 128;
            float a = 0.f;
#pragma unroll 8
            for (int k = 0; k < 128; ++k) a += b2[k] * W3[k * 128 + c];
            e2[c] = a;
        } else if (t < 256 + 88) {
            accz[t - 256] = 0;      // zero pw1, pw2, cnt, lookback flags
        }
    }
}

// ---------------- fused: partial-reduce + norms + z + lookback scan --------
// blocks [0,49): 1024 nodes each. blocks [49,113): W123. block 113: e1b.
__global__ __launch_bounds__(256) void scan_fused(
    const unsigned int* __restrict__ phist, const int* __restrict__ gid,
    float* __restrict__ srcn, float* __restrict__ pq, float* __restrict__ z,
    int* __restrict__ cnt, int* __restrict__ row_ptr, int* __restrict__ cursor,
    int* __restrict__ fs,
    const float* __restrict__ W12, const float* __restrict__ W3,
    const float* __restrict__ e1,
    float* __restrict__ W123, float* __restrict__ e1b)
{
    int b = blockIdx.x, t = threadIdx.x;
    if (b < NCHUNK) {
        __shared__ int tsum[256];
        __shared__ int lc[Gg];
        __shared__ int sbase;
        if (t < Gg) lc[t] = 0;
        __syncthreads();

        int d4[4];
        int wbase = b * 512 + t * 2;
#pragma unroll
        for (int wi = 0; wi < 2; ++wi) {
            int w = wbase + wi;
            unsigned so0 = 0, so1 = 0, si0 = 0, si1 = 0;
            if (w < HWORDS) {
#pragma unroll
                for (int p = 0; p < HB; ++p) {
                    unsigned a  = phist[(size_t)(2 * p) * HWORDS + w];
                    unsigned bb = phist[(size_t)(2 * p + 1) * HWORDS + w];
                    so0 += a & 0xffffu; so1 += a >> 16;
                    si0 += bb & 0xffffu; si1 += bb >> 16;
                }
            }
#pragma unroll
            for (int hh = 0; hh < 2; ++hh) {
                int n = 2 * w + hh;
                unsigned so = hh ? so1 : so0, si = hh ? si1 : si0;
                int d = 0;
                if (n < Nn) {
                    d = (int)so;
                    float sn = 1.f / sqrtf(fmaxf((float)so, 1.f));
                    float dn = 1.f / sqrtf(fmaxf((float)si, 1.f));
                    srcn[n] = sn; pq[n] = sn * dn;
                    int g = gid[n];
                    atomicAdd(&lc[g], 1);
                    float zr[8];
#pragma unroll
                    for (int gg = 0; gg < 8; ++gg) zr[gg] = (gg == g) ? dn : 0.f;
                    *(float4*)(z + (size_t)n * 8)     = *(float4*)zr;
                    *(float4*)(z + (size_t)n * 8 + 4) = *(float4*)(zr + 4);
                }
                d4[wi * 2 + hh] = d;
            }
        }
        int s = (d4[0] + d4[1]) + (d4[2] + d4[3]);
        tsum[t] = s;
        __syncthreads();
        for (int off = 1; off < 256; off <<= 1) {
            int x = (t >= off) ? tsum[t - off] : 0;
            __syncthreads();
            tsum[t] += x;
            __syncthreads();
        }
        int run = tsum[t] - s;

        if (t == 0) {
            int total = tsum[255];
            atomicExch(&fs[b], (total << 1) | 1);   // publish aggregate
            int base = 0;
            for (int p = 0; p < b; ++p) {           // sum predecessors
                int r;
                do { r = atomicAdd(&fs[p], 0); } while (!(r & 1));
                base += (r >> 1);
            }
            sbase = base;
        }
        __syncthreads();

        int gpos = sbase + run;
#pragma unroll
        for (int i = 0; i < 4; ++i) {
            int n = b * 1024 + t * 4 + i;
            if (n < Nn) { row_ptr[n] = gpos; cursor[n] = gpos; }
            gpos += d4[i];
        }
        if (b == NCHUNK - 1 && t == 255) row_ptr[Nn] = Ee;
        __syncthreads();
        if (t < Gg && lc[t] > 0) atomicAdd(&cnt[t], lc[t]);
    } else if (b < NCHUNK + W123_BLOCKS) {
        int j = (b - NCHUNK) * 2 + (t & 1);
        int k = t >> 1;
        float a = 0.f;
#pragma unroll 8
        for (int m = 0; m < 128; ++m) a += W12[k * 128 + m] * W3[m * 128 + j];
        W123[k * 128 + j] = a;
    } else {
        if (t < 128) {
            float a = 0.f;
#pragma unroll 8
            for (int k = 0; k < 128; ++k) a += e1[k] * W3[k * 128 + t];
            e1b[t] = a;
        }
    }
}

// ---------------- CSR-by-src fill ------------------------------------------
__global__ __launch_bounds__(256) void fill_kernel(
    const int* __restrict__ src, const int* __restrict__ dst,
    int* __restrict__ cursor, int* __restrict__ csr_dst)
{
    int e = blockIdx.x * 256 + threadIdx.x;
    if (e >= Ee) return;
    int pos = atomicAdd(&cursor[src[e]], 1);
    csr_dst[pos] = dst[e];
}

// ---------------- backward SpMM (N x 8) ------------------------------------
__global__ __launch_bounds__(256) void bspmm_kernel(
    const float* __restrict__ uin, const int* __restrict__ row_ptr,
    const int* __restrict__ csr, const float* __restrict__ scal,
    float* __restrict__ uout, const float* __restrict__ sn,
    float* __restrict__ pwout)
{
    int t = threadIdx.x;
    int m = blockIdx.x * 32 + (t >> 3);
    int g = t & 7;
    float acc = 0.f, snm = 0.f;
    if (m < Nn) {
        int beg = row_ptr[m], end = row_ptr[m + 1];
        float a0 = 0.f, a1 = 0.f;
        int j = beg;
        if (scal) {
            for (; j + 1 < end; j += 2) {
                int i0 = csr[j], i1 = csr[j + 1];
                a0 += scal[i0] * uin[(size_t)i0 * 8 + g];
                a1 += scal[i1] * uin[(size_t)i1 * 8 + g];
            }
            if (j < end) { int i0 = csr[j]; a0 += scal[i0] * uin[(size_t)i0 * 8 + g]; }
        } else {
            for (; j + 1 < end; j += 2) {
                int i0 = csr[j], i1 = csr[j + 1];
                a0 += uin[(size_t)i0 * 8 + g];
                a1 += uin[(size_t)i1 * 8 + g];
            }
            if (j < end) a0 += uin[(size_t)csr[j] * 8 + g];
        }
        acc = a0 + a1;
        uout[(size_t)m * 8 + g] = acc;
        if (pwout) snm = sn[m];
    }
    if (pwout) {
        __shared__ float red[Gg];
        if (t < Gg) red[t] = 0.f;
        __syncthreads();
        atomicAdd(&red[g], snm * acc);
        __syncthreads();
        if (t < Gg) atomicAdd(&pwout[t], red[t]);
    }
}

// ---------------- fused u3-compute + dense dot-pool ------------------------
// phase1: f[i][g] = sn[n] * sum_{j in row n} pq[csr]*u2[csr][g]  (u3 in LDS)
// phase2: partial[b][g][c] = sum_i f[i][g]*x[n0+i][c]
__global__ __launch_bounds__(256) void dotpool_kernel(
    const float* __restrict__ x, const float* __restrict__ u2,
    const float* __restrict__ pq, const float* __restrict__ sn,
    const int* __restrict__ row_ptr, const int* __restrict__ csr,
    float* __restrict__ partial)
{
    __shared__ float f[128][Gg];
    __shared__ float sp[Gg][Dd];
    int t = threadIdx.x;
    int n0 = blockIdx.x * 128;

    {   // phase 1: 2 threads per node, 4 g-channels each
        int i = t >> 1, gq = (t & 1) * 4;
        int n = n0 + i;
        float4 a0 = {0.f,0.f,0.f,0.f}, a1 = {0.f,0.f,0.f,0.f};
        float s = 0.f;
        if (n < Nn) {
            s = sn[n];
            int beg = row_ptr[n], end = row_ptr[n + 1];
            int j = beg;
            for (; j + 1 < end; j += 2) {
                int i0 = csr[j], i1 = csr[j + 1];
                float c0 = pq[i0], c1 = pq[i1];
                float4 u0 = *(const float4*)(u2 + (size_t)i0 * 8 + gq);
                float4 u1 = *(const float4*)(u2 + (size_t)i1 * 8 + gq);
                a0.x += c0 * u0.x; a0.y += c0 * u0.y;
                a0.z += c0 * u0.z; a0.w += c0 * u0.w;
                a1.x += c1 * u1.x; a1.y += c1 * u1.y;
                a1.z += c1 * u1.z; a1.w += c1 * u1.w;
            }
            if (j < end) {
                int i0 = csr[j];
                float c0 = pq[i0];
                float4 u0 = *(const float4*)(u2 + (size_t)i0 * 8 + gq);
                a0.x += c0 * u0.x; a0.y += c0 * u0.y;
                a0.z += c0 * u0.z; a0.w += c0 * u0.w;
            }
        }
        f[i][gq + 0] = s * (a0.x + a1.x);
        f[i][gq + 1] = s * (a0.y + a1.y);
        f[i][gq + 2] = s * (a0.z + a1.z);
        f[i][gq + 3] = s * (a0.w + a1.w);
    }
    for (int i = t; i < Gg * Dd; i += 256) ((float*)sp)[i] = 0.f;
    __syncthreads();

    int r0 = t >> 5, c = t & 31;
    float4 acc[Gg];
#pragma unroll
    for (int g = 0; g < Gg; ++g) acc[g] = make_float4(0.f, 0.f, 0.f, 0.f);
    for (int i = r0; i < 128; i += 8) {
        int n = n0 + i;
        if (n >= Nn) break;
        float4 xv = ((const float4*)x)[(size_t)n * 32 + c];
#pragma unroll
        for (int g = 0; g < Gg; ++g) {
            float fv = f[i][g];
            acc[g].x += fv * xv.x; acc[g].y += fv * xv.y;
            acc[g].z += fv * xv.z; acc[g].w += fv * xv.w;
        }
    }
#pragma unroll
    for (int g = 0; g < Gg; ++g) {
        atomicAdd(&sp[g][c * 4 + 0], acc[g].x);
        atomicAdd(&sp[g][c * 4 + 1], acc[g].y);
        atomicAdd(&sp[g][c * 4 + 2], acc[g].z);
        atomicAdd(&sp[g][c * 4 + 3], acc[g].w);
    }
    __syncthreads();
    float* out = partial + (size_t)blockIdx.x * Gg * Dd;
    for (int i = t; i < Gg * Dd; i += 256) out[i] = ((float*)sp)[i];
}

// ---------------- fused reduce + x0: 4 blocks x 256 ------------------------
// block b owns outputs [b*256, b*256+256) = graph rows {2b, 2b+1}
__global__ __launch_bounds__(256) void redx0_kernel(
    const float* __restrict__ partial, const float* __restrict__ pw1r,
    const float* __restrict__ pw2r, const int* __restrict__ cnt,
    const float* __restrict__ W123, const float* __restrict__ e1b,
    const float* __restrict__ e2, const float* __restrict__ b3,
    float* __restrict__ x0g)
{
    __shared__ float ps[256];    // 2 pooled rows
    int t = threadIdx.x;
    int o = blockIdx.x * 256 + t;
    float a0 = 0.f, a1 = 0.f, a2 = 0.f, a3 = 0.f;
    int b = 0;
    for (; b + 3 < PBLK; b += 4) {
        a0 += partial[(size_t)(b + 0) * 1024 + o];
        a1 += partial[(size_t)(b + 1) * 1024 + o];
        a2 += partial[(size_t)(b + 2) * 1024 + o];
        a3 += partial[(size_t)(b + 3) * 1024 + o];
    }
    for (; b < PBLK; ++b) a0 += partial[(size_t)b * 1024 + o];
    ps[t] = (a0 + a1) + (a2 + a3);
    __syncthreads();

    int g = o >> 7, c = o & 127, gl = t >> 7;
    float a = 0.f;
#pragma unroll 8
    for (int k = 0; k < 128; ++k) a += ps[gl * 128 + k] * W123[k * 128 + c];
    float inv = 1.f / fmaxf((float)cnt[g], 1.f);
    x0g[o] = a * inv + (pw2r[g] * inv) * e1b[c] + (pw1r[g] * inv) * e2[c] + b3[c];
}

// ---------------- head: fc1 (128->512), 32 blocks --------------------------
__global__ __launch_bounds__(256) void fc1_kernel(
    const float* __restrict__ x0g, const float* __restrict__ Wc1,
    const float* __restrict__ bc1, float* __restrict__ x1g)
{
    __shared__ float xs[Gg * 128];
    __shared__ float par[256];
    int t = threadIdx.x;
    for (int i = t; i < Gg * 128; i += 256) xs[i] = x0g[i];
    __syncthreads();
    int h = t >> 7, rem = t & 127;
    int g = rem >> 4, m = blockIdx.x * 16 + (rem & 15);
    int k0 = h * 64;
    float a = 0.f;
#pragma unroll 16
    for (int k = 0; k < 64; ++k) a += xs[g * 128 + k0 + k] * Wc1[(size_t)(k0 + k) * 512 + m];
    par[t] = a;
    __syncthreads();
    if (t < 128) {
        float v = par[t] + par[t + 128] + bc1[m];
        x1g[g * 512 + m] = v > 0.f ? v : 0.01f * v;
    }
}

// ---------------- head: fc2 (512->256), 32 blocks --------------------------
__global__ __launch_bounds__(256) void fc2_kernel(
    const float* __restrict__ x1g, const float* __restrict__ Wc2,
    const float* __restrict__ bc2, float* __restrict__ x2g)
{
    __shared__ float xs[Gg * 512];
    __shared__ float par[256];
    int t = threadIdx.x;
    for (int i = t; i < Gg * 512; i += 256) xs[i] = x1g[i];
    __syncthreads();
    int q = t >> 6, rem = t & 63;
    int g = rem >> 3, m = blockIdx.x * 8 + (rem & 7);
    int k0 = q * 128;
    float a = 0.f;
#pragma unroll 16
    for (int k = 0; k < 128; ++k) a += xs[g * 512 + k0 + k] * Wc2[(size_t)(k0 + k) * 256 + m];
    par[t] = a;
    __syncthreads();
    if (t < 64) {
        float v = par[t] + par[t + 64] + par[t + 128] + par[t + 192] + bc2[m];
        x2g[g * 256 + m] = v > 0.f ? v : 0.01f * v;
    }
}

// ---------------- head: fc3 (256->10), 1 block -----------------------------
__global__ __launch_bounds__(640) void fc3_kernel(
    const float* __restrict__ x2g, const float* __restrict__ Wc3,
    const float* __restrict__ bc3, float* __restrict__ out)
{
    __shared__ float xs[Gg * 256];
    int t = threadIdx.x;
    for (int i = t; i < Gg * 256; i += 640) xs[i] = x2g[i];
    __syncthreads();
    int w = t >> 6, lane = t & 63;
    if (w < 10) {
        float acc[Gg];
#pragma unroll
        for (int g = 0; g < Gg; ++g) acc[g] = 0.f;
#pragma unroll
        for (int kk = 0; kk < 4; ++kk) {
            int k = lane + kk * 64;
            float wv = Wc3[(size_t)k * 10 + w];
#pragma unroll
            for (int g = 0; g < Gg; ++g) acc[g] += xs[g * 256 + k] * wv;
        }
#pragma unroll
        for (int g = 0; g < Gg; ++g) {
            float v = acc[g];
            for (int off = 32; off; off >>= 1) v += __shfl_down(v, off, 64);
            if (lane == 0) {
                v += bc3[w];
                out[g * 10 + w] = v > 0.f ? v : 0.01f * v;
            }
        }
    }
}

extern "C" void kernel_launch(void* const* d_in, const int* in_sizes, int n_in,
                              void* d_out, int out_size, void* d_ws, size_t ws_size,
                              hipStream_t stream)
{
    const float* inputs = (const float*)d_in[0];
    const int*   src    = (const int*)d_in[1];
    const int*   dst    = (const int*)d_in[2];
    const int*   gid    = (const int*)d_in[3];
    const float* W1  = (const float*)d_in[4];
    const float* b1  = (const float*)d_in[5];
    const float* W2  = (const float*)d_in[6];
    const float* b2  = (const float*)d_in[7];
    const float* W3  = (const float*)d_in[8];
    const float* b3  = (const float*)d_in[9];
    const float* Wc1 = (const float*)d_in[10];
    const float* bc1 = (const float*)d_in[11];
    const float* Wc2 = (const float*)d_in[12];
    const float* bc2 = (const float*)d_in[13];
    const float* Wc3 = (const float*)d_in[14];
    const float* bc3 = (const float*)d_in[15];

    // ---- workspace layout ----
    int*   wi      = (int*)d_ws;
    int*   row_ptr = wi;                       // NP (uses N+1)
    int*   cursor  = row_ptr + NP;             // NP
    int*   csr_dst = cursor + NP;              // Ee
    float* wf      = (float*)(csr_dst + Ee);
    float* srcn    = wf;                       // NP
    float* pq      = srcn + NP;                // NP
    float* z       = pq + NP;                  // NP*8
    float* u1      = z + (size_t)NP * 8;       // NP*8
    float* u2      = u1 + (size_t)NP * 8;      // NP*8
    float* partial = u2 + (size_t)NP * 8;      // PBLK*1024
    float* pw1     = partial + (size_t)PBLK * 1024;  // 8
    float* pw2     = pw1 + Gg;                 // 8
    int*   cnt     = (int*)(pw2 + Gg);         // 8
    int*   fs      = cnt + Gg;                 // 64 (lookback flags)
    float* W12v    = (float*)(fs + 64);        // 128*128
    float* W123v   = W12v + 128 * 128;         // 128*128
    float* e1v     = W123v + 128 * 128;        // 128
    float* e1bv    = e1v + 128;                // 128
    float* e2v     = e1bv + 128;               // 128
    float* x0g     = e2v + 128;                // 1024
    float* x1g     = x0g + 1024;               // 4096
    float* x2g     = x1g + 4096;               // 2048
    unsigned int* phist = (unsigned int*)(x2g + 2048);  // 32*HWORDS

    // 1. histograms + W12/e1/e2 + zero pw1/pw2/cnt/flags
    hist_kernel<<<HIST_BLOCKS + W12_BLOCKS + 1, 1024, 0, stream>>>(
        src, dst, phist, W1, W2, W3, b1, b2, W12v, e1v, e2v, (int*)pw1);
    // 2. fused: partial-reduce -> norms/z/cnt + lookback scan -> row_ptr/cursor
    scan_fused<<<NCHUNK + W123_BLOCKS + 1, 256, 0, stream>>>(
        phist, gid, srcn, pq, z, cnt, row_ptr, cursor, fs,
        W12v, W3, e1v, W123v, e1bv);
    // 3. CSR fill
    fill_kernel<<<(Ee + 255) / 256, 256, 0, stream>>>(src, dst, cursor, csr_dst);

    // 4-5. backward chain (u3 folded into dotpool)
    int bblocks = (Nn + 31) / 32;
    bspmm_kernel<<<bblocks, 256, 0, stream>>>(z, row_ptr, csr_dst, nullptr,
                                              u1, srcn, pw1);
    bspmm_kernel<<<bblocks, 256, 0, stream>>>(u1, row_ptr, csr_dst, pq,
                                              u2, srcn, pw2);

    // 6. fused u3 + dot-pool
    dotpool_kernel<<<PBLK, 256, 0, stream>>>(inputs, u2, pq, srcn,
                                             row_ptr, csr_dst, partial);
    // 7. fused reduce + x0
    redx0_kernel<<<4, 256, 0, stream>>>(partial, pw1, pw2, cnt,
                                        W123v, e1bv, e2v, b3, x0g);
    // 8-10. MLP head
    fc1_kernel<<<32, 256, 0, stream>>>(x0g, Wc1, bc1, x1g);
    fc2_kernel<<<32, 256, 0, stream>>>(x1g, Wc2, bc2, x2g);
    fc3_kernel<<<1, 640, 0, stream>>>(x2g, Wc3, bc3, (float*)d_out);
}